// Round 8
// baseline (750.027 us; speedup 1.0000x reference)
//
#include <hip/hip_runtime.h>
#include <hip/hip_bf16.h>
#include <math.h>

#define BB 4
#define NN 1437
#define SS 56
#define PP 28
#define FIN 10
#define FFUT 6
#define HH 64
#define NBLK 2
#define TOPK 5
#define DD (SS*HH)     /* 3584 */
#define FD (PP*HH)     /* 1792 */
#define TOT (DD+FD)    /* 5376 */
#define MP 1536        /* padded M (12*128) */
#define KP 1472        /* padded K (46*32)  */
#define NT (KP/32)     /* 46 K-steps */
#define SP 1536        /* scores stride */
#define WIMG_SZ 16384  /* shorts per mixer-block weight image */

typedef __attribute__((ext_vector_type(8))) __bf16 bf16x8;
typedef __attribute__((ext_vector_type(4))) float  f32x4;

__device__ __forceinline__ float gelu_exact(float x){
    return 0.5f*x*(1.0f+erff(x*0.70710678118654752440f));
}
__device__ __forceinline__ float wave_sum64(float v){
    #pragma unroll
    for (int o=1;o<64;o<<=1) v += __shfl_xor(v,o,64);
    return v;
}
__device__ __forceinline__ void async_load16(const void* g, void* l){
    __builtin_amdgcn_global_load_lds(
        (const __attribute__((address_space(1))) void*)g,
        (__attribute__((address_space(3))) void*)l, 16, 0, 0);
}
__device__ __forceinline__ unsigned short f2bf(float x){
    unsigned int u = __float_as_uint(x);
    unsigned int r = (u + 0x7fffu + ((u>>16)&1u)) >> 16;
    return (unsigned short)r;
}
__device__ __forceinline__ unsigned long long umax64(unsigned long long a, unsigned long long b){return a>b?a:b;}
__device__ __forceinline__ unsigned long long umin64(unsigned long long a, unsigned long long b){return a<b?a:b;}

// ---------------- emb norm ----------------
__global__ __launch_bounds__(64) void k_embnorm(const float* __restrict__ emb,
                                                float* __restrict__ out){
    int n = blockIdx.x; int l = threadIdx.x;
    float v = emb[(size_t)n*HH+l];
    float ss = wave_sum64(v*v);
    float nrm = fmaxf(sqrtf(ss), 1e-12f);
    out[(size_t)n*HH+l] = v/nrm;
}

// ------- front: h = LN(x@fp_w^T+fp_b)+embn ; ctx = recency ctx -------
__global__ __launch_bounds__(256) void k_front(
    const float* __restrict__ x, const float* __restrict__ fpw, const float* __restrict__ fpb,
    const float* __restrict__ lng, const float* __restrict__ lnb,
    const float* __restrict__ embn, float* __restrict__ h, float* __restrict__ ctx)
{
    int bn = blockIdx.x; int n = bn % NN;
    int tid=threadIdx.x; int lane=tid&63; int wv=tid>>6;
    __shared__ float xin[SS*FIN];
    __shared__ float wlds[HH*FIN];
    __shared__ float rw[SS];
    __shared__ float rsum;
    __shared__ float red[4][HH];
    for (int i=tid;i<SS*FIN;i+=256) xin[i]=x[(size_t)bn*SS*FIN+i];
    for (int i=tid;i<HH*FIN;i+=256) wlds[i]=fpw[i];
    if (tid<SS) rw[tid]=expf(-(float)(SS-tid)/14.0f);
    __syncthreads();
    if (tid==0){ float s=0.f; for(int i=0;i<SS;++i) s+=rw[i]; rsum=s; }
    __syncthreads();
    float inv_rs = 1.0f/rsum;
    float gg=lng[lane], bv=lnb[lane], el=embn[(size_t)n*HH+lane], fb0=fpb[lane];
    float cacc=0.f;
    for (int s=wv;s<SS;s+=4){
        float v=fb0;
        #pragma unroll
        for (int c=0;c<FIN;++c) v += xin[s*FIN+c]*wlds[lane*FIN+c];
        float m = wave_sum64(v)*(1.f/HH);
        float d = v-m;
        float va = wave_sum64(d*d)*(1.f/HH);
        float hn = d*rsqrtf(va+1e-5f)*gg + bv + el;
        h[((size_t)bn*SS+s)*HH+lane]=hn;
        cacc += hn * rw[s]*inv_rs;
    }
    red[wv][lane]=cacc;
    __syncthreads();
    if (wv==0) ctx[(size_t)bn*HH+lane]=red[0][lane]+red[1][lane]+red[2][lane]+red[3][lane];
}

// ---------------- Q/K projections -> K-packed bf16 [b][8][MP][8] ----------------
__global__ __launch_bounds__(64) void k_qk(
    const float* __restrict__ ctx, const float* __restrict__ qw, const float* __restrict__ qb,
    const float* __restrict__ kw, const float* __restrict__ kb,
    unsigned short* __restrict__ qpack, unsigned short* __restrict__ kpack)
{
    __shared__ float wq[HH*65];
    __shared__ float wk2[HH*65];
    int lane=threadIdx.x; int bn=blockIdx.x;
    for (int i=lane;i<HH*HH;i+=64){ int hh=i>>6, kk=i&63; wq[kk*65+hh]=qw[i]; wk2[kk*65+hh]=kw[i]; }
    __syncthreads();
    const float* c = ctx + (size_t)bn*HH;
    float q=qb[lane], k=kb[lane];
    for (int kk=0;kk<HH;++kk){ float cv=c[kk]; q+=cv*wq[kk*65+lane]; k+=cv*wk2[kk*65+lane]; }
    int b = bn/NN, m = bn%NN;
    size_t off = (size_t)b*8*MP*8 + (size_t)(lane>>3)*MP*8 + (size_t)m*8 + (lane&7);
    qpack[off]=f2bf(q); kpack[off]=f2bf(k);
}

// ---------------- QK^T via MFMA -> scores = relu(clip(QK^T/8)) f32 ----------------
__global__ __launch_bounds__(256) void k_qkt(
    const unsigned short* __restrict__ qp, const unsigned short* __restrict__ kp,
    float* __restrict__ scores)
{
    int bm=blockIdx.x, bnn=blockIdx.y, b=blockIdx.z;
    int tid=threadIdx.x, lane=tid&63, wv=tid>>6;
    int g=lane>>4, c15=lane&15;
    int m0=bm*128, n0=bnn*128;
    __shared__ unsigned short As[8192];  // [8][128][8]
    __shared__ unsigned short Bs[8192];
    const char* qbase = (const char*)(qp + (size_t)b*8*MP*8);
    const char* kbase = (const char*)(kp + (size_t)b*8*MP*8);
    #pragma unroll
    for (int i=0;i<4;++i){
        int idx=i*256+tid; int ch=idx>>7, r=idx&127;
        async_load16(qbase + ((size_t)(ch*MP + m0 + r))*16, (char*)As + idx*16);
        async_load16(kbase + ((size_t)(ch*MP + n0 + r))*16, (char*)Bs + idx*16);
    }
    asm volatile("s_waitcnt vmcnt(0)");
    __syncthreads();
    int wr=wv>>1, wc=wv&1;
    f32x4 acc[4][4];
    #pragma unroll
    for (int i=0;i<4;++i)
        #pragma unroll
        for (int j=0;j<4;++j) acc[i][j]=(f32x4){0.f,0.f,0.f,0.f};
    #pragma unroll
    for (int kc=0;kc<2;++kc){
        bf16x8 af[4], bfv[4];
        #pragma unroll
        for (int i=0;i<4;++i)
            af[i]=*(const bf16x8*)((const char*)As + ((4*kc+g)*128 + wr*64+i*16+c15)*16);
        #pragma unroll
        for (int j=0;j<4;++j)
            bfv[j]=*(const bf16x8*)((const char*)Bs + ((4*kc+g)*128 + wc*64+j*16+c15)*16);
        #pragma unroll
        for (int i=0;i<4;++i)
            #pragma unroll
            for (int j=0;j<4;++j)
                acc[i][j]=__builtin_amdgcn_mfma_f32_16x16x32_bf16(af[i],bfv[j],acc[i][j],0,0,0);
    }
    #pragma unroll
    for (int i=0;i<4;++i){
        #pragma unroll
        for (int q=0;q<4;++q){
            int m = m0 + wr*64 + i*16 + g*4 + q;
            float* sr = scores + ((size_t)b*SP + m)*SP + n0 + wc*64 + c15;
            #pragma unroll
            for (int j=0;j<4;++j){
                float v = acc[i][j][q]*0.125f;
                v = fminf(fmaxf(v,0.f),10.f);
                sr[j*16]=v;
            }
        }
    }
}

// ---- top-5 + softmax + blend + L1 normalize -> comb bf16 [b][MP][KP] ----
#define INS(x) do{ unsigned long long t_=(x); \
    unsigned long long n0_=umax64(u0,t_), t1_=umin64(u0,t_); \
    unsigned long long n1_=umax64(u1,t1_), t2_=umin64(u1,t1_); \
    unsigned long long n2_=umax64(u2,t2_), t3_=umin64(u2,t2_); \
    unsigned long long n3_=umax64(u3,t3_), t4_=umin64(u3,t3_); \
    unsigned long long n4_=umax64(u4,t4_); \
    u0=n0_;u1=n1_;u2=n2_;u3=n3_;u4=n4_; }while(0)

#define MERGE(b0,b1,b2,b3,b4) do{ \
    unsigned long long o0_=umax64(u0,(b0)); \
    unsigned long long o1_=umax64(umax64((b1),umin64(u0,(b0))),u1); \
    unsigned long long o2_=umax64(umax64((b2),umin64(u0,(b1))),umax64(umin64(u1,(b0)),u2)); \
    unsigned long long o3_=umax64(umax64((b3),umin64(u0,(b2))),umax64(umin64(u1,(b1)),umax64(umin64(u2,(b0)),u3))); \
    unsigned long long o4_=umax64(umax64((b4),umin64(u0,(b3))),umax64(umax64(umin64(u1,(b2)),umin64(u2,(b1))),umax64(umin64(u3,(b0)),u4))); \
    u0=o0_;u1=o1_;u2=o2_;u3=o3_;u4=o4_; }while(0)

__global__ __launch_bounds__(256) void k_topk(
    const float* __restrict__ scores, const float* __restrict__ adj,
    const float* __restrict__ galpha, __hip_bfloat16* __restrict__ combh)
{
    int m=blockIdx.x, b=blockIdx.y, tid=threadIdx.x, lane=tid&63, wv=tid>>6;
    __shared__ float row[KP];
    __shared__ unsigned long long wtop[4][8];
    __shared__ float redp[4];
    const float* srow = scores + ((size_t)b*SP + m)*SP;
    unsigned long long u0=0,u1=0,u2=0,u3=0,u4=0;
    for (int n=tid;n<NN;n+=256){
        float v=srow[n];
        unsigned long long key=((unsigned long long)__float_as_uint(v)<<32)|(unsigned long long)(0xFFFFFFFFu-(unsigned)n);
        INS(key);
    }
    #pragma unroll
    for (int off=1; off<64; off<<=1){
        unsigned long long b0=__shfl_xor(u0,off,64), b1=__shfl_xor(u1,off,64),
                           b2=__shfl_xor(u2,off,64), b3=__shfl_xor(u3,off,64),
                           b4=__shfl_xor(u4,off,64);
        MERGE(b0,b1,b2,b3,b4);
    }
    if (lane==0){ wtop[wv][0]=u0; wtop[wv][1]=u1; wtop[wv][2]=u2; wtop[wv][3]=u3; wtop[wv][4]=u4; }
    __syncthreads();
    u0=wtop[0][0]; u1=wtop[0][1]; u2=wtop[0][2]; u3=wtop[0][3]; u4=wtop[0][4];
    #pragma unroll
    for (int w2=1;w2<4;++w2)
        MERGE(wtop[w2][0],wtop[w2][1],wtop[w2][2],wtop[w2][3],wtop[w2][4]);

    float s0=__uint_as_float((unsigned)(u0>>32)), s1=__uint_as_float((unsigned)(u1>>32)),
          s2=__uint_as_float((unsigned)(u2>>32)), s3=__uint_as_float((unsigned)(u3>>32)),
          s4=__uint_as_float((unsigned)(u4>>32));
    int i0=(int)(0xFFFFFFFFu-(unsigned)u0), i1=(int)(0xFFFFFFFFu-(unsigned)u1),
        i2=(int)(0xFFFFFFFFu-(unsigned)u2), i3=(int)(0xFFFFFFFFu-(unsigned)u3),
        i4=(int)(0xFFFFFFFFu-(unsigned)u4);
    float e0=1.f, e1=expf(s1-s0), e2=expf(s2-s0), e3=expf(s3-s0), e4=expf(s4-s0);
    float den=e0+e1+e2+e3+e4;
    float alpha=1.f/(1.f+expf(-galpha[0]));
    float oma=(1.f-alpha)/den;
    float p0=oma*e0, p1=oma*e1, p2=oma*e2, p3=oma*e3, p4=oma*e4;

    const float* arow = adj + (size_t)m*NN;
    float part=0.f;
    for (int n=tid;n<NN;n+=256){
        float v=alpha*arow[n];
        v += (n==i0)?p0:0.f;
        v += (n==i1)?p1:0.f;
        v += (n==i2)?p2:0.f;
        v += (n==i3)?p3:0.f;
        v += (n==i4)?p4:0.f;
        row[n]=v;
        part+=fabsf(v);
    }
    part=wave_sum64(part);
    if (lane==0) redp[wv]=part;
    __syncthreads();
    float inv=1.f/fmaxf(redp[0]+redp[1]+redp[2]+redp[3],1e-12f);
    __hip_bfloat16* dst = combh + ((size_t)b*MP+m)*KP;
    for (int n=tid;n<KP;n+=256){
        float v = (n<NN) ? row[n]*inv : 0.f;
        dst[n]=__float2bfloat16(v);
    }
}
#undef INS
#undef MERGE

// ---- prep: build per-mixer-block bf16 weight images ----
__global__ __launch_bounds__(256) void k_prepw(
    const float* __restrict__ wk, const float* __restrict__ mk,
    const float* __restrict__ tw, const float* __restrict__ fw,
    const float* __restrict__ sw, unsigned short* __restrict__ wimg)
{
    int i = blockIdx.x; int tid = threadIdx.x;
    const float* wki = wk + i*7;
    const float* mki = mk + i*28;
    const float* twi = tw + i*SS*SS;
    const float* fwi = fw + i*HH*HH;
    const float* swi = sw + i*HH*HH;
    unsigned short* o = wimg + (size_t)i*WIMG_SZ;
    for (int e=tid; e<4096; e+=256){
        int r = e>>6, k = e&63;
        int swz = ((k*2) ^ ((r&7)<<4)) >> 1;
        float mv = 0.f;
        if (r<SS && k<SS){
            int a = k-r+3;  if (a>=0 && a<7)  mv += wki[a];
            int b2= k-r+13; if (b2>=0 && b2<28) mv += mki[b2];
        }
        o[r*64 + swz] = f2bf(mv);
        float tv = (r<SS && k<SS) ? twi[r*SS+k] : 0.f;
        o[4096 + r*64 + swz] = f2bf(tv);
        int pk = (k>>3)*512 + r*8 + (k&7);
        o[8192  + pk] = f2bf(fwi[r*HH+k]);
        o[12288 + pk] = f2bf(swi[r*HH+k]);
    }
}

// ---- prep: head_w f32 [28][5376] -> bf16 [32][5376] (pad rows zero) ----
__global__ __launch_bounds__(256) void k_prep_head(
    const float* __restrict__ hw, __hip_bfloat16* __restrict__ hw16)
{
    int i = blockIdx.x*256 + threadIdx.x;   // 32*TOT total
    int r = i / TOT, k = i - r*TOT;
    float v = (r<PP) ? hw[(size_t)r*TOT + k] : 0.f;
    hw16[i] = __float2bfloat16(v);
}

// ---- fut: feats16[bn][3584+q] = bf16(x_future @ futw^T + futb) ----
__global__ __launch_bounds__(256) void k_fut(
    const float* __restrict__ xf, const float* __restrict__ fw,
    const float* __restrict__ fbias, __hip_bfloat16* __restrict__ feats)
{
    int bn=blockIdx.x, tid=threadIdx.x;
    __shared__ float fwl[HH*FFUT];
    __shared__ float fbl[HH];
    __shared__ float xfl[PP*FFUT];
    for (int i=tid;i<HH*FFUT;i+=256) fwl[i]=fw[i];
    if (tid<HH) fbl[tid]=fbias[tid];
    for (int i=tid;i<PP*FFUT;i+=256) xfl[i]=xf[(size_t)bn*PP*FFUT+i];
    __syncthreads();
    __hip_bfloat16* dst = feats + (size_t)bn*TOT + DD;
    for (int q=tid;q<FD;q+=256){
        int pp=q>>6, hh2=q&63;
        float v=fbl[hh2];
        #pragma unroll
        for (int c2=0;c2<FFUT;++c2) v += xfl[pp*FFUT+c2]*fwl[hh2*FFUT+c2];
        dst[q]=__float2bfloat16(v);
    }
}

// ---------------- MFMA mixer block ----------------
__global__ __launch_bounds__(256) void k_mixer2(
    float* __restrict__ h, __hip_bfloat16* __restrict__ xpb,
    const unsigned short* __restrict__ wimg,
    const float* __restrict__ lncg, const float* __restrict__ lncb,
    const float* __restrict__ lntg, const float* __restrict__ lntb,
    const float* __restrict__ lnfg, const float* __restrict__ lnfb,
    const float* __restrict__ lnsg, const float* __restrict__ lnsb,
    const float* __restrict__ tb, const float* __restrict__ fb)
{
    int bn=blockIdx.x, tid=threadIdx.x, lane=tid&63, w=tid>>6;
    int g=lane>>4, c=lane&15;
    __shared__ unsigned short wbuf[4][4096];
    __shared__ unsigned short xs[4096];
    __shared__ float prm[640];

    const char* wsrc=(const char*)wimg;
    char* wdst=(char*)&wbuf[0][0];
    #pragma unroll
    for (int i=0;i<8;++i)
        async_load16(wsrc+((size_t)(i*256+tid))*16, wdst+(i*256+w*64)*16);
    if (tid<64){
        prm[tid]      =lncg[tid]; prm[64+tid] =lncb[tid];
        prm[128+tid]  =lntg[tid]; prm[192+tid]=lntb[tid];
        prm[256+tid]  =lnfg[tid]; prm[320+tid]=lnfb[tid];
        prm[384+tid]  =lnsg[tid]; prm[448+tid]=lnsb[tid];
        prm[512+tid]  =(tid<SS)?tb[tid]:0.f;
        prm[576+tid]  =fb[tid];
    }
    float xl[4][4];
    float* hb = h + (size_t)bn*DD;
    int srow = 16*w + 4*g;
    #pragma unroll
    for (int q=0;q<4;++q){
        int s=srow+q;
        #pragma unroll
        for (int tj=0;tj<4;++tj)
            xl[q][tj] = (s<SS) ? hb[s*HH + tj*16 + c] : 0.f;
    }
    __syncthreads();

    float xn[4][4];
    f32x4 acc[4];

#define LNSTAGE(GOFF,BOFF) do{ \
    _Pragma("unroll") \
    for (int q=0;q<4;++q){ \
        float sv = xl[q][0]+xl[q][1]+xl[q][2]+xl[q][3]; \
        float s2 = xl[q][0]*xl[q][0]+xl[q][1]*xl[q][1]+xl[q][2]*xl[q][2]+xl[q][3]*xl[q][3]; \
        _Pragma("unroll") \
        for (int m2=1;m2<16;m2<<=1){ sv += __shfl_xor(sv,m2,64); s2 += __shfl_xor(s2,m2,64); } \
        float mn = sv*(1.f/64.f); \
        float var = s2*(1.f/64.f)-mn*mn; \
        float rstd = rsqrtf(var+1e-5f); \
        bool ok = (srow+q)<SS; \
        _Pragma("unroll") \
        for (int tj=0;tj<4;++tj){ \
            float v=(xl[q][tj]-mn)*rstd*prm[(GOFF)+tj*16+c]+prm[(BOFF)+tj*16+c]; \
            xn[q][tj]= ok ? v : 0.f; \
        } \
    } }while(0)

#define WRITE_XNP() do{ \
    _Pragma("unroll") \
    for (int qp=0;qp<2;++qp){ \
        int s0=srow+2*qp; \
        _Pragma("unroll") \
        for (int tj=0;tj<4;++tj){ \
            unsigned int pv=(unsigned int)f2bf(xn[2*qp][tj])|((unsigned int)f2bf(xn[2*qp+1][tj])<<16); \
            *(unsigned int*)((char*)xs + ((s0>>3)*1024 + (tj*16+c)*16 + (s0&7)*2)) = pv; \
        } \
    } }while(0)

#define WRITE_XNR() do{ \
    _Pragma("unroll") \
    for (int q=0;q<4;++q){ int s=srow+q; \
        _Pragma("unroll") \
        for (int tj=0;tj<4;++tj){ \
            *(unsigned short*)((char*)xs + s*128 + (((tj*16+c)*2) ^ ((s&7)<<4))) = f2bf(xn[q][tj]); \
        } \
    } }while(0)

#define MM(APTR,BPTR) do{ \
    _Pragma("unroll") \
    for (int tj=0;tj<4;++tj) acc[tj]=(f32x4){0.f,0.f,0.f,0.f}; \
    _Pragma("unroll") \
    for (int kc=0;kc<2;++kc){ \
        int arow=16*w+c; \
        bf16x8 af=*(const bf16x8*)((const char*)(APTR)+arow*128+((kc*64+g*16)^((arow&7)<<4))); \
        _Pragma("unroll") \
        for (int tj=0;tj<4;++tj){ \
            bf16x8 bf2=*(const bf16x8*)((const char*)(BPTR)+(kc*4+g)*1024+(tj*16+c)*16); \
            acc[tj]=__builtin_amdgcn_mfma_f32_16x16x32_bf16(af,bf2,acc[tj],0,0,0); \
        } \
    } }while(0)

    LNSTAGE(0,64); WRITE_XNP();
    __syncthreads();
    MM(&wbuf[0][0], xs);
    #pragma unroll
    for (int q=0;q<4;++q)
        #pragma unroll
        for (int tj=0;tj<4;++tj) xl[q][tj]+=acc[tj][q];
    __syncthreads();
    LNSTAGE(128,192); WRITE_XNP();
    __syncthreads();
    MM(&wbuf[1][0], xs);
    #pragma unroll
    for (int q=0;q<4;++q){
        float tbv=prm[512+srow+q];
        #pragma unroll
        for (int tj=0;tj<4;++tj) xl[q][tj]+=gelu_exact(acc[tj][q]+tbv);
    }
    __syncthreads();
    LNSTAGE(256,320); WRITE_XNR();
    __syncthreads();
    MM(xs, &wbuf[2][0]);
    #pragma unroll
    for (int q=0;q<4;++q)
        #pragma unroll
        for (int tj=0;tj<4;++tj) xl[q][tj]+=gelu_exact(acc[tj][q]+prm[576+tj*16+c]);
    __syncthreads();
    LNSTAGE(384,448); WRITE_XNR();
    __syncthreads();
    MM(xs, &wbuf[3][0]);
    __hip_bfloat16* xpo = xpb + (size_t)bn*DD;
    #pragma unroll
    for (int q=0;q<4;++q){
        int s=srow+q;
        if (s<SS){
            #pragma unroll
            for (int tj=0;tj<4;++tj){
                int d=s*HH+tj*16+c;
                hb[d]=xl[q][tj];
                xpo[d]=__float2bfloat16(acc[tj][q]);
            }
        }
    }
#undef LNSTAGE
#undef WRITE_XNP
#undef WRITE_XNR
#undef MM
}

// ---- pack xp bf16 [N][D] -> MFMA-ready [KP/8][D][8] with K zero-pad ----
__global__ __launch_bounds__(256) void k_pack_xp(
    const __hip_bfloat16* __restrict__ xpb, __hip_bfloat16* __restrict__ xpg)
{
    int d = blockIdx.x*256 + threadIdx.x;
    int kc = blockIdx.y; int b = blockIdx.z;
    union { __hip_bfloat16 hv[8]; float4 f4; } u;
    #pragma unroll
    for (int j=0;j<8;++j){
        int k = kc*8+j;
        u.hv[j] = (k<NN) ? xpb[((size_t)b*NN+k)*DD + d] : __float2bfloat16(0.f);
    }
    *reinterpret_cast<float4*>(&xpg[(((size_t)b*(KP/8)+kc)*DD + d)*8]) = u.f4;
}

// ---- spatial bmm via MFMA: h[b] += comb[b] @ xp[b] + sb ----
// 64x128 tile, 4 waves (2x2 of 32x64), 4-buffer depth-3 prefetch, counted vmcnt.
__global__ __launch_bounds__(256,3) void k_bmm_mfma(
    const __hip_bfloat16* __restrict__ combh,
    const __hip_bfloat16* __restrict__ xpg,
    const float* __restrict__ sb,
    float* __restrict__ h,
    __hip_bfloat16* __restrict__ h16,
    int write_h)
{
    __shared__ short As[4][2048];   // [64][32] bf16 per buf (A-swizzled)
    __shared__ short Bs[4][4096];   // [4][128][8] per buf

    int bid = blockIdx.x;
    int wg = (bid & 7)*336 + (bid >> 3);     // bijective XCD-chunked swizzle (2688 = 8*336)
    int bm = wg % 24; int tmp2 = wg / 24; int bd = tmp2 % 28; int b = tmp2 / 28;
    int tid=threadIdx.x, lane=tid&63, w=tid>>6;
    int g=lane>>4, c=lane&15;
    int wr=w>>1, wc=w&1;
    int m0=bm*64, d0=bd*128;

    const char* cb = (const char*)(combh + (size_t)b*MP*KP);
    const char* xb = (const char*)(xpg   + (size_t)b*(KP/8)*(size_t)DD*8);

    // A staging: lane L -> LDS byte L*16 = [row=L>>2][slot=L&3]; data = k-chunk (slot ^ ((row>>1)&3))
    int arow_s = tid>>2, aslot = tid&3;
    int ag = aslot ^ ((arow_s>>1)&3);
    const char* srcA = cb + ((size_t)(m0+arow_s)*KP + ag*8)*2;
    // B staging: two insts cover chunks 0..1 and 2..3
    int bch = tid>>7, bcol = tid&127;
    const char* srcB0 = xb + ((size_t)bch*DD + d0 + bcol)*16;
    const char* srcB1 = xb + ((size_t)(bch+2)*DD + d0 + bcol)*16;
    const size_t BSTEP = (size_t)4*DD*16;

    f32x4 acc[2][4];
    #pragma unroll
    for (int i=0;i<2;++i)
        #pragma unroll
        for (int j=0;j<4;++j) acc[i][j]=(f32x4){0.f,0.f,0.f,0.f};

    // fragment LDS byte offsets
    int aoff[2], boff[4];
    #pragma unroll
    for (int i=0;i<2;++i){
        int row = 32*wr + 16*i + c;
        aoff[i] = row*64 + ((g*16) ^ (((row>>1)&3)<<4));
    }
    #pragma unroll
    for (int j=0;j<4;++j) boff[j] = (g*128 + 64*wc + 16*j + c)*16;

#define STAGE(BUF,T) do { \
    async_load16(srcA  + (size_t)(T)*64,    (char*)As[BUF] + w*1024); \
    async_load16(srcB0 + (size_t)(T)*BSTEP, (char*)Bs[BUF] + w*1024); \
    async_load16(srcB1 + (size_t)(T)*BSTEP, (char*)Bs[BUF] + 4096 + w*1024); } while(0)

    STAGE(0,0); STAGE(1,1); STAGE(2,2);
    asm volatile("s_waitcnt vmcnt(6)" ::: "memory");
    __builtin_amdgcn_s_barrier();

    int cur=0;
    for (int t=0;t<NT;++t){
        if (t+3<NT) STAGE((cur+3)&3, t+3);
        const char* Ab=(const char*)As[cur];
        const char* Bb=(const char*)Bs[cur];
        bf16x8 af[2], bfv[4];
        #pragma unroll
        for (int i=0;i<2;++i) af[i]=*(const bf16x8*)(Ab + aoff[i]);
        #pragma unroll
        for (int j=0;j<4;++j) bfv[j]=*(const bf16x8*)(Bb + boff[j]);
        #pragma unroll
        for (int i=0;i<2;++i)
            #pragma unroll
            for (int j=0;j<4;++j)
                acc[i][j]=__builtin_amdgcn_mfma_f32_16x16x32_bf16(af[i],bfv[j],acc[i][j],0,0,0);
        if      (t+3<NT) asm volatile("s_waitcnt vmcnt(6)" ::: "memory");
        else if (t+2<NT) asm volatile("s_waitcnt vmcnt(3)" ::: "memory");
        else             asm volatile("s_waitcnt vmcnt(0)" ::: "memory");
        __builtin_amdgcn_s_barrier();
        cur=(cur+1)&3;
    }
#undef STAGE

    // epilogue
    int row_b = m0 + 32*wr + g*4;
    int col_b = d0 + 64*wc + c;
    #pragma unroll
    for (int i=0;i<2;++i){
        #pragma unroll
        for (int q=0;q<4;++q){
            int m = row_b + 16*i + q;
            if (m < NN){
                size_t rb = ((size_t)b*NN+m)*DD;
                size_t fr = ((size_t)b*NN+m)*TOT;
                #pragma unroll
                for (int j=0;j<4;++j){
                    int d = col_b + j*16;
                    float nv = h[rb+d] + acc[i][j][q] + sb[16*j+c];
                    if (write_h) h[rb+d] = nv;
                    if (h16) h16[fr+d] = __float2bfloat16(nv);
                }
            }
        }
    }
}

// ---------------- head GEMM: out = feats16 @ hw16^T + hb ----------------
__global__ __launch_bounds__(256) void k_head_mfma(
    const __hip_bfloat16* __restrict__ feats, const __hip_bfloat16* __restrict__ hw16,
    const float* __restrict__ hb, float* __restrict__ out)
{
    int tid=threadIdx.x, lane=tid&63, w=tid>>6;
    int g=lane>>4, c=lane&15;
    int m0=blockIdx.x*32;
    int rt=w>>1, pt=w&1;
    int arow = m0 + rt*16 + c;
    if (arow > BB*NN-1) arow = BB*NN-1;
    const char* abase = (const char*)feats + (size_t)arow*TOT*2 + g*16;
    const char* bbase = (const char*)hw16 + (size_t)(pt*16+c)*TOT*2 + g*16;
    f32x4 acc=(f32x4){0.f,0.f,0.f,0.f};
    #pragma unroll 4
    for (int kc=0;kc<TOT/32;++kc){
        bf16x8 af =*(const bf16x8*)(abase + (size_t)kc*64);
        bf16x8 bf2=*(const bf16x8*)(bbase + (size_t)kc*64);
        acc=__builtin_amdgcn_mfma_f32_16x16x32_bf16(af,bf2,acc,0,0,0);
    }
    int col = pt*16 + c;
    #pragma unroll
    for (int q=0;q<4;++q){
        int row = m0 + rt*16 + g*4 + q;
        if (row < BB*NN && col < PP)
            out[(size_t)row*PP + col] = acc[q] + hb[col];
    }
}

extern "C" void kernel_launch(void* const* d_in, const int* in_sizes, int n_in,
                              void* d_out, int out_size, void* d_ws, size_t ws_size,
                              hipStream_t stream)
{
    const float* x      = (const float*)d_in[0];
    const float* xfut   = (const float*)d_in[1];
    const float* adj    = (const float*)d_in[2];
    const float* fp_w   = (const float*)d_in[3];
    const float* fp_b   = (const float*)d_in[4];
    const float* inlng  = (const float*)d_in[5];
    const float* inlnb  = (const float*)d_in[6];
    const float* q_w    = (const float*)d_in[7];
    const float* q_b    = (const float*)d_in[8];
    const float* k_w    = (const float*)d_in[9];
    const float* k_b    = (const float*)d_in[10];
    const float* nemb   = (const float*)d_in[11];
    const float* galpha = (const float*)d_in[12];
    const float* wk     = (const float*)d_in[13];
    const float* mk     = (const float*)d_in[14];
    const float* lncg   = (const float*)d_in[15];
    const float* lncb   = (const float*)d_in[16];
    const float* lntg   = (const float*)d_in[17];
    const float* lntb   = (const float*)d_in[18];
    const float* lnfg   = (const float*)d_in[19];
    const float* lnfb   = (const float*)d_in[20];
    const float* lnsg   = (const float*)d_in[21];
    const float* lnsb   = (const float*)d_in[22];
    const float* tw     = (const float*)d_in[23];
    const float* tb     = (const float*)d_in[24];
    const float* fw     = (const float*)d_in[25];
    const float* fb     = (const float*)d_in[26];
    const float* sw     = (const float*)d_in[27];
    const float* sb     = (const float*)d_in[28];
    const float* futw   = (const float*)d_in[29];
    const float* futb   = (const float*)d_in[30];
    const float* hw     = (const float*)d_in[31];
    const float* hb     = (const float*)d_in[32];
    (void)in_sizes; (void)n_in; (void)out_size; (void)ws_size;
    float* out = (float*)d_out;
    float* ws = (float*)d_ws;
    const size_t HSZ = (size_t)BB*NN*SS*HH;

    float* h    = ws;
    float* embn = h + HSZ;
    float* ctx  = embn + (size_t)NN*HH;
    __hip_bfloat16* xpb   = (__hip_bfloat16*)(ctx + (size_t)BB*NN*HH);
    __hip_bfloat16* combh = xpb + HSZ;
    __hip_bfloat16* xpg   = combh + (size_t)BB*MP*KP;
    float* scores = (float*)xpg;   // aliased: scores dead before xpg is written
    unsigned short* wimg  = (unsigned short*)(xpg + (size_t)BB*(KP/8)*(size_t)DD*8);
    unsigned short* qpack = wimg + (size_t)NBLK*WIMG_SZ;
    unsigned short* kpack = qpack + (size_t)BB*8*MP*8;
    __hip_bfloat16* feats16 = (__hip_bfloat16*)(kpack + (size_t)BB*8*MP*8);
    __hip_bfloat16* hw16    = feats16 + (size_t)BB*NN*TOT;

    k_prepw<<<NBLK,256,0,stream>>>(wk, mk, tw, fw, sw, wimg);
    k_prep_head<<<(32*TOT)/256,256,0,stream>>>(hw, hw16);
    k_fut<<<BB*NN,256,0,stream>>>(xfut, futw, futb, feats16);
    k_embnorm<<<NN,64,0,stream>>>(nemb, embn);
    k_front<<<BB*NN,256,0,stream>>>(x, fp_w, fp_b, inlng, inlnb, embn, h, ctx);
    k_qk<<<BB*NN,64,0,stream>>>(ctx, q_w,q_b,k_w,k_b, qpack, kpack);
    dim3 gqkt(MP/128, MP/128, BB);
    k_qkt<<<gqkt,256,0,stream>>>(qpack, kpack, scores);
    dim3 gtop(NN,BB);
    k_topk<<<gtop,256,0,stream>>>(scores, adj, galpha, combh);
    dim3 gpack(DD/256, KP/8, BB);
    for (int i=0;i<NBLK;++i){
        k_mixer2<<<BB*NN,256,0,stream>>>(h, xpb, wimg + (size_t)i*WIMG_SZ,
            lncg+i*HH,lncb+i*HH, lntg+i*HH,lntb+i*HH, lnfg+i*HH,lnfb+i*HH, lnsg+i*HH,lnsb+i*HH,
            tb+i*SS, fb+i*HH);
        k_pack_xp<<<gpack,256,0,stream>>>(xpb, xpg);
        k_bmm_mfma<<<2688,256,0,stream>>>(combh, xpg, sb+i*HH, h,
            (i==NBLK-1) ? feats16 : (__hip_bfloat16*)nullptr,
            (i==NBLK-1) ? 0 : 1);
    }
    k_head_mfma<<<(BB*NN+31)/32,256,0,stream>>>(feats16, hw16, hb, out);
}

// Round 9
// 660.083 us; speedup vs baseline: 1.1363x; 1.1363x over previous
//
#include <hip/hip_runtime.h>
#include <hip/hip_bf16.h>
#include <math.h>

#define BB 4
#define NN 1437
#define SS 56
#define PP 28
#define FIN 10
#define FFUT 6
#define HH 64
#define NBLK 2
#define TOPK 5
#define DD (SS*HH)     /* 3584 */
#define FD (PP*HH)     /* 1792 */
#define TOT (DD+FD)    /* 5376 */
#define MP 1536        /* padded M (12*128) */
#define KP 1472        /* padded K (46*32)  */
#define NT (KP/32)     /* 46 K-steps */
#define SP 1536        /* scores stride */
#define WIMG_SZ 16384  /* shorts per mixer-block weight image */

typedef __attribute__((ext_vector_type(8))) __bf16 bf16x8;
typedef __attribute__((ext_vector_type(4))) float  f32x4;

// h lives in a permuted intra-row layout: element (s,f) at s*64 + (f&15)*4 + (f>>4).
// Consumers: k_front (write), k_mixer2 (rw), k_bmm_mfma (rw). All use this layout.

__device__ __forceinline__ float gelu_exact(float x){
    return 0.5f*x*(1.0f+erff(x*0.70710678118654752440f));
}
__device__ __forceinline__ float wave_sum64(float v){
    #pragma unroll
    for (int o=1;o<64;o<<=1) v += __shfl_xor(v,o,64);
    return v;
}
__device__ __forceinline__ void async_load16(const void* g, void* l){
    __builtin_amdgcn_global_load_lds(
        (const __attribute__((address_space(1))) void*)g,
        (__attribute__((address_space(3))) void*)l, 16, 0, 0);
}
__device__ __forceinline__ unsigned short f2bf(float x){
    unsigned int u = __float_as_uint(x);
    unsigned int r = (u + 0x7fffu + ((u>>16)&1u)) >> 16;
    return (unsigned short)r;
}
__device__ __forceinline__ unsigned long long umax64(unsigned long long a, unsigned long long b){return a>b?a:b;}
__device__ __forceinline__ unsigned long long umin64(unsigned long long a, unsigned long long b){return a<b?a:b;}

// ---------------- emb norm ----------------
__global__ __launch_bounds__(64) void k_embnorm(const float* __restrict__ emb,
                                                float* __restrict__ out){
    int n = blockIdx.x; int l = threadIdx.x;
    float v = emb[(size_t)n*HH+l];
    float ss = wave_sum64(v*v);
    float nrm = fmaxf(sqrtf(ss), 1e-12f);
    out[(size_t)n*HH+l] = v/nrm;
}

// ------- front: h = LN(x@fp_w^T+fp_b)+embn ; ctx = recency ctx -------
__global__ __launch_bounds__(256) void k_front(
    const float* __restrict__ x, const float* __restrict__ fpw, const float* __restrict__ fpb,
    const float* __restrict__ lng, const float* __restrict__ lnb,
    const float* __restrict__ embn, float* __restrict__ h, float* __restrict__ ctx)
{
    int bn = blockIdx.x; int n = bn % NN;
    int tid=threadIdx.x; int lane=tid&63; int wv=tid>>6;
    __shared__ float xin[SS*FIN];
    __shared__ float wlds[HH*FIN];
    __shared__ float rw[SS];
    __shared__ float rsum;
    __shared__ float red[4][HH];
    for (int i=tid;i<SS*FIN;i+=256) xin[i]=x[(size_t)bn*SS*FIN+i];
    for (int i=tid;i<HH*FIN;i+=256) wlds[i]=fpw[i];
    if (tid<SS) rw[tid]=expf(-(float)(SS-tid)/14.0f);
    __syncthreads();
    if (tid==0){ float s=0.f; for(int i=0;i<SS;++i) s+=rw[i]; rsum=s; }
    __syncthreads();
    float inv_rs = 1.0f/rsum;
    float gg=lng[lane], bv=lnb[lane], el=embn[(size_t)n*HH+lane], fb0=fpb[lane];
    int paddr = (lane&15)*4 + (lane>>4);
    float cacc=0.f;
    for (int s=wv;s<SS;s+=4){
        float v=fb0;
        #pragma unroll
        for (int c=0;c<FIN;++c) v += xin[s*FIN+c]*wlds[lane*FIN+c];
        float m = wave_sum64(v)*(1.f/HH);
        float d = v-m;
        float va = wave_sum64(d*d)*(1.f/HH);
        float hn = d*rsqrtf(va+1e-5f)*gg + bv + el;
        h[((size_t)bn*SS+s)*HH + paddr]=hn;
        cacc += hn * rw[s]*inv_rs;
    }
    red[wv][lane]=cacc;
    __syncthreads();
    if (wv==0) ctx[(size_t)bn*HH+lane]=red[0][lane]+red[1][lane]+red[2][lane]+red[3][lane];
}

// ---------------- Q/K projections -> K-packed bf16 [b][8][MP][8] ----------------
__global__ __launch_bounds__(64) void k_qk(
    const float* __restrict__ ctx, const float* __restrict__ qw, const float* __restrict__ qb,
    const float* __restrict__ kw, const float* __restrict__ kb,
    unsigned short* __restrict__ qpack, unsigned short* __restrict__ kpack)
{
    __shared__ float wq[HH*65];
    __shared__ float wk2[HH*65];
    int lane=threadIdx.x; int bn=blockIdx.x;
    for (int i=lane;i<HH*HH;i+=64){ int hh=i>>6, kk=i&63; wq[kk*65+hh]=qw[i]; wk2[kk*65+hh]=kw[i]; }
    __syncthreads();
    const float* c = ctx + (size_t)bn*HH;
    float q=qb[lane], k=kb[lane];
    for (int kk=0;kk<HH;++kk){ float cv=c[kk]; q+=cv*wq[kk*65+lane]; k+=cv*wk2[kk*65+lane]; }
    int b = bn/NN, m = bn%NN;
    size_t off = (size_t)b*8*MP*8 + (size_t)(lane>>3)*MP*8 + (size_t)m*8 + (lane&7);
    qpack[off]=f2bf(q); kpack[off]=f2bf(k);
}

// ---------------- QK^T via MFMA -> scores = relu(clip(QK^T/8)) f32 ----------------
__global__ __launch_bounds__(256) void k_qkt(
    const unsigned short* __restrict__ qp, const unsigned short* __restrict__ kp,
    float* __restrict__ scores)
{
    int bm=blockIdx.x, bnn=blockIdx.y, b=blockIdx.z;
    int tid=threadIdx.x, lane=tid&63, wv=tid>>6;
    int g=lane>>4, c15=lane&15;
    int m0=bm*128, n0=bnn*128;
    __shared__ unsigned short As[8192];  // [8][128][8]
    __shared__ unsigned short Bs[8192];
    const char* qbase = (const char*)(qp + (size_t)b*8*MP*8);
    const char* kbase = (const char*)(kp + (size_t)b*8*MP*8);
    #pragma unroll
    for (int i=0;i<4;++i){
        int idx=i*256+tid; int ch=idx>>7, r=idx&127;
        async_load16(qbase + ((size_t)(ch*MP + m0 + r))*16, (char*)As + idx*16);
        async_load16(kbase + ((size_t)(ch*MP + n0 + r))*16, (char*)Bs + idx*16);
    }
    asm volatile("s_waitcnt vmcnt(0)");
    __syncthreads();
    int wr=wv>>1, wc=wv&1;
    f32x4 acc[4][4];
    #pragma unroll
    for (int i=0;i<4;++i)
        #pragma unroll
        for (int j=0;j<4;++j) acc[i][j]=(f32x4){0.f,0.f,0.f,0.f};
    #pragma unroll
    for (int kc=0;kc<2;++kc){
        bf16x8 af[4], bfv[4];
        #pragma unroll
        for (int i=0;i<4;++i)
            af[i]=*(const bf16x8*)((const char*)As + ((4*kc+g)*128 + wr*64+i*16+c15)*16);
        #pragma unroll
        for (int j=0;j<4;++j)
            bfv[j]=*(const bf16x8*)((const char*)Bs + ((4*kc+g)*128 + wc*64+j*16+c15)*16);
        #pragma unroll
        for (int i=0;i<4;++i)
            #pragma unroll
            for (int j=0;j<4;++j)
                acc[i][j]=__builtin_amdgcn_mfma_f32_16x16x32_bf16(af[i],bfv[j],acc[i][j],0,0,0);
    }
    #pragma unroll
    for (int i=0;i<4;++i){
        #pragma unroll
        for (int q=0;q<4;++q){
            int m = m0 + wr*64 + i*16 + g*4 + q;
            float* sr = scores + ((size_t)b*SP + m)*SP + n0 + wc*64 + c15;
            #pragma unroll
            for (int j=0;j<4;++j){
                float v = acc[i][j][q]*0.125f;
                v = fminf(fmaxf(v,0.f),10.f);
                sr[j*16]=v;
            }
        }
    }
}

// ---- top-5 + softmax + blend + L1 normalize -> comb bf16 [b][MP][KP] ----
#define INS(x) do{ unsigned long long t_=(x); \
    unsigned long long n0_=umax64(u0,t_), t1_=umin64(u0,t_); \
    unsigned long long n1_=umax64(u1,t1_), t2_=umin64(u1,t1_); \
    unsigned long long n2_=umax64(u2,t2_), t3_=umin64(u2,t2_); \
    unsigned long long n3_=umax64(u3,t3_), t4_=umin64(u3,t3_); \
    unsigned long long n4_=umax64(u4,t4_); \
    u0=n0_;u1=n1_;u2=n2_;u3=n3_;u4=n4_; }while(0)

#define MERGE(b0,b1,b2,b3,b4) do{ \
    unsigned long long o0_=umax64(u0,(b0)); \
    unsigned long long o1_=umax64(umax64((b1),umin64(u0,(b0))),u1); \
    unsigned long long o2_=umax64(umax64((b2),umin64(u0,(b1))),umax64(umin64(u1,(b0)),u2)); \
    unsigned long long o3_=umax64(umax64((b3),umin64(u0,(b2))),umax64(umin64(u1,(b1)),umax64(umin64(u2,(b0)),u3))); \
    unsigned long long o4_=umax64(umax64((b4),umin64(u0,(b3))),umax64(umax64(umin64(u1,(b2)),umin64(u2,(b1))),umax64(umin64(u3,(b0)),u4))); \
    u0=o0_;u1=o1_;u2=o2_;u3=o3_;u4=o4_; }while(0)

__global__ __launch_bounds__(256) void k_topk(
    const float* __restrict__ scores, const float* __restrict__ adj,
    const float* __restrict__ galpha, __hip_bfloat16* __restrict__ combh)
{
    int m=blockIdx.x, b=blockIdx.y, tid=threadIdx.x, lane=tid&63, wv=tid>>6;
    __shared__ float row[KP];
    __shared__ unsigned long long wtop[4][8];
    __shared__ float redp[4];
    const float* srow = scores + ((size_t)b*SP + m)*SP;
    unsigned long long u0=0,u1=0,u2=0,u3=0,u4=0;
    for (int n=tid;n<NN;n+=256){
        float v=srow[n];
        unsigned long long key=((unsigned long long)__float_as_uint(v)<<32)|(unsigned long long)(0xFFFFFFFFu-(unsigned)n);
        INS(key);
    }
    #pragma unroll
    for (int off=1; off<64; off<<=1){
        unsigned long long b0=__shfl_xor(u0,off,64), b1=__shfl_xor(u1,off,64),
                           b2=__shfl_xor(u2,off,64), b3=__shfl_xor(u3,off,64),
                           b4=__shfl_xor(u4,off,64);
        MERGE(b0,b1,b2,b3,b4);
    }
    if (lane==0){ wtop[wv][0]=u0; wtop[wv][1]=u1; wtop[wv][2]=u2; wtop[wv][3]=u3; wtop[wv][4]=u4; }
    __syncthreads();
    u0=wtop[0][0]; u1=wtop[0][1]; u2=wtop[0][2]; u3=wtop[0][3]; u4=wtop[0][4];
    #pragma unroll
    for (int w2=1;w2<4;++w2)
        MERGE(wtop[w2][0],wtop[w2][1],wtop[w2][2],wtop[w2][3],wtop[w2][4]);

    float s0=__uint_as_float((unsigned)(u0>>32)), s1=__uint_as_float((unsigned)(u1>>32)),
          s2=__uint_as_float((unsigned)(u2>>32)), s3=__uint_as_float((unsigned)(u3>>32)),
          s4=__uint_as_float((unsigned)(u4>>32));
    int i0=(int)(0xFFFFFFFFu-(unsigned)u0), i1=(int)(0xFFFFFFFFu-(unsigned)u1),
        i2=(int)(0xFFFFFFFFu-(unsigned)u2), i3=(int)(0xFFFFFFFFu-(unsigned)u3),
        i4=(int)(0xFFFFFFFFu-(unsigned)u4);
    float e0=1.f, e1=expf(s1-s0), e2=expf(s2-s0), e3=expf(s3-s0), e4=expf(s4-s0);
    float den=e0+e1+e2+e3+e4;
    float alpha=1.f/(1.f+expf(-galpha[0]));
    float oma=(1.f-alpha)/den;
    float p0=oma*e0, p1=oma*e1, p2=oma*e2, p3=oma*e3, p4=oma*e4;

    const float* arow = adj + (size_t)m*NN;
    float part=0.f;
    for (int n=tid;n<NN;n+=256){
        float v=alpha*arow[n];
        v += (n==i0)?p0:0.f;
        v += (n==i1)?p1:0.f;
        v += (n==i2)?p2:0.f;
        v += (n==i3)?p3:0.f;
        v += (n==i4)?p4:0.f;
        row[n]=v;
        part+=fabsf(v);
    }
    part=wave_sum64(part);
    if (lane==0) redp[wv]=part;
    __syncthreads();
    float inv=1.f/fmaxf(redp[0]+redp[1]+redp[2]+redp[3],1e-12f);
    __hip_bfloat16* dst = combh + ((size_t)b*MP+m)*KP;
    for (int n=tid;n<KP;n+=256){
        float v = (n<NN) ? row[n]*inv : 0.f;
        dst[n]=__float2bfloat16(v);
    }
}
#undef INS
#undef MERGE

// ---- prep: build per-mixer-block bf16 weight images ----
__global__ __launch_bounds__(256) void k_prepw(
    const float* __restrict__ wk, const float* __restrict__ mk,
    const float* __restrict__ tw, const float* __restrict__ fw,
    const float* __restrict__ sw, unsigned short* __restrict__ wimg)
{
    int i = blockIdx.x; int tid = threadIdx.x;
    const float* wki = wk + i*7;
    const float* mki = mk + i*28;
    const float* twi = tw + i*SS*SS;
    const float* fwi = fw + i*HH*HH;
    const float* swi = sw + i*HH*HH;
    unsigned short* o = wimg + (size_t)i*WIMG_SZ;
    for (int e=tid; e<4096; e+=256){
        int r = e>>6, k = e&63;
        int swz = ((k*2) ^ ((r&7)<<4)) >> 1;
        float mv = 0.f;
        if (r<SS && k<SS){
            int a = k-r+3;  if (a>=0 && a<7)  mv += wki[a];
            int b2= k-r+13; if (b2>=0 && b2<28) mv += mki[b2];
        }
        o[r*64 + swz] = f2bf(mv);
        float tv = (r<SS && k<SS) ? twi[r*SS+k] : 0.f;
        o[4096 + r*64 + swz] = f2bf(tv);
        int pk = (k>>3)*512 + r*8 + (k&7);
        o[8192  + pk] = f2bf(fwi[r*HH+k]);
        o[12288 + pk] = f2bf(swi[r*HH+k]);
    }
}

// ---- prep: head_w f32 [28][5376] -> bf16 [32][5376] (pad rows zero) ----
__global__ __launch_bounds__(256) void k_prep_head(
    const float* __restrict__ hw, __hip_bfloat16* __restrict__ hw16)
{
    int i = blockIdx.x*256 + threadIdx.x;   // 32*TOT total
    int r = i / TOT, k = i - r*TOT;
    float v = (r<PP) ? hw[(size_t)r*TOT + k] : 0.f;
    hw16[i] = __float2bfloat16(v);
}

// ---- fut: feats16[bn][3584+q] = bf16(x_future @ futw^T + futb) ----
__global__ __launch_bounds__(256) void k_fut(
    const float* __restrict__ xf, const float* __restrict__ fw,
    const float* __restrict__ fbias, __hip_bfloat16* __restrict__ feats)
{
    int bn=blockIdx.x, tid=threadIdx.x;
    __shared__ float fwl[HH*FFUT];
    __shared__ float fbl[HH];
    __shared__ float xfl[PP*FFUT];
    for (int i=tid;i<HH*FFUT;i+=256) fwl[i]=fw[i];
    if (tid<HH) fbl[tid]=fbias[tid];
    for (int i=tid;i<PP*FFUT;i+=256) xfl[i]=xf[(size_t)bn*PP*FFUT+i];
    __syncthreads();
    __hip_bfloat16* dst = feats + (size_t)bn*TOT + DD;
    for (int q=tid;q<FD;q+=256){
        int pp=q>>6, hh2=q&63;
        float v=fbl[hh2];
        #pragma unroll
        for (int c2=0;c2<FFUT;++c2) v += xfl[pp*FFUT+c2]*fwl[hh2*FFUT+c2];
        dst[q]=__float2bfloat16(v);
    }
}

// ---------------- MFMA mixer block (h in permuted layout) ----------------
__global__ __launch_bounds__(256) void k_mixer2(
    float* __restrict__ h, __hip_bfloat16* __restrict__ xpb,
    const unsigned short* __restrict__ wimg,
    const float* __restrict__ lncg, const float* __restrict__ lncb,
    const float* __restrict__ lntg, const float* __restrict__ lntb,
    const float* __restrict__ lnfg, const float* __restrict__ lnfb,
    const float* __restrict__ lnsg, const float* __restrict__ lnsb,
    const float* __restrict__ tb, const float* __restrict__ fb)
{
    int bn=blockIdx.x, tid=threadIdx.x, lane=tid&63, w=tid>>6;
    int g=lane>>4, c=lane&15;
    __shared__ unsigned short wbuf[4][4096];
    __shared__ unsigned short xs[4096];
    __shared__ float prm[640];

    const char* wsrc=(const char*)wimg;
    char* wdst=(char*)&wbuf[0][0];
    #pragma unroll
    for (int i=0;i<8;++i)
        async_load16(wsrc+((size_t)(i*256+tid))*16, wdst+(i*256+w*64)*16);
    if (tid<64){
        prm[tid]      =lncg[tid]; prm[64+tid] =lncb[tid];
        prm[128+tid]  =lntg[tid]; prm[192+tid]=lntb[tid];
        prm[256+tid]  =lnfg[tid]; prm[320+tid]=lnfb[tid];
        prm[384+tid]  =lnsg[tid]; prm[448+tid]=lnsb[tid];
        prm[512+tid]  =(tid<SS)?tb[tid]:0.f;
        prm[576+tid]  =fb[tid];
    }
    float xl[4][4];
    float* hb = h + (size_t)bn*DD;
    int srow = 16*w + 4*g;
    #pragma unroll
    for (int q=0;q<4;++q){
        int s=srow+q;
        if (s<SS){
            const float4 v4 = *reinterpret_cast<const float4*>(hb + s*HH + c*4);
            xl[q][0]=v4.x; xl[q][1]=v4.y; xl[q][2]=v4.z; xl[q][3]=v4.w;
        } else {
            xl[q][0]=0.f; xl[q][1]=0.f; xl[q][2]=0.f; xl[q][3]=0.f;
        }
    }
    __syncthreads();

    float xn[4][4];
    f32x4 acc[4];

#define LNSTAGE(GOFF,BOFF) do{ \
    _Pragma("unroll") \
    for (int q=0;q<4;++q){ \
        float sv = xl[q][0]+xl[q][1]+xl[q][2]+xl[q][3]; \
        float s2 = xl[q][0]*xl[q][0]+xl[q][1]*xl[q][1]+xl[q][2]*xl[q][2]+xl[q][3]*xl[q][3]; \
        _Pragma("unroll") \
        for (int m2=1;m2<16;m2<<=1){ sv += __shfl_xor(sv,m2,64); s2 += __shfl_xor(s2,m2,64); } \
        float mn = sv*(1.f/64.f); \
        float var = s2*(1.f/64.f)-mn*mn; \
        float rstd = rsqrtf(var+1e-5f); \
        bool ok = (srow+q)<SS; \
        _Pragma("unroll") \
        for (int tj=0;tj<4;++tj){ \
            float v=(xl[q][tj]-mn)*rstd*prm[(GOFF)+tj*16+c]+prm[(BOFF)+tj*16+c]; \
            xn[q][tj]= ok ? v : 0.f; \
        } \
    } }while(0)

#define WRITE_XNP() do{ \
    _Pragma("unroll") \
    for (int qp=0;qp<2;++qp){ \
        int s0=srow+2*qp; \
        _Pragma("unroll") \
        for (int tj=0;tj<4;++tj){ \
            unsigned int pv=(unsigned int)f2bf(xn[2*qp][tj])|((unsigned int)f2bf(xn[2*qp+1][tj])<<16); \
            *(unsigned int*)((char*)xs + ((s0>>3)*1024 + (tj*16+c)*16 + (s0&7)*2)) = pv; \
        } \
    } }while(0)

#define WRITE_XNR() do{ \
    _Pragma("unroll") \
    for (int q=0;q<4;++q){ int s=srow+q; \
        _Pragma("unroll") \
        for (int tj=0;tj<4;++tj){ \
            *(unsigned short*)((char*)xs + s*128 + (((tj*16+c)*2) ^ ((s&7)<<4))) = f2bf(xn[q][tj]); \
        } \
    } }while(0)

#define MM(APTR,BPTR) do{ \
    _Pragma("unroll") \
    for (int tj=0;tj<4;++tj) acc[tj]=(f32x4){0.f,0.f,0.f,0.f}; \
    _Pragma("unroll") \
    for (int kc=0;kc<2;++kc){ \
        int arow=16*w+c; \
        bf16x8 af=*(const bf16x8*)((const char*)(APTR)+arow*128+((kc*64+g*16)^((arow&7)<<4))); \
        _Pragma("unroll") \
        for (int tj=0;tj<4;++tj){ \
            bf16x8 bf2=*(const bf16x8*)((const char*)(BPTR)+(kc*4+g)*1024+(tj*16+c)*16); \
            acc[tj]=__builtin_amdgcn_mfma_f32_16x16x32_bf16(af,bf2,acc[tj],0,0,0); \
        } \
    } }while(0)

    LNSTAGE(0,64); WRITE_XNP();
    __syncthreads();
    MM(&wbuf[0][0], xs);
    #pragma unroll
    for (int q=0;q<4;++q)
        #pragma unroll
        for (int tj=0;tj<4;++tj) xl[q][tj]+=acc[tj][q];
    __syncthreads();
    LNSTAGE(128,192); WRITE_XNP();
    __syncthreads();
    MM(&wbuf[1][0], xs);
    #pragma unroll
    for (int q=0;q<4;++q){
        float tbv=prm[512+srow+q];
        #pragma unroll
        for (int tj=0;tj<4;++tj) xl[q][tj]+=gelu_exact(acc[tj][q]+tbv);
    }
    __syncthreads();
    LNSTAGE(256,320); WRITE_XNR();
    __syncthreads();
    MM(xs, &wbuf[2][0]);
    #pragma unroll
    for (int q=0;q<4;++q)
        #pragma unroll
        for (int tj=0;tj<4;++tj) xl[q][tj]+=gelu_exact(acc[tj][q]+prm[576+tj*16+c]);
    __syncthreads();
    LNSTAGE(384,448); WRITE_XNR();
    __syncthreads();
    MM(xs, &wbuf[3][0]);
    __hip_bfloat16* xpo = xpb + (size_t)bn*DD;
    #pragma unroll
    for (int q=0;q<4;++q){
        int s=srow+q;
        if (s<SS){
            float4 hv; hv.x=xl[q][0]; hv.y=xl[q][1]; hv.z=xl[q][2]; hv.w=xl[q][3];
            *reinterpret_cast<float4*>(hb + s*HH + c*4) = hv;
            #pragma unroll
            for (int tj=0;tj<4;++tj)
                xpo[s*HH + tj*16 + c]=__float2bfloat16(acc[tj][q]);
        }
    }
#undef LNSTAGE
#undef WRITE_XNP
#undef WRITE_XNR
#undef MM
}

// ---- pack xp bf16 [N][D] -> MFMA-ready [KP/8][D][8], coalesced via LDS transpose ----
__global__ __launch_bounds__(256) void k_pack_xp(
    const __hip_bfloat16* __restrict__ xpb, __hip_bfloat16* __restrict__ xpg)
{
    __shared__ unsigned short t8[8*256];   // [e][d] 4KB
    int dblk=blockIdx.x, kc=blockIdx.y, b=blockIdx.z;
    int tid=threadIdx.x;
    int r=tid>>5, l=tid&31;
    int k=kc*8+r;
    if (k<NN){
        async_load16((const char*)xpb + (((size_t)b*NN+k)*DD + dblk*256 + l*8)*2,
                     (char*)t8 + tid*16);
    } else {
        uint4 z; z.x=0; z.y=0; z.z=0; z.w=0;
        *reinterpret_cast<uint4*>((char*)t8 + tid*16) = z;
    }
    asm volatile("s_waitcnt vmcnt(0)");
    __syncthreads();
    union { unsigned short v[8]; float4 f4; } u;
    #pragma unroll
    for (int e=0;e<8;++e) u.v[e]=t8[e*256+tid];
    *reinterpret_cast<float4*>(xpg + (((size_t)b*(KP/8)+kc)*DD + dblk*256 + tid)*8) = u.f4;
}

// ---- spatial bmm via MFMA: h[b] += comb[b] @ xp[b] + sb ----
// 64x128 tile, 4 waves (2x2 of 32x64), 3-buffer depth-2 prefetch, counted vmcnt.
// h accessed in permuted layout (float4 per thread).
__global__ __launch_bounds__(256,4) void k_bmm_mfma(
    const __hip_bfloat16* __restrict__ combh,
    const __hip_bfloat16* __restrict__ xpg,
    const float* __restrict__ sb,
    float* __restrict__ h,
    __hip_bfloat16* __restrict__ h16,
    int write_h)
{
    __shared__ short As[3][2048];   // [64][32] bf16 per buf (A-swizzled)
    __shared__ short Bs[3][4096];   // [4][128][8] per buf

    int bid = blockIdx.x;
    int wg = (bid & 7)*336 + (bid >> 3);     // bijective XCD-chunked swizzle (2688 = 8*336)
    int bm = wg % 24; int tmp2 = wg / 24; int bd = tmp2 % 28; int b = tmp2 / 28;
    int tid=threadIdx.x, lane=tid&63, w=tid>>6;
    int g=lane>>4, c=lane&15;
    int wr=w>>1, wc=w&1;
    int m0=bm*64, d0=bd*128;

    const char* cb = (const char*)(combh + (size_t)b*MP*KP);
    const char* xb = (const char*)(xpg   + (size_t)b*(KP/8)*(size_t)DD*8);

    int arow_s = tid>>2, aslot = tid&3;
    int ag = aslot ^ ((arow_s>>1)&3);
    const char* srcA = cb + ((size_t)(m0+arow_s)*KP + ag*8)*2;
    int bch = tid>>7, bcol = tid&127;
    const char* srcB0 = xb + ((size_t)bch*DD + d0 + bcol)*16;
    const char* srcB1 = xb + ((size_t)(bch+2)*DD + d0 + bcol)*16;
    const size_t BSTEP = (size_t)4*DD*16;

    f32x4 acc[2][4];
    #pragma unroll
    for (int i=0;i<2;++i)
        #pragma unroll
        for (int j=0;j<4;++j) acc[i][j]=(f32x4){0.f,0.f,0.f,0.f};

    int aoff[2], boff[4];
    #pragma unroll
    for (int i=0;i<2;++i){
        int row = 32*wr + 16*i + c;
        aoff[i] = row*64 + ((g*16) ^ (((row>>1)&3)<<4));
    }
    #pragma unroll
    for (int j=0;j<4;++j) boff[j] = (g*128 + 64*wc + 16*j + c)*16;

#define STAGE(BUF,T) do { \
    async_load16(srcA  + (size_t)(T)*64,    (char*)As[BUF] + w*1024); \
    async_load16(srcB0 + (size_t)(T)*BSTEP, (char*)Bs[BUF] + w*1024); \
    async_load16(srcB1 + (size_t)(T)*BSTEP, (char*)Bs[BUF] + 4096 + w*1024); } while(0)

    STAGE(0,0); STAGE(1,1);
    asm volatile("s_waitcnt vmcnt(3)" ::: "memory");
    __builtin_amdgcn_s_barrier();

    int cur=0;
    for (int t=0;t<NT;++t){
        if (t+2<NT){
            int nb = cur+2; if (nb>=3) nb-=3;
            STAGE(nb, t+2);
        }
        const char* Ab=(const char*)As[cur];
        const char* Bb=(const char*)Bs[cur];
        bf16x8 af[2], bfv[4];
        #pragma unroll
        for (int i=0;i<2;++i) af[i]=*(const bf16x8*)(Ab + aoff[i]);
        #pragma unroll
        for (int j=0;j<4;++j) bfv[j]=*(const bf16x8*)(Bb + boff[j]);
        #pragma unroll
        for (int i=0;i<2;++i)
            #pragma unroll
            for (int j=0;j<4;++j)
                acc[i][j]=__builtin_amdgcn_mfma_f32_16x16x32_bf16(af[i],bfv[j],acc[i][j],0,0,0);
        if (t+2<NT) asm volatile("s_waitcnt vmcnt(3)" ::: "memory");
        else        asm volatile("s_waitcnt vmcnt(0)" ::: "memory");
        __builtin_amdgcn_s_barrier();
        ++cur; if (cur>=3) cur=0;
    }
#undef STAGE

    // epilogue: h is permuted ( (s,f) at s*64 + (f&15)*4 + (f>>4) ); here f = 16j+c
    int row_b = m0 + 32*wr + g*4;
    int s2 = 2*bd + wc;
    float sb0=sb[c], sb1=sb[16+c], sb2=sb[32+c], sb3=sb[48+c];
    #pragma unroll
    for (int i=0;i<2;++i){
        #pragma unroll
        for (int q=0;q<4;++q){
            int m = row_b + 16*i + q;
            if (m < NN){
                float* hp = h + ((size_t)b*NN+m)*DD + s2*HH + c*4;
                float4 hv = *reinterpret_cast<const float4*>(hp);
                float nv0 = hv.x + acc[i][0][q] + sb0;
                float nv1 = hv.y + acc[i][1][q] + sb1;
                float nv2 = hv.z + acc[i][2][q] + sb2;
                float nv3 = hv.w + acc[i][3][q] + sb3;
                if (write_h){
                    float4 ov; ov.x=nv0; ov.y=nv1; ov.z=nv2; ov.w=nv3;
                    *reinterpret_cast<float4*>(hp) = ov;
                }
                if (h16){
                    size_t fr = ((size_t)b*NN+m)*TOT + (size_t)bd*128 + wc*64;
                    h16[fr + c]      = __float2bfloat16(nv0);
                    h16[fr + 16 + c] = __float2bfloat16(nv1);
                    h16[fr + 32 + c] = __float2bfloat16(nv2);
                    h16[fr + 48 + c] = __float2bfloat16(nv3);
                }
            }
        }
    }
}

// ---------------- head GEMM: out = feats16 @ hw16^T + hb ----------------
__global__ __launch_bounds__(256) void k_head_mfma(
    const __hip_bfloat16* __restrict__ feats, const __hip_bfloat16* __restrict__ hw16,
    const float* __restrict__ hb, float* __restrict__ out)
{
    int tid=threadIdx.x, lane=tid&63, w=tid>>6;
    int g=lane>>4, c=lane&15;
    int m0=blockIdx.x*32;
    int rt=w>>1, pt=w&1;
    int arow = m0 + rt*16 + c;
    if (arow > BB*NN-1) arow = BB*NN-1;
    const char* abase = (const char*)feats + (size_t)arow*TOT*2 + g*16;
    const char* bbase = (const char*)hw16 + (size_t)(pt*16+c)*TOT*2 + g*16;
    f32x4 acc=(f32x4){0.f,0.f,0.f,0.f};
    #pragma unroll 4
    for (int kc=0;kc<TOT/32;++kc){
        bf16x8 af =*(const bf16x8*)(abase + (size_t)kc*64);
        bf16x8 bf2=*(const bf16x8*)(bbase + (size_t)kc*64);
        acc=__builtin_amdgcn_mfma_f32_16x16x32_bf16(af,bf2,acc,0,0,0);
    }
    int col = pt*16 + c;
    #pragma unroll
    for (int q=0;q<4;++q){
        int row = m0 + rt*16 + g*4 + q;
        if (row < BB*NN && col < PP)
            out[(size_t)row*PP + col] = acc[q] + hb[col];
    }
}

extern "C" void kernel_launch(void* const* d_in, const int* in_sizes, int n_in,
                              void* d_out, int out_size, void* d_ws, size_t ws_size,
                              hipStream_t stream)
{
    const float* x      = (const float*)d_in[0];
    const float* xfut   = (const float*)d_in[1];
    const float* adj    = (const float*)d_in[2];
    const float* fp_w   = (const float*)d_in[3];
    const float* fp_b   = (const float*)d_in[4];
    const float* inlng  = (const float*)d_in[5];
    const float* inlnb  = (const float*)d_in[6];
    const float* q_w    = (const float*)d_in[7];
    const float* q_b    = (const float*)d_in[8];
    const float* k_w    = (const float*)d_in[9];
    const float* k_b    = (const float*)d_in[10];
    const float* nemb   = (const float*)d_in[11];
    const float* galpha = (const float*)d_in[12];
    const float* wk     = (const float*)d_in[13];
    const float* mk     = (const float*)d_in[14];
    const float* lncg   = (const float*)d_in[15];
    const float* lncb   = (const float*)d_in[16];
    const float* lntg   = (const float*)d_in[17];
    const float* lntb   = (const float*)d_in[18];
    const float* lnfg   = (const float*)d_in[19];
    const float* lnfb   = (const float*)d_in[20];
    const float* lnsg   = (const float*)d_in[21];
    const float* lnsb   = (const float*)d_in[22];
    const float* tw     = (const float*)d_in[23];
    const float* tb     = (const float*)d_in[24];
    const float* fw     = (const float*)d_in[25];
    const float* fb     = (const float*)d_in[26];
    const float* sw     = (const float*)d_in[27];
    const float* sb     = (const float*)d_in[28];
    const float* futw   = (const float*)d_in[29];
    const float* futb   = (const float*)d_in[30];
    const float* hw     = (const float*)d_in[31];
    const float* hb     = (const float*)d_in[32];
    (void)in_sizes; (void)n_in; (void)out_size; (void)ws_size;
    float* out = (float*)d_out;
    float* ws = (float*)d_ws;
    const size_t HSZ = (size_t)BB*NN*SS*HH;

    float* h    = ws;
    float* embn = h + HSZ;
    float* ctx  = embn + (size_t)NN*HH;
    __hip_bfloat16* xpb   = (__hip_bfloat16*)(ctx + (size_t)BB*NN*HH);
    __hip_bfloat16* combh = xpb + HSZ;
    __hip_bfloat16* xpg   = combh + (size_t)BB*MP*KP;
    float* scores = (float*)xpg;   // aliased: scores dead before xpg is written
    unsigned short* wimg  = (unsigned short*)(xpg + (size_t)BB*(KP/8)*(size_t)DD*8);
    unsigned short* qpack = wimg + (size_t)NBLK*WIMG_SZ;
    unsigned short* kpack = qpack + (size_t)BB*8*MP*8;
    __hip_bfloat16* feats16 = (__hip_bfloat16*)(kpack + (size_t)BB*8*MP*8);
    __hip_bfloat16* hw16    = feats16 + (size_t)BB*NN*TOT;

    k_prepw<<<NBLK,256,0,stream>>>(wk, mk, tw, fw, sw, wimg);
    k_prep_head<<<(32*TOT)/256,256,0,stream>>>(hw, hw16);
    k_fut<<<BB*NN,256,0,stream>>>(xfut, futw, futb, feats16);
    k_embnorm<<<NN,64,0,stream>>>(nemb, embn);
    k_front<<<BB*NN,256,0,stream>>>(x, fp_w, fp_b, inlng, inlnb, embn, h, ctx);
    k_qk<<<BB*NN,64,0,stream>>>(ctx, q_w,q_b,k_w,k_b, qpack, kpack);
    dim3 gqkt(MP/128, MP/128, BB);
    k_qkt<<<gqkt,256,0,stream>>>(qpack, kpack, scores);
    dim3 gtop(NN,BB);
    k_topk<<<gtop,256,0,stream>>>(scores, adj, galpha, combh);
    dim3 gpack(DD/256, KP/8, BB);
    for (int i=0;i<NBLK;++i){
        k_mixer2<<<BB*NN,256,0,stream>>>(h, xpb, wimg + (size_t)i*WIMG_SZ,
            lncg+i*HH,lncb+i*HH, lntg+i*HH,lntb+i*HH, lnfg+i*HH,lnfb+i*HH, lnsg+i*HH,lnsb+i*HH,
            tb+i*SS, fb+i*HH);
        k_pack_xp<<<gpack,256,0,stream>>>(xpb, xpg);
        k_bmm_mfma<<<2688,256,0,stream>>>(combh, xpg, sb+i*HH, h,
            (i==NBLK-1) ? feats16 : (__hip_bfloat16*)nullptr,
            (i==NBLK-1) ? 0 : 1);
    }
    k_head_mfma<<<(BB*NN+31)/32,256,0,stream>>>(feats16, hw16, hb, out);
}

// Round 10
// 602.349 us; speedup vs baseline: 1.2452x; 1.0958x over previous
//
#include <hip/hip_runtime.h>
#include <hip/hip_bf16.h>
#include <math.h>

#define BB 4
#define NN 1437
#define SS 56
#define PP 28
#define FIN 10
#define FFUT 6
#define HH 64
#define NBLK 2
#define TOPK 5
#define DD (SS*HH)     /* 3584 */
#define FD (PP*HH)     /* 1792 */
#define TOT (DD+FD)    /* 5376 */
#define MP 1536        /* padded M (12*128) */
#define KP 1472        /* padded K (46*32)  */
#define NT (KP/32)     /* 46 K-steps */
#define SP 1536        /* scores stride */
#define WIMG_SZ 16384  /* shorts per mixer-block weight image */

typedef __attribute__((ext_vector_type(8))) __bf16 bf16x8;
typedef __attribute__((ext_vector_type(4))) float  f32x4;

// h lives in a permuted intra-row layout: element (s,f) at s*64 + (f&15)*4 + (f>>4).
// Consumers: k_front (write), k_mixer2 (rw), k_bmm_mfma (rw). All use this layout.

__device__ __forceinline__ float gelu_fast(float x){
    // sigmoid form of the tanh-approx GELU: x*(1 - 1/(exp2(2.3022077*(x+0.044715x^3))+1))
    float x2 = x*x;
    float u  = __builtin_fmaf(0.044715f*x2, x, x);
    float e  = __builtin_amdgcn_exp2f(2.3022077f*u);
    float r  = __builtin_amdgcn_rcpf(e+1.f);
    return x - x*r;
}
__device__ __forceinline__ float wave_sum64(float v){
    #pragma unroll
    for (int o=1;o<64;o<<=1) v += __shfl_xor(v,o,64);
    return v;
}
__device__ __forceinline__ void async_load16(const void* g, void* l){
    __builtin_amdgcn_global_load_lds(
        (const __attribute__((address_space(1))) void*)g,
        (__attribute__((address_space(3))) void*)l, 16, 0, 0);
}
__device__ __forceinline__ unsigned short f2bf(float x){
    unsigned int u = __float_as_uint(x);
    unsigned int r = (u + 0x7fffu + ((u>>16)&1u)) >> 16;
    return (unsigned short)r;
}
__device__ __forceinline__ unsigned long long umax64(unsigned long long a, unsigned long long b){return a>b?a:b;}
__device__ __forceinline__ unsigned long long umin64(unsigned long long a, unsigned long long b){return a<b?a:b;}

// ---------------- emb norm ----------------
__global__ __launch_bounds__(64) void k_embnorm(const float* __restrict__ emb,
                                                float* __restrict__ out){
    int n = blockIdx.x; int l = threadIdx.x;
    float v = emb[(size_t)n*HH+l];
    float ss = wave_sum64(v*v);
    float nrm = fmaxf(sqrtf(ss), 1e-12f);
    out[(size_t)n*HH+l] = v/nrm;
}

// ------- front: h = LN(x@fp_w^T+fp_b)+embn ; ctx = recency ctx -------
__global__ __launch_bounds__(256) void k_front(
    const float* __restrict__ x, const float* __restrict__ fpw, const float* __restrict__ fpb,
    const float* __restrict__ lng, const float* __restrict__ lnb,
    const float* __restrict__ embn, float* __restrict__ h, float* __restrict__ ctx)
{
    int bn = blockIdx.x; int n = bn % NN;
    int tid=threadIdx.x; int lane=tid&63; int wv=tid>>6;
    __shared__ float xin[SS*FIN];
    __shared__ float wlds[HH*FIN];
    __shared__ float rw[SS];
    __shared__ float rsum;
    __shared__ float red[4][HH];
    for (int i=tid;i<SS*FIN;i+=256) xin[i]=x[(size_t)bn*SS*FIN+i];
    for (int i=tid;i<HH*FIN;i+=256) wlds[i]=fpw[i];
    if (tid<SS) rw[tid]=expf(-(float)(SS-tid)/14.0f);
    __syncthreads();
    if (tid==0){ float s=0.f; for(int i=0;i<SS;++i) s+=rw[i]; rsum=s; }
    __syncthreads();
    float inv_rs = 1.0f/rsum;
    float gg=lng[lane], bv=lnb[lane], el=embn[(size_t)n*HH+lane], fb0=fpb[lane];
    int paddr = (lane&15)*4 + (lane>>4);
    float cacc=0.f;
    for (int s=wv;s<SS;s+=4){
        float v=fb0;
        #pragma unroll
        for (int c=0;c<FIN;++c) v += xin[s*FIN+c]*wlds[lane*FIN+c];
        float m = wave_sum64(v)*(1.f/HH);
        float d = v-m;
        float va = wave_sum64(d*d)*(1.f/HH);
        float hn = d*rsqrtf(va+1e-5f)*gg + bv + el;
        h[((size_t)bn*SS+s)*HH + paddr]=hn;
        cacc += hn * rw[s]*inv_rs;
    }
    red[wv][lane]=cacc;
    __syncthreads();
    if (wv==0) ctx[(size_t)bn*HH+lane]=red[0][lane]+red[1][lane]+red[2][lane]+red[3][lane];
}

// ---------------- Q/K projections -> K-packed bf16 [b][8][MP][8] ----------------
__global__ __launch_bounds__(64) void k_qk(
    const float* __restrict__ ctx, const float* __restrict__ qw, const float* __restrict__ qb,
    const float* __restrict__ kw, const float* __restrict__ kb,
    unsigned short* __restrict__ qpack, unsigned short* __restrict__ kpack)
{
    __shared__ float wq[HH*65];
    __shared__ float wk2[HH*65];
    int lane=threadIdx.x; int bn=blockIdx.x;
    for (int i=lane;i<HH*HH;i+=64){ int hh=i>>6, kk=i&63; wq[kk*65+hh]=qw[i]; wk2[kk*65+hh]=kw[i]; }
    __syncthreads();
    const float* c = ctx + (size_t)bn*HH;
    float q=qb[lane], k=kb[lane];
    for (int kk=0;kk<HH;++kk){ float cv=c[kk]; q+=cv*wq[kk*65+lane]; k+=cv*wk2[kk*65+lane]; }
    int b = bn/NN, m = bn%NN;
    size_t off = (size_t)b*8*MP*8 + (size_t)(lane>>3)*MP*8 + (size_t)m*8 + (lane&7);
    qpack[off]=f2bf(q); kpack[off]=f2bf(k);
}

// ---------------- QK^T via MFMA -> scores = relu(clip(QK^T/8)) f32 ----------------
__global__ __launch_bounds__(256) void k_qkt(
    const unsigned short* __restrict__ qp, const unsigned short* __restrict__ kp,
    float* __restrict__ scores)
{
    int bm=blockIdx.x, bnn=blockIdx.y, b=blockIdx.z;
    int tid=threadIdx.x, lane=tid&63, wv=tid>>6;
    int g=lane>>4, c15=lane&15;
    int m0=bm*128, n0=bnn*128;
    __shared__ unsigned short As[8192];  // [8][128][8]
    __shared__ unsigned short Bs[8192];
    const char* qbase = (const char*)(qp + (size_t)b*8*MP*8);
    const char* kbase = (const char*)(kp + (size_t)b*8*MP*8);
    #pragma unroll
    for (int i=0;i<4;++i){
        int idx=i*256+tid; int ch=idx>>7, r=idx&127;
        async_load16(qbase + ((size_t)(ch*MP + m0 + r))*16, (char*)As + idx*16);
        async_load16(kbase + ((size_t)(ch*MP + n0 + r))*16, (char*)Bs + idx*16);
    }
    asm volatile("s_waitcnt vmcnt(0)");
    __syncthreads();
    int wr=wv>>1, wc=wv&1;
    f32x4 acc[4][4];
    #pragma unroll
    for (int i=0;i<4;++i)
        #pragma unroll
        for (int j=0;j<4;++j) acc[i][j]=(f32x4){0.f,0.f,0.f,0.f};
    #pragma unroll
    for (int kc=0;kc<2;++kc){
        bf16x8 af[4], bfv[4];
        #pragma unroll
        for (int i=0;i<4;++i)
            af[i]=*(const bf16x8*)((const char*)As + ((4*kc+g)*128 + wr*64+i*16+c15)*16);
        #pragma unroll
        for (int j=0;j<4;++j)
            bfv[j]=*(const bf16x8*)((const char*)Bs + ((4*kc+g)*128 + wc*64+j*16+c15)*16);
        #pragma unroll
        for (int i=0;i<4;++i)
            #pragma unroll
            for (int j=0;j<4;++j)
                acc[i][j]=__builtin_amdgcn_mfma_f32_16x16x32_bf16(af[i],bfv[j],acc[i][j],0,0,0);
    }
    #pragma unroll
    for (int i=0;i<4;++i){
        #pragma unroll
        for (int q=0;q<4;++q){
            int m = m0 + wr*64 + i*16 + g*4 + q;
            float* sr = scores + ((size_t)b*SP + m)*SP + n0 + wc*64 + c15;
            #pragma unroll
            for (int j=0;j<4;++j){
                float v = acc[i][j][q]*0.125f;
                v = fminf(fmaxf(v,0.f),10.f);
                sr[j*16]=v;
            }
        }
    }
}

// ---- top-5 + softmax + blend + L1 normalize -> comb bf16 [b][MP][KP] ----
#define INS(x) do{ unsigned long long t_=(x); \
    unsigned long long n0_=umax64(u0,t_), t1_=umin64(u0,t_); \
    unsigned long long n1_=umax64(u1,t1_), t2_=umin64(u1,t1_); \
    unsigned long long n2_=umax64(u2,t2_), t3_=umin64(u2,t2_); \
    unsigned long long n3_=umax64(u3,t3_), t4_=umin64(u3,t3_); \
    unsigned long long n4_=umax64(u4,t4_); \
    u0=n0_;u1=n1_;u2=n2_;u3=n3_;u4=n4_; }while(0)

#define MERGE(b0,b1,b2,b3,b4) do{ \
    unsigned long long o0_=umax64(u0,(b0)); \
    unsigned long long o1_=umax64(umax64((b1),umin64(u0,(b0))),u1); \
    unsigned long long o2_=umax64(umax64((b2),umin64(u0,(b1))),umax64(umin64(u1,(b0)),u2)); \
    unsigned long long o3_=umax64(umax64((b3),umin64(u0,(b2))),umax64(umin64(u1,(b1)),umax64(umin64(u2,(b0)),u3))); \
    unsigned long long o4_=umax64(umax64((b4),umin64(u0,(b3))),umax64(umax64(umin64(u1,(b2)),umin64(u2,(b1))),umax64(umin64(u3,(b0)),u4))); \
    u0=o0_;u1=o1_;u2=o2_;u3=o3_;u4=o4_; }while(0)

__global__ __launch_bounds__(256) void k_topk(
    const float* __restrict__ scores, const float* __restrict__ adj,
    const float* __restrict__ galpha, __hip_bfloat16* __restrict__ combh)
{
    int m=blockIdx.x, b=blockIdx.y, tid=threadIdx.x, lane=tid&63, wv=tid>>6;
    __shared__ float row[KP];
    __shared__ unsigned long long wtop[4][8];
    __shared__ float redp[4];
    const float* srow = scores + ((size_t)b*SP + m)*SP;
    unsigned long long u0=0,u1=0,u2=0,u3=0,u4=0;
    for (int n=tid;n<NN;n+=256){
        float v=srow[n];
        unsigned long long key=((unsigned long long)__float_as_uint(v)<<32)|(unsigned long long)(0xFFFFFFFFu-(unsigned)n);
        INS(key);
    }
    #pragma unroll
    for (int off=1; off<64; off<<=1){
        unsigned long long b0=__shfl_xor(u0,off,64), b1=__shfl_xor(u1,off,64),
                           b2=__shfl_xor(u2,off,64), b3=__shfl_xor(u3,off,64),
                           b4=__shfl_xor(u4,off,64);
        MERGE(b0,b1,b2,b3,b4);
    }
    if (lane==0){ wtop[wv][0]=u0; wtop[wv][1]=u1; wtop[wv][2]=u2; wtop[wv][3]=u3; wtop[wv][4]=u4; }
    __syncthreads();
    u0=wtop[0][0]; u1=wtop[0][1]; u2=wtop[0][2]; u3=wtop[0][3]; u4=wtop[0][4];
    #pragma unroll
    for (int w2=1;w2<4;++w2)
        MERGE(wtop[w2][0],wtop[w2][1],wtop[w2][2],wtop[w2][3],wtop[w2][4]);

    float s0=__uint_as_float((unsigned)(u0>>32)), s1=__uint_as_float((unsigned)(u1>>32)),
          s2=__uint_as_float((unsigned)(u2>>32)), s3=__uint_as_float((unsigned)(u3>>32)),
          s4=__uint_as_float((unsigned)(u4>>32));
    int i0=(int)(0xFFFFFFFFu-(unsigned)u0), i1=(int)(0xFFFFFFFFu-(unsigned)u1),
        i2=(int)(0xFFFFFFFFu-(unsigned)u2), i3=(int)(0xFFFFFFFFu-(unsigned)u3),
        i4=(int)(0xFFFFFFFFu-(unsigned)u4);
    float e0=1.f, e1=expf(s1-s0), e2=expf(s2-s0), e3=expf(s3-s0), e4=expf(s4-s0);
    float den=e0+e1+e2+e3+e4;
    float alpha=1.f/(1.f+expf(-galpha[0]));
    float oma=(1.f-alpha)/den;
    float p0=oma*e0, p1=oma*e1, p2=oma*e2, p3=oma*e3, p4=oma*e4;

    const float* arow = adj + (size_t)m*NN;
    float part=0.f;
    for (int n=tid;n<NN;n+=256){
        float v=alpha*arow[n];
        v += (n==i0)?p0:0.f;
        v += (n==i1)?p1:0.f;
        v += (n==i2)?p2:0.f;
        v += (n==i3)?p3:0.f;
        v += (n==i4)?p4:0.f;
        row[n]=v;
        part+=fabsf(v);
    }
    part=wave_sum64(part);
    if (lane==0) redp[wv]=part;
    __syncthreads();
    float inv=1.f/fmaxf(redp[0]+redp[1]+redp[2]+redp[3],1e-12f);
    __hip_bfloat16* dst = combh + ((size_t)b*MP+m)*KP;
    for (int n=tid;n<KP;n+=256){
        float v = (n<NN) ? row[n]*inv : 0.f;
        dst[n]=__float2bfloat16(v);
    }
}
#undef INS
#undef MERGE

// ---- prep: build per-mixer-block bf16 weight images ----
__global__ __launch_bounds__(256) void k_prepw(
    const float* __restrict__ wk, const float* __restrict__ mk,
    const float* __restrict__ tw, const float* __restrict__ fw,
    const float* __restrict__ sw, unsigned short* __restrict__ wimg)
{
    int i = blockIdx.x; int tid = threadIdx.x;
    const float* wki = wk + i*7;
    const float* mki = mk + i*28;
    const float* twi = tw + i*SS*SS;
    const float* fwi = fw + i*HH*HH;
    const float* swi = sw + i*HH*HH;
    unsigned short* o = wimg + (size_t)i*WIMG_SZ;
    for (int e=tid; e<4096; e+=256){
        int r = e>>6, k = e&63;
        int swz = ((k*2) ^ ((r&7)<<4)) >> 1;
        float mv = 0.f;
        if (r<SS && k<SS){
            int a = k-r+3;  if (a>=0 && a<7)  mv += wki[a];
            int b2= k-r+13; if (b2>=0 && b2<28) mv += mki[b2];
        }
        o[r*64 + swz] = f2bf(mv);
        float tv = (r<SS && k<SS) ? twi[r*SS+k] : 0.f;
        o[4096 + r*64 + swz] = f2bf(tv);
        int pk = (k>>3)*512 + r*8 + (k&7);
        o[8192  + pk] = f2bf(fwi[r*HH+k]);
        o[12288 + pk] = f2bf(swi[r*HH+k]);
    }
}

// ---- prep: head_w f32 [28][5376] -> bf16 [32][5376] (pad rows zero) ----
__global__ __launch_bounds__(256) void k_prep_head(
    const float* __restrict__ hw, __hip_bfloat16* __restrict__ hw16)
{
    int i = blockIdx.x*256 + threadIdx.x;   // 32*TOT total
    int r = i / TOT, k = i - r*TOT;
    float v = (r<PP) ? hw[(size_t)r*TOT + k] : 0.f;
    hw16[i] = __float2bfloat16(v);
}

// ---- fut: feats16[bn][3584+q] = bf16(x_future @ futw^T + futb) ----
__global__ __launch_bounds__(256) void k_fut(
    const float* __restrict__ xf, const float* __restrict__ fw,
    const float* __restrict__ fbias, __hip_bfloat16* __restrict__ feats)
{
    int bn=blockIdx.x, tid=threadIdx.x;
    __shared__ float fwl[HH*FFUT];
    __shared__ float fbl[HH];
    __shared__ float xfl[PP*FFUT];
    for (int i=tid;i<HH*FFUT;i+=256) fwl[i]=fw[i];
    if (tid<HH) fbl[tid]=fbias[tid];
    for (int i=tid;i<PP*FFUT;i+=256) xfl[i]=xf[(size_t)bn*PP*FFUT+i];
    __syncthreads();
    __hip_bfloat16* dst = feats + (size_t)bn*TOT + DD;
    for (int q=tid;q<FD;q+=256){
        int pp=q>>6, hh2=q&63;
        float v=fbl[hh2];
        #pragma unroll
        for (int c2=0;c2<FFUT;++c2) v += xfl[pp*FFUT+c2]*fwl[hh2*FFUT+c2];
        dst[q]=__float2bfloat16(v);
    }
}

// ---------------- MFMA mixer block (h permuted; 2-buffer weights; fast GELU) ----------------
__global__ __launch_bounds__(256) void k_mixer2(
    float* __restrict__ h, __hip_bfloat16* __restrict__ xpb,
    const unsigned short* __restrict__ wimg,
    const float* __restrict__ lncg, const float* __restrict__ lncb,
    const float* __restrict__ lntg, const float* __restrict__ lntb,
    const float* __restrict__ lnfg, const float* __restrict__ lnfb,
    const float* __restrict__ lnsg, const float* __restrict__ lnsb,
    const float* __restrict__ tb, const float* __restrict__ fb)
{
    int bn=blockIdx.x, tid=threadIdx.x, lane=tid&63, w=tid>>6;
    int g=lane>>4, c=lane&15;
    __shared__ unsigned short wbuf[2][4096];
    __shared__ unsigned short xs[4096];
    __shared__ float prm[640];

    const char* wsrc=(const char*)wimg;
#define LOADW(SLOTB, BUFP) do{ \
    async_load16(wsrc+(size_t)(SLOTB)+((size_t)tid)*16,       (char*)(BUFP)+(w*64)*16); \
    async_load16(wsrc+(size_t)(SLOTB)+((size_t)(256+tid))*16, (char*)(BUFP)+((256+w*64))*16); } while(0)

    LOADW(0,    wbuf[0]);   // conv matrix (A-layout)
    LOADW(8192, wbuf[1]);   // temporal (A-layout)
    if (tid<64){
        prm[tid]      =lncg[tid]; prm[64+tid] =lncb[tid];
        prm[128+tid]  =lntg[tid]; prm[192+tid]=lntb[tid];
        prm[256+tid]  =lnfg[tid]; prm[320+tid]=lnfb[tid];
        prm[384+tid]  =lnsg[tid]; prm[448+tid]=lnsb[tid];
        prm[512+tid]  =(tid<SS)?tb[tid]:0.f;
        prm[576+tid]  =fb[tid];
    }
    float xl[4][4];
    float* hb = h + (size_t)bn*DD;
    int srow = 16*w + 4*g;
    #pragma unroll
    for (int q=0;q<4;++q){
        int s=srow+q;
        if (s<SS){
            const float4 v4 = *reinterpret_cast<const float4*>(hb + s*HH + c*4);
            xl[q][0]=v4.x; xl[q][1]=v4.y; xl[q][2]=v4.z; xl[q][3]=v4.w;
        } else {
            xl[q][0]=0.f; xl[q][1]=0.f; xl[q][2]=0.f; xl[q][3]=0.f;
        }
    }
    __syncthreads();

    float xn[4][4];
    f32x4 acc[4];

#define LNSTAGE(GOFF,BOFF) do{ \
    _Pragma("unroll") \
    for (int q=0;q<4;++q){ \
        float sv = xl[q][0]+xl[q][1]+xl[q][2]+xl[q][3]; \
        float s2 = xl[q][0]*xl[q][0]+xl[q][1]*xl[q][1]+xl[q][2]*xl[q][2]+xl[q][3]*xl[q][3]; \
        _Pragma("unroll") \
        for (int m2=1;m2<16;m2<<=1){ sv += __shfl_xor(sv,m2,64); s2 += __shfl_xor(s2,m2,64); } \
        float mn = sv*(1.f/64.f); \
        float var = s2*(1.f/64.f)-mn*mn; \
        float rstd = rsqrtf(var+1e-5f); \
        bool ok = (srow+q)<SS; \
        _Pragma("unroll") \
        for (int tj=0;tj<4;++tj){ \
            float v=(xl[q][tj]-mn)*rstd*prm[(GOFF)+tj*16+c]+prm[(BOFF)+tj*16+c]; \
            xn[q][tj]= ok ? v : 0.f; \
        } \
    } }while(0)

#define WRITE_XNP() do{ \
    _Pragma("unroll") \
    for (int qp=0;qp<2;++qp){ \
        int s0=srow+2*qp; \
        _Pragma("unroll") \
        for (int tj=0;tj<4;++tj){ \
            unsigned int pv=(unsigned int)f2bf(xn[2*qp][tj])|((unsigned int)f2bf(xn[2*qp+1][tj])<<16); \
            *(unsigned int*)((char*)xs + ((s0>>3)*1024 + (tj*16+c)*16 + (s0&7)*2)) = pv; \
        } \
    } }while(0)

#define WRITE_XNR() do{ \
    _Pragma("unroll") \
    for (int q=0;q<4;++q){ int s=srow+q; \
        _Pragma("unroll") \
        for (int tj=0;tj<4;++tj){ \
            *(unsigned short*)((char*)xs + s*128 + (((tj*16+c)*2) ^ ((s&7)<<4))) = f2bf(xn[q][tj]); \
        } \
    } }while(0)

#define MM(APTR,BPTR) do{ \
    _Pragma("unroll") \
    for (int tj=0;tj<4;++tj) acc[tj]=(f32x4){0.f,0.f,0.f,0.f}; \
    _Pragma("unroll") \
    for (int kc=0;kc<2;++kc){ \
        int arow=16*w+c; \
        bf16x8 af=*(const bf16x8*)((const char*)(APTR)+arow*128+((kc*64+g*16)^((arow&7)<<4))); \
        _Pragma("unroll") \
        for (int tj=0;tj<4;++tj){ \
            bf16x8 bf2=*(const bf16x8*)((const char*)(BPTR)+(kc*4+g)*1024+(tj*16+c)*16); \
            acc[tj]=__builtin_amdgcn_mfma_f32_16x16x32_bf16(af,bf2,acc[tj],0,0,0); \
        } \
    } }while(0)

    // ---- conv (banded matmul) ----
    LNSTAGE(0,64); WRITE_XNP();
    __syncthreads();
    MM(&wbuf[0][0], xs);
    #pragma unroll
    for (int q=0;q<4;++q)
        #pragma unroll
        for (int tj=0;tj<4;++tj) xl[q][tj]+=acc[tj][q];
    __syncthreads();               // wbuf[0] free
    LOADW(16384, wbuf[0]);         // prefetch feature weights (B-packed)
    // ---- temporal ----
    LNSTAGE(128,192); WRITE_XNP();
    __syncthreads();               // (drains feature-weight load too)
    MM(&wbuf[1][0], xs);
    #pragma unroll
    for (int q=0;q<4;++q){
        float tbv=prm[512+srow+q];
        #pragma unroll
        for (int tj=0;tj<4;++tj) xl[q][tj]+=gelu_fast(acc[tj][q]+tbv);
    }
    __syncthreads();               // wbuf[1] free
    LOADW(24576, wbuf[1]);         // prefetch spatial weights (B-packed)
    // ---- feature ----
    LNSTAGE(256,320); WRITE_XNR();
    __syncthreads();               // (drains spatial-weight load too)
    MM(xs, &wbuf[0][0]);
    #pragma unroll
    for (int q=0;q<4;++q)
        #pragma unroll
        for (int tj=0;tj<4;++tj) xl[q][tj]+=gelu_fast(acc[tj][q]+prm[576+tj*16+c]);
    __syncthreads();
    // ---- spatial projection ----
    LNSTAGE(384,448); WRITE_XNR();
    __syncthreads();
    MM(xs, &wbuf[1][0]);
    __hip_bfloat16* xpo = xpb + (size_t)bn*DD;
    #pragma unroll
    for (int q=0;q<4;++q){
        int s=srow+q;
        if (s<SS){
            float4 hv; hv.x=xl[q][0]; hv.y=xl[q][1]; hv.z=xl[q][2]; hv.w=xl[q][3];
            *reinterpret_cast<float4*>(hb + s*HH + c*4) = hv;
            #pragma unroll
            for (int tj=0;tj<4;++tj)
                xpo[s*HH + tj*16 + c]=__float2bfloat16(acc[tj][q]);
        }
    }
#undef LNSTAGE
#undef WRITE_XNP
#undef WRITE_XNR
#undef MM
#undef LOADW
}

// ---- pack xp bf16 [N][D] -> MFMA-ready [KP/8][D][8], coalesced via LDS transpose ----
__global__ __launch_bounds__(256) void k_pack_xp(
    const __hip_bfloat16* __restrict__ xpb, __hip_bfloat16* __restrict__ xpg)
{
    __shared__ unsigned short t8[8*256];   // [e][d] 4KB
    int dblk=blockIdx.x, kc=blockIdx.y, b=blockIdx.z;
    int tid=threadIdx.x;
    int r=tid>>5, l=tid&31;
    int k=kc*8+r;
    if (k<NN){
        async_load16((const char*)xpb + (((size_t)b*NN+k)*DD + dblk*256 + l*8)*2,
                     (char*)t8 + tid*16);
    } else {
        uint4 z; z.x=0; z.y=0; z.z=0; z.w=0;
        *reinterpret_cast<uint4*>((char*)t8 + tid*16) = z;
    }
    asm volatile("s_waitcnt vmcnt(0)");
    __syncthreads();
    union { unsigned short v[8]; float4 f4; } u;
    #pragma unroll
    for (int e=0;e<8;++e) u.v[e]=t8[e*256+tid];
    *reinterpret_cast<float4*>(xpg + (((size_t)b*(KP/8)+kc)*DD + dblk*256 + tid)*8) = u.f4;
}

// ---- spatial bmm via MFMA: h[b] += comb[b] @ xp[b] + sb ----
// 64x128 tile, 4 waves (2x2 of 32x64), 3-buffer depth-2 prefetch, counted vmcnt.
// h accessed in permuted layout (float4 per thread).
__global__ __launch_bounds__(256,4) void k_bmm_mfma(
    const __hip_bfloat16* __restrict__ combh,
    const __hip_bfloat16* __restrict__ xpg,
    const float* __restrict__ sb,
    float* __restrict__ h,
    __hip_bfloat16* __restrict__ h16,
    int write_h)
{
    __shared__ short As[3][2048];   // [64][32] bf16 per buf (A-swizzled)
    __shared__ short Bs[3][4096];   // [4][128][8] per buf

    int bid = blockIdx.x;
    int wg = (bid & 7)*336 + (bid >> 3);     // bijective XCD-chunked swizzle (2688 = 8*336)
    int bm = wg % 24; int tmp2 = wg / 24; int bd = tmp2 % 28; int b = tmp2 / 28;
    int tid=threadIdx.x, lane=tid&63, w=tid>>6;
    int g=lane>>4, c=lane&15;
    int wr=w>>1, wc=w&1;
    int m0=bm*64, d0=bd*128;

    const char* cb = (const char*)(combh + (size_t)b*MP*KP);
    const char* xb = (const char*)(xpg   + (size_t)b*(KP/8)*(size_t)DD*8);

    int arow_s = tid>>2, aslot = tid&3;
    int ag = aslot ^ ((arow_s>>1)&3);
    const char* srcA = cb + ((size_t)(m0+arow_s)*KP + ag*8)*2;
    int bch = tid>>7, bcol = tid&127;
    const char* srcB0 = xb + ((size_t)bch*DD + d0 + bcol)*16;
    const char* srcB1 = xb + ((size_t)(bch+2)*DD + d0 + bcol)*16;
    const size_t BSTEP = (size_t)4*DD*16;

    f32x4 acc[2][4];
    #pragma unroll
    for (int i=0;i<2;++i)
        #pragma unroll
        for (int j=0;j<4;++j) acc[i][j]=(f32x4){0.f,0.f,0.f,0.f};

    int aoff[2], boff[4];
    #pragma unroll
    for (int i=0;i<2;++i){
        int row = 32*wr + 16*i + c;
        aoff[i] = row*64 + ((g*16) ^ (((row>>1)&3)<<4));
    }
    #pragma unroll
    for (int j=0;j<4;++j) boff[j] = (g*128 + 64*wc + 16*j + c)*16;

#define STAGE(BUF,T) do { \
    async_load16(srcA  + (size_t)(T)*64,    (char*)As[BUF] + w*1024); \
    async_load16(srcB0 + (size_t)(T)*BSTEP, (char*)Bs[BUF] + w*1024); \
    async_load16(srcB1 + (size_t)(T)*BSTEP, (char*)Bs[BUF] + 4096 + w*1024); } while(0)

    STAGE(0,0); STAGE(1,1);
    asm volatile("s_waitcnt vmcnt(3)" ::: "memory");
    __builtin_amdgcn_s_barrier();

    int cur=0;
    for (int t=0;t<NT;++t){
        if (t+2<NT){
            int nb = cur+2; if (nb>=3) nb-=3;
            STAGE(nb, t+2);
        }
        const char* Ab=(const char*)As[cur];
        const char* Bb=(const char*)Bs[cur];
        bf16x8 af[2], bfv[4];
        #pragma unroll
        for (int i=0;i<2;++i) af[i]=*(const bf16x8*)(Ab + aoff[i]);
        #pragma unroll
        for (int j=0;j<4;++j) bfv[j]=*(const bf16x8*)(Bb + boff[j]);
        #pragma unroll
        for (int i=0;i<2;++i)
            #pragma unroll
            for (int j=0;j<4;++j)
                acc[i][j]=__builtin_amdgcn_mfma_f32_16x16x32_bf16(af[i],bfv[j],acc[i][j],0,0,0);
        if (t+2<NT) asm volatile("s_waitcnt vmcnt(3)" ::: "memory");
        else        asm volatile("s_waitcnt vmcnt(0)" ::: "memory");
        __builtin_amdgcn_s_barrier();
        ++cur; if (cur>=3) cur=0;
    }
#undef STAGE

    // epilogue: h is permuted ( (s,f) at s*64 + (f&15)*4 + (f>>4) ); here f = 16j+c
    int row_b = m0 + 32*wr + g*4;
    int s2 = 2*bd + wc;
    float sb0=sb[c], sb1=sb[16+c], sb2=sb[32+c], sb3=sb[48+c];
    #pragma unroll
    for (int i=0;i<2;++i){
        #pragma unroll
        for (int q=0;q<4;++q){
            int m = row_b + 16*i + q;
            if (m < NN){
                float* hp = h + ((size_t)b*NN+m)*DD + s2*HH + c*4;
                float4 hv = *reinterpret_cast<const float4*>(hp);
                float nv0 = hv.x + acc[i][0][q] + sb0;
                float nv1 = hv.y + acc[i][1][q] + sb1;
                float nv2 = hv.z + acc[i][2][q] + sb2;
                float nv3 = hv.w + acc[i][3][q] + sb3;
                if (write_h){
                    float4 ov; ov.x=nv0; ov.y=nv1; ov.z=nv2; ov.w=nv3;
                    *reinterpret_cast<float4*>(hp) = ov;
                }
                if (h16){
                    size_t fr = ((size_t)b*NN+m)*TOT + (size_t)bd*128 + wc*64;
                    h16[fr + c]      = __float2bfloat16(nv0);
                    h16[fr + 16 + c] = __float2bfloat16(nv1);
                    h16[fr + 32 + c] = __float2bfloat16(nv2);
                    h16[fr + 48 + c] = __float2bfloat16(nv3);
                }
            }
        }
    }
}

// ---------------- head GEMM: out = feats16 @ hw16^T + hb ----------------
__global__ __launch_bounds__(256) void k_head_mfma(
    const __hip_bfloat16* __restrict__ feats, const __hip_bfloat16* __restrict__ hw16,
    const float* __restrict__ hb, float* __restrict__ out)
{
    int tid=threadIdx.x, lane=tid&63, w=tid>>6;
    int g=lane>>4, c=lane&15;
    int m0=blockIdx.x*32;
    int rt=w>>1, pt=w&1;
    int arow = m0 + rt*16 + c;
    if (arow > BB*NN-1) arow = BB*NN-1;
    const char* abase = (const char*)feats + (size_t)arow*TOT*2 + g*16;
    const char* bbase = (const char*)hw16 + (size_t)(pt*16+c)*TOT*2 + g*16;
    f32x4 acc=(f32x4){0.f,0.f,0.f,0.f};
    #pragma unroll 4
    for (int kc=0;kc<TOT/32;++kc){
        bf16x8 af =*(const bf16x8*)(abase + (size_t)kc*64);
        bf16x8 bf2=*(const bf16x8*)(bbase + (size_t)kc*64);
        acc=__builtin_amdgcn_mfma_f32_16x16x32_bf16(af,bf2,acc,0,0,0);
    }
    int col = pt*16 + c;
    #pragma unroll
    for (int q=0;q<4;++q){
        int row = m0 + rt*16 + g*4 + q;
        if (row < BB*NN && col < PP)
            out[(size_t)row*PP + col] = acc[q] + hb[col];
    }
}

extern "C" void kernel_launch(void* const* d_in, const int* in_sizes, int n_in,
                              void* d_out, int out_size, void* d_ws, size_t ws_size,
                              hipStream_t stream)
{
    const float* x      = (const float*)d_in[0];
    const float* xfut   = (const float*)d_in[1];
    const float* adj    = (const float*)d_in[2];
    const float* fp_w   = (const float*)d_in[3];
    const float* fp_b   = (const float*)d_in[4];
    const float* inlng  = (const float*)d_in[5];
    const float* inlnb  = (const float*)d_in[6];
    const float* q_w    = (const float*)d_in[7];
    const float* q_b    = (const float*)d_in[8];
    const float* k_w    = (const float*)d_in[9];
    const float* k_b    = (const float*)d_in[10];
    const float* nemb   = (const float*)d_in[11];
    const float* galpha = (const float*)d_in[12];
    const float* wk     = (const float*)d_in[13];
    const float* mk     = (const float*)d_in[14];
    const float* lncg   = (const float*)d_in[15];
    const float* lncb   = (const float*)d_in[16];
    const float* lntg   = (const float*)d_in[17];
    const float* lntb   = (const float*)d_in[18];
    const float* lnfg   = (const float*)d_in[19];
    const float* lnfb   = (const float*)d_in[20];
    const float* lnsg   = (const float*)d_in[21];
    const float* lnsb   = (const float*)d_in[22];
    const float* tw     = (const float*)d_in[23];
    const float* tb     = (const float*)d_in[24];
    const float* fw     = (const float*)d_in[25];
    const float* fb     = (const float*)d_in[26];
    const float* sw     = (const float*)d_in[27];
    const float* sb     = (const float*)d_in[28];
    const float* futw   = (const float*)d_in[29];
    const float* futb   = (const float*)d_in[30];
    const float* hw     = (const float*)d_in[31];
    const float* hb     = (const float*)d_in[32];
    (void)in_sizes; (void)n_in; (void)out_size; (void)ws_size;
    float* out = (float*)d_out;
    float* ws = (float*)d_ws;
    const size_t HSZ = (size_t)BB*NN*SS*HH;

    float* h    = ws;
    float* embn = h + HSZ;
    float* ctx  = embn + (size_t)NN*HH;
    __hip_bfloat16* xpb   = (__hip_bfloat16*)(ctx + (size_t)BB*NN*HH);
    __hip_bfloat16* combh = xpb + HSZ;
    __hip_bfloat16* xpg   = combh + (size_t)BB*MP*KP;
    float* scores = (float*)xpg;   // aliased: scores dead before xpg is written
    unsigned short* wimg  = (unsigned short*)(xpg + (size_t)BB*(KP/8)*(size_t)DD*8);
    unsigned short* qpack = wimg + (size_t)NBLK*WIMG_SZ;
    unsigned short* kpack = qpack + (size_t)BB*8*MP*8;
    __hip_bfloat16* feats16 = (__hip_bfloat16*)(kpack + (size_t)BB*8*MP*8);
    __hip_bfloat16* hw16    = feats16 + (size_t)BB*NN*TOT;

    k_prepw<<<NBLK,256,0,stream>>>(wk, mk, tw, fw, sw, wimg);
    k_prep_head<<<(32*TOT)/256,256,0,stream>>>(hw, hw16);
    k_fut<<<BB*NN,256,0,stream>>>(xfut, futw, futb, feats16);
    k_embnorm<<<NN,64,0,stream>>>(nemb, embn);
    k_front<<<BB*NN,256,0,stream>>>(x, fp_w, fp_b, inlng, inlnb, embn, h, ctx);
    k_qk<<<BB*NN,64,0,stream>>>(ctx, q_w,q_b,k_w,k_b, qpack, kpack);
    dim3 gqkt(MP/128, MP/128, BB);
    k_qkt<<<gqkt,256,0,stream>>>(qpack, kpack, scores);
    dim3 gtop(NN,BB);
    k_topk<<<gtop,256,0,stream>>>(scores, adj, galpha, combh);
    dim3 gpack(DD/256, KP/8, BB);
    for (int i=0;i<NBLK;++i){
        k_mixer2<<<BB*NN,256,0,stream>>>(h, xpb, wimg + (size_t)i*WIMG_SZ,
            lncg+i*HH,lncb+i*HH, lntg+i*HH,lntb+i*HH, lnfg+i*HH,lnfb+i*HH, lnsg+i*HH,lnsb+i*HH,
            tb+i*SS, fb+i*HH);
        k_pack_xp<<<gpack,256,0,stream>>>(xpb, xpg);
        k_bmm_mfma<<<2688,256,0,stream>>>(combh, xpg, sb+i*HH, h,
            (i==NBLK-1) ? feats16 : (__hip_bfloat16*)nullptr,
            (i==NBLK-1) ? 0 : 1);
    }
    k_head_mfma<<<(BB*NN+31)/32,256,0,stream>>>(feats16, hw16, hb, out);
}

// Round 11
// 602.304 us; speedup vs baseline: 1.2453x; 1.0001x over previous
//
#include <hip/hip_runtime.h>
#include <hip/hip_bf16.h>
#include <math.h>

#define BB 4
#define NN 1437
#define SS 56
#define PP 28
#define FIN 10
#define FFUT 6
#define HH 64
#define NBLK 2
#define TOPK 5
#define DD (SS*HH)     /* 3584 */
#define FD (PP*HH)     /* 1792 */
#define TOT (DD+FD)    /* 5376 */
#define MP 1536        /* padded M (12*128) */
#define KP 1472        /* padded K (46*32)  */
#define NT (KP/32)     /* 46 K-steps */
#define SP 1536        /* scores stride */
#define WIMG_SZ 16384  /* shorts per mixer-block weight image */

typedef __attribute__((ext_vector_type(8))) __bf16 bf16x8;
typedef __attribute__((ext_vector_type(4))) float  f32x4;

// h lives in a permuted intra-row layout: element (s,f) at s*64 + (f&15)*4 + (f>>4).
// Consumers: k_front (write), k_mixer2 (rw), k_bmm_mfma (rw). All use this layout.

__device__ __forceinline__ float gelu_fast(float x){
    float x2 = x*x;
    float u  = __builtin_fmaf(0.044715f*x2, x, x);
    float e  = __builtin_amdgcn_exp2f(2.3022077f*u);
    float r  = __builtin_amdgcn_rcpf(e+1.f);
    return x - x*r;
}
__device__ __forceinline__ float wave_sum64(float v){
    #pragma unroll
    for (int o=1;o<64;o<<=1) v += __shfl_xor(v,o,64);
    return v;
}
__device__ __forceinline__ void async_load16(const void* g, void* l){
    __builtin_amdgcn_global_load_lds(
        (const __attribute__((address_space(1))) void*)g,
        (__attribute__((address_space(3))) void*)l, 16, 0, 0);
}
__device__ __forceinline__ unsigned short f2bf(float x){
    unsigned int u = __float_as_uint(x);
    unsigned int r = (u + 0x7fffu + ((u>>16)&1u)) >> 16;
    return (unsigned short)r;
}
__device__ __forceinline__ unsigned long long umax64(unsigned long long a, unsigned long long b){return a>b?a:b;}
__device__ __forceinline__ unsigned long long umin64(unsigned long long a, unsigned long long b){return a<b?a:b;}

// ---------------- emb norm ----------------
__global__ __launch_bounds__(64) void k_embnorm(const float* __restrict__ emb,
                                                float* __restrict__ out){
    int n = blockIdx.x; int l = threadIdx.x;
    float v = emb[(size_t)n*HH+l];
    float ss = wave_sum64(v*v);
    float nrm = fmaxf(sqrtf(ss), 1e-12f);
    out[(size_t)n*HH+l] = v/nrm;
}

// ------- front: h = LN(x@fp_w^T+fp_b)+embn ; ctx -> Q/K packed bf16 -------
__global__ __launch_bounds__(256) void k_front(
    const float* __restrict__ x, const float* __restrict__ fpw, const float* __restrict__ fpb,
    const float* __restrict__ lng, const float* __restrict__ lnb,
    const float* __restrict__ embn,
    const float* __restrict__ qw, const float* __restrict__ qb,
    const float* __restrict__ kw, const float* __restrict__ kb,
    float* __restrict__ h,
    unsigned short* __restrict__ qpack, unsigned short* __restrict__ kpack)
{
    int bn = blockIdx.x; int n = bn % NN;
    int tid=threadIdx.x; int lane=tid&63; int wv=tid>>6;
    __shared__ float xin[SS*FIN];
    __shared__ float wlds[HH*FIN];
    __shared__ float rw[SS];
    __shared__ float rsum;
    __shared__ float red[4][HH];
    __shared__ float ctxs[HH];
    for (int i=tid;i<SS*FIN;i+=256) xin[i]=x[(size_t)bn*SS*FIN+i];
    for (int i=tid;i<HH*FIN;i+=256) wlds[i]=fpw[i];
    if (tid<SS) rw[tid]=expf(-(float)(SS-tid)/14.0f);
    __syncthreads();
    if (tid==0){ float s=0.f; for(int i=0;i<SS;++i) s+=rw[i]; rsum=s; }
    __syncthreads();
    float inv_rs = 1.0f/rsum;
    float gg=lng[lane], bv=lnb[lane], el=embn[(size_t)n*HH+lane], fb0=fpb[lane];
    int paddr = (lane&15)*4 + (lane>>4);
    float cacc=0.f;
    for (int s=wv;s<SS;s+=4){
        float v=fb0;
        #pragma unroll
        for (int c=0;c<FIN;++c) v += xin[s*FIN+c]*wlds[lane*FIN+c];
        float m = wave_sum64(v)*(1.f/HH);
        float d = v-m;
        float va = wave_sum64(d*d)*(1.f/HH);
        float hn = d*rsqrtf(va+1e-5f)*gg + bv + el;
        h[((size_t)bn*SS+s)*HH + paddr]=hn;
        cacc += hn * rw[s]*inv_rs;
    }
    red[wv][lane]=cacc;
    __syncthreads();
    if (wv==0) ctxs[lane]=red[0][lane]+red[1][lane]+red[2][lane]+red[3][lane];
    __syncthreads();
    if (wv==0){
        const float4* qr = reinterpret_cast<const float4*>(qw + (size_t)lane*HH);
        const float4* kr = reinterpret_cast<const float4*>(kw + (size_t)lane*HH);
        float q=qb[lane], k=kb[lane];
        #pragma unroll 4
        for (int t=0;t<16;++t){
            float4 qv=qr[t], kv=kr[t];
            float c0=ctxs[4*t], c1=ctxs[4*t+1], c2=ctxs[4*t+2], c3=ctxs[4*t+3];
            q += qv.x*c0+qv.y*c1+qv.z*c2+qv.w*c3;
            k += kv.x*c0+kv.y*c1+kv.z*c2+kv.w*c3;
        }
        int b = bn/NN, m = bn%NN;
        size_t off = (size_t)b*8*MP*8 + (size_t)(lane>>3)*MP*8 + (size_t)m*8 + (lane&7);
        qpack[off]=f2bf(q); kpack[off]=f2bf(k);
    }
}

// ---------------- QK^T via MFMA -> scores = relu(clip(QK^T/8)) f32 ----------------
__global__ __launch_bounds__(256) void k_qkt(
    const unsigned short* __restrict__ qp, const unsigned short* __restrict__ kp,
    float* __restrict__ scores)
{
    int bm=blockIdx.x, bnn=blockIdx.y, b=blockIdx.z;
    int tid=threadIdx.x, lane=tid&63, wv=tid>>6;
    int g=lane>>4, c15=lane&15;
    int m0=bm*128, n0=bnn*128;
    __shared__ unsigned short As[8192];  // [8][128][8]
    __shared__ unsigned short Bs[8192];
    const char* qbase = (const char*)(qp + (size_t)b*8*MP*8);
    const char* kbase = (const char*)(kp + (size_t)b*8*MP*8);
    #pragma unroll
    for (int i=0;i<4;++i){
        int idx=i*256+tid; int ch=idx>>7, r=idx&127;
        async_load16(qbase + ((size_t)(ch*MP + m0 + r))*16, (char*)As + idx*16);
        async_load16(kbase + ((size_t)(ch*MP + n0 + r))*16, (char*)Bs + idx*16);
    }
    asm volatile("s_waitcnt vmcnt(0)");
    __syncthreads();
    int wr=wv>>1, wc=wv&1;
    f32x4 acc[4][4];
    #pragma unroll
    for (int i=0;i<4;++i)
        #pragma unroll
        for (int j=0;j<4;++j) acc[i][j]=(f32x4){0.f,0.f,0.f,0.f};
    #pragma unroll
    for (int kc=0;kc<2;++kc){
        bf16x8 af[4], bfv[4];
        #pragma unroll
        for (int i=0;i<4;++i)
            af[i]=*(const bf16x8*)((const char*)As + ((4*kc+g)*128 + wr*64+i*16+c15)*16);
        #pragma unroll
        for (int j=0;j<4;++j)
            bfv[j]=*(const bf16x8*)((const char*)Bs + ((4*kc+g)*128 + wc*64+j*16+c15)*16);
        #pragma unroll
        for (int i=0;i<4;++i)
            #pragma unroll
            for (int j=0;j<4;++j)
                acc[i][j]=__builtin_amdgcn_mfma_f32_16x16x32_bf16(af[i],bfv[j],acc[i][j],0,0,0);
    }
    #pragma unroll
    for (int i=0;i<4;++i){
        #pragma unroll
        for (int q=0;q<4;++q){
            int m = m0 + wr*64 + i*16 + g*4 + q;
            float* sr = scores + ((size_t)b*SP + m)*SP + n0 + wc*64 + c15;
            #pragma unroll
            for (int j=0;j<4;++j){
                float v = acc[i][j][q]*0.125f;
                v = fminf(fmaxf(v,0.f),10.f);
                sr[j*16]=v;
            }
        }
    }
}

// ---- top-5 + softmax + blend + L1 normalize -> comb bf16 [b][MP][KP] ----
#define INS(x) do{ unsigned long long t_=(x); \
    unsigned long long n0_=umax64(u0,t_), t1_=umin64(u0,t_); \
    unsigned long long n1_=umax64(u1,t1_), t2_=umin64(u1,t1_); \
    unsigned long long n2_=umax64(u2,t2_), t3_=umin64(u2,t2_); \
    unsigned long long n3_=umax64(u3,t3_), t4_=umin64(u3,t3_); \
    unsigned long long n4_=umax64(u4,t4_); \
    u0=n0_;u1=n1_;u2=n2_;u3=n3_;u4=n4_; }while(0)

#define MERGE(b0,b1,b2,b3,b4) do{ \
    unsigned long long o0_=umax64(u0,(b0)); \
    unsigned long long o1_=umax64(umax64((b1),umin64(u0,(b0))),u1); \
    unsigned long long o2_=umax64(umax64((b2),umin64(u0,(b1))),umax64(umin64(u1,(b0)),u2)); \
    unsigned long long o3_=umax64(umax64((b3),umin64(u0,(b2))),umax64(umin64(u1,(b1)),umax64(umin64(u2,(b0)),u3))); \
    unsigned long long o4_=umax64(umax64((b4),umin64(u0,(b3))),umax64(umax64(umin64(u1,(b2)),umin64(u2,(b1))),umax64(umin64(u3,(b0)),u4))); \
    u0=o0_;u1=o1_;u2=o2_;u3=o3_;u4=o4_; }while(0)

__global__ __launch_bounds__(256) void k_topk(
    const float* __restrict__ scores, const float* __restrict__ adj,
    const float* __restrict__ galpha, __hip_bfloat16* __restrict__ combh)
{
    int m=blockIdx.x, b=blockIdx.y, tid=threadIdx.x, lane=tid&63, wv=tid>>6;
    __shared__ float row[KP];
    __shared__ unsigned long long wtop[4][8];
    __shared__ float redp[4];
    const float* srow = scores + ((size_t)b*SP + m)*SP;
    unsigned long long u0=0,u1=0,u2=0,u3=0,u4=0;
    for (int n=tid;n<NN;n+=256){
        float v=srow[n];
        unsigned long long key=((unsigned long long)__float_as_uint(v)<<32)|(unsigned long long)(0xFFFFFFFFu-(unsigned)n);
        INS(key);
    }
    #pragma unroll
    for (int off=1; off<64; off<<=1){
        unsigned long long b0=__shfl_xor(u0,off,64), b1=__shfl_xor(u1,off,64),
                           b2=__shfl_xor(u2,off,64), b3=__shfl_xor(u3,off,64),
                           b4=__shfl_xor(u4,off,64);
        MERGE(b0,b1,b2,b3,b4);
    }
    if (lane==0){ wtop[wv][0]=u0; wtop[wv][1]=u1; wtop[wv][2]=u2; wtop[wv][3]=u3; wtop[wv][4]=u4; }
    __syncthreads();
    u0=wtop[0][0]; u1=wtop[0][1]; u2=wtop[0][2]; u3=wtop[0][3]; u4=wtop[0][4];
    #pragma unroll
    for (int w2=1;w2<4;++w2)
        MERGE(wtop[w2][0],wtop[w2][1],wtop[w2][2],wtop[w2][3],wtop[w2][4]);

    float s0=__uint_as_float((unsigned)(u0>>32)), s1=__uint_as_float((unsigned)(u1>>32)),
          s2=__uint_as_float((unsigned)(u2>>32)), s3=__uint_as_float((unsigned)(u3>>32)),
          s4=__uint_as_float((unsigned)(u4>>32));
    int i0=(int)(0xFFFFFFFFu-(unsigned)u0), i1=(int)(0xFFFFFFFFu-(unsigned)u1),
        i2=(int)(0xFFFFFFFFu-(unsigned)u2), i3=(int)(0xFFFFFFFFu-(unsigned)u3),
        i4=(int)(0xFFFFFFFFu-(unsigned)u4);
    float e0=1.f, e1=expf(s1-s0), e2=expf(s2-s0), e3=expf(s3-s0), e4=expf(s4-s0);
    float den=e0+e1+e2+e3+e4;
    float alpha=1.f/(1.f+expf(-galpha[0]));
    float oma=(1.f-alpha)/den;
    float p0=oma*e0, p1=oma*e1, p2=oma*e2, p3=oma*e3, p4=oma*e4;

    const float* arow = adj + (size_t)m*NN;
    float part=0.f;
    for (int n=tid;n<NN;n+=256){
        float v=alpha*arow[n];
        v += (n==i0)?p0:0.f;
        v += (n==i1)?p1:0.f;
        v += (n==i2)?p2:0.f;
        v += (n==i3)?p3:0.f;
        v += (n==i4)?p4:0.f;
        row[n]=v;
        part+=fabsf(v);
    }
    part=wave_sum64(part);
    if (lane==0) redp[wv]=part;
    __syncthreads();
    float inv=1.f/fmaxf(redp[0]+redp[1]+redp[2]+redp[3],1e-12f);
    __hip_bfloat16* dst = combh + ((size_t)b*MP+m)*KP;
    for (int n=tid;n<KP;n+=256){
        float v = (n<NN) ? row[n]*inv : 0.f;
        dst[n]=__float2bfloat16(v);
    }
}
#undef INS
#undef MERGE

// ---- prep: build per-mixer-block bf16 weight images ----
__global__ __launch_bounds__(256) void k_prepw(
    const float* __restrict__ wk, const float* __restrict__ mk,
    const float* __restrict__ tw, const float* __restrict__ fw,
    const float* __restrict__ sw, unsigned short* __restrict__ wimg)
{
    int i = blockIdx.x; int tid = threadIdx.x;
    const float* wki = wk + i*7;
    const float* mki = mk + i*28;
    const float* twi = tw + i*SS*SS;
    const float* fwi = fw + i*HH*HH;
    const float* swi = sw + i*HH*HH;
    unsigned short* o = wimg + (size_t)i*WIMG_SZ;
    for (int e=tid; e<4096; e+=256){
        int r = e>>6, k = e&63;
        int swz = ((k*2) ^ ((r&7)<<4)) >> 1;
        float mv = 0.f;
        if (r<SS && k<SS){
            int a = k-r+3;  if (a>=0 && a<7)  mv += wki[a];
            int b2= k-r+13; if (b2>=0 && b2<28) mv += mki[b2];
        }
        o[r*64 + swz] = f2bf(mv);
        float tv = (r<SS && k<SS) ? twi[r*SS+k] : 0.f;
        o[4096 + r*64 + swz] = f2bf(tv);
        int pk = (k>>3)*512 + r*8 + (k&7);
        o[8192  + pk] = f2bf(fwi[r*HH+k]);
        o[12288 + pk] = f2bf(swi[r*HH+k]);
    }
}

// ---- prep: head_w f32 [28][5376] -> bf16 [32][5376] (pad rows zero) ----
__global__ __launch_bounds__(256) void k_prep_head(
    const float* __restrict__ hw, __hip_bfloat16* __restrict__ hw16)
{
    int i = blockIdx.x*256 + threadIdx.x;   // 32*TOT total
    int r = i / TOT, k = i - r*TOT;
    float v = (r<PP) ? hw[(size_t)r*TOT + k] : 0.f;
    hw16[i] = __float2bfloat16(v);
}

// ---- fut: feats16[bn][3584+q] = bf16(x_future @ futw^T + futb) ----
__global__ __launch_bounds__(256) void k_fut(
    const float* __restrict__ xf, const float* __restrict__ fw,
    const float* __restrict__ fbias, __hip_bfloat16* __restrict__ feats)
{
    int bn=blockIdx.x, tid=threadIdx.x;
    __shared__ float fwl[HH*FFUT];
    __shared__ float fbl[HH];
    __shared__ float xfl[PP*FFUT];
    for (int i=tid;i<HH*FFUT;i+=256) fwl[i]=fw[i];
    if (tid<HH) fbl[tid]=fbias[tid];
    for (int i=tid;i<PP*FFUT;i+=256) xfl[i]=xf[(size_t)bn*PP*FFUT+i];
    __syncthreads();
    __hip_bfloat16* dst = feats + (size_t)bn*TOT + DD;
    for (int q=tid;q<FD;q+=256){
        int pp=q>>6, hh2=q&63;
        float v=fbl[hh2];
        #pragma unroll
        for (int c2=0;c2<FFUT;++c2) v += xfl[pp*FFUT+c2]*fwl[hh2*FFUT+c2];
        dst[q]=__float2bfloat16(v);
    }
}

// ---------------- MFMA mixer block (h permuted; xpg direct-write) ----------------
__global__ __launch_bounds__(256) void k_mixer2(
    float* __restrict__ h, unsigned short* __restrict__ xpg,
    const unsigned short* __restrict__ wimg,
    const float* __restrict__ lncg, const float* __restrict__ lncb,
    const float* __restrict__ lntg, const float* __restrict__ lntb,
    const float* __restrict__ lnfg, const float* __restrict__ lnfb,
    const float* __restrict__ lnsg, const float* __restrict__ lnsb,
    const float* __restrict__ tb, const float* __restrict__ fb)
{
    int bn=blockIdx.x, tid=threadIdx.x, lane=tid&63, w=tid>>6;
    int g=lane>>4, c=lane&15;
    __shared__ unsigned short wbuf[2][4096];
    __shared__ unsigned short xs[4096];
    __shared__ float prm[640];

    const char* wsrc=(const char*)wimg;
#define LOADW(SLOTB, BUFP) do{ \
    async_load16(wsrc+(size_t)(SLOTB)+((size_t)tid)*16,       (char*)(BUFP)+(w*64)*16); \
    async_load16(wsrc+(size_t)(SLOTB)+((size_t)(256+tid))*16, (char*)(BUFP)+((256+w*64))*16); } while(0)

    LOADW(0,    wbuf[0]);
    LOADW(8192, wbuf[1]);
    if (tid<64){
        prm[tid]      =lncg[tid]; prm[64+tid] =lncb[tid];
        prm[128+tid]  =lntg[tid]; prm[192+tid]=lntb[tid];
        prm[256+tid]  =lnfg[tid]; prm[320+tid]=lnfb[tid];
        prm[384+tid]  =lnsg[tid]; prm[448+tid]=lnsb[tid];
        prm[512+tid]  =(tid<SS)?tb[tid]:0.f;
        prm[576+tid]  =fb[tid];
    }
    float xl[4][4];
    float* hb = h + (size_t)bn*DD;
    int srow = 16*w + 4*g;
    #pragma unroll
    for (int q=0;q<4;++q){
        int s=srow+q;
        if (s<SS){
            const float4 v4 = *reinterpret_cast<const float4*>(hb + s*HH + c*4);
            xl[q][0]=v4.x; xl[q][1]=v4.y; xl[q][2]=v4.z; xl[q][3]=v4.w;
        } else {
            xl[q][0]=0.f; xl[q][1]=0.f; xl[q][2]=0.f; xl[q][3]=0.f;
        }
    }
    __syncthreads();

    float xn[4][4];
    f32x4 acc[4];

#define LNSTAGE(GOFF,BOFF) do{ \
    _Pragma("unroll") \
    for (int q=0;q<4;++q){ \
        float sv = xl[q][0]+xl[q][1]+xl[q][2]+xl[q][3]; \
        float s2 = xl[q][0]*xl[q][0]+xl[q][1]*xl[q][1]+xl[q][2]*xl[q][2]+xl[q][3]*xl[q][3]; \
        _Pragma("unroll") \
        for (int m2=1;m2<16;m2<<=1){ sv += __shfl_xor(sv,m2,64); s2 += __shfl_xor(s2,m2,64); } \
        float mn = sv*(1.f/64.f); \
        float var = s2*(1.f/64.f)-mn*mn; \
        float rstd = rsqrtf(var+1e-5f); \
        bool ok = (srow+q)<SS; \
        _Pragma("unroll") \
        for (int tj=0;tj<4;++tj){ \
            float v=(xl[q][tj]-mn)*rstd*prm[(GOFF)+tj*16+c]+prm[(BOFF)+tj*16+c]; \
            xn[q][tj]= ok ? v : 0.f; \
        } \
    } }while(0)

#define WRITE_XNP() do{ \
    _Pragma("unroll") \
    for (int qp=0;qp<2;++qp){ \
        int s0=srow+2*qp; \
        _Pragma("unroll") \
        for (int tj=0;tj<4;++tj){ \
            unsigned int pv=(unsigned int)f2bf(xn[2*qp][tj])|((unsigned int)f2bf(xn[2*qp+1][tj])<<16); \
            *(unsigned int*)((char*)xs + ((s0>>3)*1024 + (tj*16+c)*16 + (s0&7)*2)) = pv; \
        } \
    } }while(0)

#define WRITE_XNR() do{ \
    _Pragma("unroll") \
    for (int q=0;q<4;++q){ int s=srow+q; \
        _Pragma("unroll") \
        for (int tj=0;tj<4;++tj){ \
            *(unsigned short*)((char*)xs + s*128 + (((tj*16+c)*2) ^ ((s&7)<<4))) = f2bf(xn[q][tj]); \
        } \
    } }while(0)

#define MM(APTR,BPTR) do{ \
    _Pragma("unroll") \
    for (int tj=0;tj<4;++tj) acc[tj]=(f32x4){0.f,0.f,0.f,0.f}; \
    _Pragma("unroll") \
    for (int kc=0;kc<2;++kc){ \
        int arow=16*w+c; \
        bf16x8 af=*(const bf16x8*)((const char*)(APTR)+arow*128+((kc*64+g*16)^((arow&7)<<4))); \
        _Pragma("unroll") \
        for (int tj=0;tj<4;++tj){ \
            bf16x8 bf2=*(const bf16x8*)((const char*)(BPTR)+(kc*4+g)*1024+(tj*16+c)*16); \
            acc[tj]=__builtin_amdgcn_mfma_f32_16x16x32_bf16(af,bf2,acc[tj],0,0,0); \
        } \
    } }while(0)

    // ---- conv (banded matmul) ----
    LNSTAGE(0,64); WRITE_XNP();
    __syncthreads();
    MM(&wbuf[0][0], xs);
    #pragma unroll
    for (int q=0;q<4;++q)
        #pragma unroll
        for (int tj=0;tj<4;++tj) xl[q][tj]+=acc[tj][q];
    __syncthreads();
    LOADW(16384, wbuf[0]);
    // ---- temporal ----
    LNSTAGE(128,192); WRITE_XNP();
    __syncthreads();
    MM(&wbuf[1][0], xs);
    #pragma unroll
    for (int q=0;q<4;++q){
        float tbv=prm[512+srow+q];
        #pragma unroll
        for (int tj=0;tj<4;++tj) xl[q][tj]+=gelu_fast(acc[tj][q]+tbv);
    }
    __syncthreads();
    LOADW(24576, wbuf[1]);
    // ---- feature ----
    LNSTAGE(256,320); WRITE_XNR();
    __syncthreads();
    MM(xs, &wbuf[0][0]);
    #pragma unroll
    for (int q=0;q<4;++q)
        #pragma unroll
        for (int tj=0;tj<4;++tj) xl[q][tj]+=gelu_fast(acc[tj][q]+prm[576+tj*16+c]);
    __syncthreads();
    // ---- spatial projection ----
    LNSTAGE(384,448); WRITE_XNR();
    __syncthreads();
    MM(xs, &wbuf[1][0]);
    int b_=bn/NN, n_=bn%NN;
    unsigned short* xpo = xpg + ((size_t)b_*(KP/8) + (size_t)(n_>>3))*(size_t)DD*8 + (n_&7);
    #pragma unroll
    for (int q=0;q<4;++q){
        int s=srow+q;
        if (s<SS){
            float4 hv; hv.x=xl[q][0]; hv.y=xl[q][1]; hv.z=xl[q][2]; hv.w=xl[q][3];
            *reinterpret_cast<float4*>(hb + s*HH + c*4) = hv;
            #pragma unroll
            for (int tj=0;tj<4;++tj){
                int d = s*HH + tj*16 + c;
                xpo[(size_t)d*8] = f2bf(acc[tj][q]);
            }
        }
    }
#undef LNSTAGE
#undef WRITE_XNP
#undef WRITE_XNR
#undef MM
#undef LOADW
}

// ---- spatial bmm via MFMA: h[b] += comb[b] @ xp[b] + sb ----
// 64x128 tile, 4 waves (2x2 of 32x64), 3-buffer depth-2 prefetch, counted vmcnt.
__global__ __launch_bounds__(256,4) void k_bmm_mfma(
    const __hip_bfloat16* __restrict__ combh,
    const __hip_bfloat16* __restrict__ xpg,
    const float* __restrict__ sb,
    float* __restrict__ h,
    __hip_bfloat16* __restrict__ h16,
    int write_h)
{
    __shared__ short As[3][2048];
    __shared__ short Bs[3][4096];

    int bid = blockIdx.x;
    int wg = (bid & 7)*336 + (bid >> 3);
    int bm = wg % 24; int tmp2 = wg / 24; int bd = tmp2 % 28; int b = tmp2 / 28;
    int tid=threadIdx.x, lane=tid&63, w=tid>>6;
    int g=lane>>4, c=lane&15;
    int wr=w>>1, wc=w&1;
    int m0=bm*64, d0=bd*128;

    const char* cb = (const char*)(combh + (size_t)b*MP*KP);
    const char* xb = (const char*)(xpg   + (size_t)b*(KP/8)*(size_t)DD*8);

    int arow_s = tid>>2, aslot = tid&3;
    int ag = aslot ^ ((arow_s>>1)&3);
    const char* srcA = cb + ((size_t)(m0+arow_s)*KP + ag*8)*2;
    int bch = tid>>7, bcol = tid&127;
    const char* srcB0 = xb + ((size_t)bch*DD + d0 + bcol)*16;
    const char* srcB1 = xb + ((size_t)(bch+2)*DD + d0 + bcol)*16;
    const size_t BSTEP = (size_t)4*DD*16;

    f32x4 acc[2][4];
    #pragma unroll
    for (int i=0;i<2;++i)
        #pragma unroll
        for (int j=0;j<4;++j) acc[i][j]=(f32x4){0.f,0.f,0.f,0.f};

    int aoff[2], boff[4];
    #pragma unroll
    for (int i=0;i<2;++i){
        int row = 32*wr + 16*i + c;
        aoff[i] = row*64 + ((g*16) ^ (((row>>1)&3)<<4));
    }
    #pragma unroll
    for (int j=0;j<4;++j) boff[j] = (g*128 + 64*wc + 16*j + c)*16;

#define STAGE(BUF,T) do { \
    async_load16(srcA  + (size_t)(T)*64,    (char*)As[BUF] + w*1024); \
    async_load16(srcB0 + (size_t)(T)*BSTEP, (char*)Bs[BUF] + w*1024); \
    async_load16(srcB1 + (size_t)(T)*BSTEP, (char*)Bs[BUF] + 4096 + w*1024); } while(0)

    STAGE(0,0); STAGE(1,1);
    asm volatile("s_waitcnt vmcnt(3)" ::: "memory");
    __builtin_amdgcn_s_barrier();

    int cur=0;
    for (int t=0;t<NT;++t){
        if (t+2<NT){
            int nb = cur+2; if (nb>=3) nb-=3;
            STAGE(nb, t+2);
        }
        const char* Ab=(const char*)As[cur];
        const char* Bb=(const char*)Bs[cur];
        bf16x8 af[2], bfv[4];
        #pragma unroll
        for (int i=0;i<2;++i) af[i]=*(const bf16x8*)(Ab + aoff[i]);
        #pragma unroll
        for (int j=0;j<4;++j) bfv[j]=*(const bf16x8*)(Bb + boff[j]);
        #pragma unroll
        for (int i=0;i<2;++i)
            #pragma unroll
            for (int j=0;j<4;++j)
                acc[i][j]=__builtin_amdgcn_mfma_f32_16x16x32_bf16(af[i],bfv[j],acc[i][j],0,0,0);
        if (t+2<NT) asm volatile("s_waitcnt vmcnt(3)" ::: "memory");
        else        asm volatile("s_waitcnt vmcnt(0)" ::: "memory");
        __builtin_amdgcn_s_barrier();
        ++cur; if (cur>=3) cur=0;
    }
#undef STAGE

    int row_b = m0 + 32*wr + g*4;
    int s2 = 2*bd + wc;
    float sb0=sb[c], sb1=sb[16+c], sb2=sb[32+c], sb3=sb[48+c];
    #pragma unroll
    for (int i=0;i<2;++i){
        #pragma unroll
        for (int q=0;q<4;++q){
            int m = row_b + 16*i + q;
            if (m < NN){
                float* hp = h + ((size_t)b*NN+m)*DD + s2*HH + c*4;
                float4 hv = *reinterpret_cast<const float4*>(hp);
                float nv0 = hv.x + acc[i][0][q] + sb0;
                float nv1 = hv.y + acc[i][1][q] + sb1;
                float nv2 = hv.z + acc[i][2][q] + sb2;
                float nv3 = hv.w + acc[i][3][q] + sb3;
                if (write_h){
                    float4 ov; ov.x=nv0; ov.y=nv1; ov.z=nv2; ov.w=nv3;
                    *reinterpret_cast<float4*>(hp) = ov;
                }
                if (h16){
                    size_t fr = ((size_t)b*NN+m)*TOT + (size_t)bd*128 + wc*64;
                    h16[fr + c]      = __float2bfloat16(nv0);
                    h16[fr + 16 + c] = __float2bfloat16(nv1);
                    h16[fr + 32 + c] = __float2bfloat16(nv2);
                    h16[fr + 48 + c] = __float2bfloat16(nv3);
                }
            }
        }
    }
}

// ---------------- head GEMM: out = feats16 @ hw16^T + hb ----------------
__global__ __launch_bounds__(256) void k_head_mfma(
    const __hip_bfloat16* __restrict__ feats, const __hip_bfloat16* __restrict__ hw16,
    const float* __restrict__ hb, float* __restrict__ out)
{
    int tid=threadIdx.x, lane=tid&63, w=tid>>6;
    int g=lane>>4, c=lane&15;
    int m0=blockIdx.x*32;
    int rt=w>>1, pt=w&1;
    int arow = m0 + rt*16 + c;
    if (arow > BB*NN-1) arow = BB*NN-1;
    const char* abase = (const char*)feats + (size_t)arow*TOT*2 + g*16;
    const char* bbase = (const char*)hw16 + (size_t)(pt*16+c)*TOT*2 + g*16;
    f32x4 acc=(f32x4){0.f,0.f,0.f,0.f};
    #pragma unroll 4
    for (int kc=0;kc<TOT/32;++kc){
        bf16x8 af =*(const bf16x8*)(abase + (size_t)kc*64);
        bf16x8 bf2=*(const bf16x8*)(bbase + (size_t)kc*64);
        acc=__builtin_amdgcn_mfma_f32_16x16x32_bf16(af,bf2,acc,0,0,0);
    }
    int col = pt*16 + c;
    #pragma unroll
    for (int q=0;q<4;++q){
        int row = m0 + rt*16 + g*4 + q;
        if (row < BB*NN && col < PP)
            out[(size_t)row*PP + col] = acc[q] + hb[col];
    }
}

extern "C" void kernel_launch(void* const* d_in, const int* in_sizes, int n_in,
                              void* d_out, int out_size, void* d_ws, size_t ws_size,
                              hipStream_t stream)
{
    const float* x      = (const float*)d_in[0];
    const float* xfut   = (const float*)d_in[1];
    const float* adj    = (const float*)d_in[2];
    const float* fp_w   = (const float*)d_in[3];
    const float* fp_b   = (const float*)d_in[4];
    const float* inlng  = (const float*)d_in[5];
    const float* inlnb  = (const float*)d_in[6];
    const float* q_w    = (const float*)d_in[7];
    const float* q_b    = (const float*)d_in[8];
    const float* k_w    = (const float*)d_in[9];
    const float* k_b    = (const float*)d_in[10];
    const float* nemb   = (const float*)d_in[11];
    const float* galpha = (const float*)d_in[12];
    const float* wk     = (const float*)d_in[13];
    const float* mk     = (const float*)d_in[14];
    const float* lncg   = (const float*)d_in[15];
    const float* lncb   = (const float*)d_in[16];
    const float* lntg   = (const float*)d_in[17];
    const float* lntb   = (const float*)d_in[18];
    const float* lnfg   = (const float*)d_in[19];
    const float* lnfb   = (const float*)d_in[20];
    const float* lnsg   = (const float*)d_in[21];
    const float* lnsb   = (const float*)d_in[22];
    const float* tw     = (const float*)d_in[23];
    const float* tb     = (const float*)d_in[24];
    const float* fw     = (const float*)d_in[25];
    const float* fb     = (const float*)d_in[26];
    const float* sw     = (const float*)d_in[27];
    const float* sb     = (const float*)d_in[28];
    const float* futw   = (const float*)d_in[29];
    const float* futb   = (const float*)d_in[30];
    const float* hw     = (const float*)d_in[31];
    const float* hb     = (const float*)d_in[32];
    (void)in_sizes; (void)n_in; (void)out_size; (void)ws_size;
    float* out = (float*)d_out;
    float* ws = (float*)d_ws;
    const size_t HSZ = (size_t)BB*NN*SS*HH;

    float* h    = ws;
    float* embn = h + HSZ;
    __hip_bfloat16* combh = (__hip_bfloat16*)(embn + (size_t)NN*HH);
    __hip_bfloat16* xpg   = combh + (size_t)BB*MP*KP;
    float* scores = (float*)xpg;   // aliased: scores dead before xpg is written
    unsigned short* wimg  = (unsigned short*)(xpg + (size_t)BB*(KP/8)*(size_t)DD*8);
    unsigned short* qpack = wimg + (size_t)NBLK*WIMG_SZ;
    unsigned short* kpack = qpack + (size_t)BB*8*MP*8;
    __hip_bfloat16* feats16 = (__hip_bfloat16*)(kpack + (size_t)BB*8*MP*8);
    __hip_bfloat16* hw16    = feats16 + (size_t)BB*NN*TOT;

    k_prepw<<<NBLK,256,0,stream>>>(wk, mk, tw, fw, sw, wimg);
    k_prep_head<<<(32*TOT)/256,256,0,stream>>>(hw, hw16);
    k_fut<<<BB*NN,256,0,stream>>>(xfut, futw, futb, feats16);
    k_embnorm<<<NN,64,0,stream>>>(nemb, embn);
    k_front<<<BB*NN,256,0,stream>>>(x, fp_w, fp_b, inlng, inlnb, embn,
                                    q_w,q_b,k_w,k_b, h, qpack, kpack);
    dim3 gqkt(MP/128, MP/128, BB);
    k_qkt<<<gqkt,256,0,stream>>>(qpack, kpack, scores);
    dim3 gtop(NN,BB);
    k_topk<<<gtop,256,0,stream>>>(scores, adj, galpha, combh);
    // zero the K-pad rows of xpg (kc in [179,184)) — scores alias is dead now
    for (int b2=0;b2<BB;++b2)
        hipMemsetAsync(xpg + ((size_t)b2*(KP/8)+179)*(size_t)DD*8, 0,
                       (size_t)5*DD*8*sizeof(__hip_bfloat16), stream);
    for (int i=0;i<NBLK;++i){
        k_mixer2<<<BB*NN,256,0,stream>>>(h, (unsigned short*)xpg, wimg + (size_t)i*WIMG_SZ,
            lncg+i*HH,lncb+i*HH, lntg+i*HH,lntb+i*HH, lnfg+i*HH,lnfb+i*HH, lnsg+i*HH,lnsb+i*HH,
            tb+i*SS, fb+i*HH);
        k_bmm_mfma<<<2688,256,0,stream>>>(combh, xpg, sb+i*HH, h,
            (i==NBLK-1) ? feats16 : (__hip_bfloat16*)nullptr,
            (i==NBLK-1) ? 0 : 1);
    }
    k_head_mfma<<<(BB*NN+31)/32,256,0,stream>>>(feats16, hw16, hb, out);
}

// Round 12
// 559.990 us; speedup vs baseline: 1.3394x; 1.0756x over previous
//
#include <hip/hip_runtime.h>
#include <hip/hip_bf16.h>
#include <math.h>

#define BB 4
#define NN 1437
#define SS 56
#define PP 28
#define FIN 10
#define FFUT 6
#define HH 64
#define NBLK 2
#define TOPK 5
#define DD (SS*HH)     /* 3584 */
#define FD (PP*HH)     /* 1792 */
#define TOT (DD+FD)    /* 5376 */
#define MP 1536        /* padded M (12*128) */
#define KP 1472        /* padded K (46*32)  */
#define NT (KP/32)     /* 46 K-steps */
#define SP 1536        /* scores stride */
#define WIMG_SZ 16384  /* shorts per mixer-block weight image */

typedef __attribute__((ext_vector_type(8))) __bf16 bf16x8;
typedef __attribute__((ext_vector_type(4))) float  f32x4;

// h lives in a permuted intra-row layout: element (s,f) at s*64 + (f&15)*4 + (f>>4).
// Consumers: k_front (write), k_mixer2 (rw), k_bmm_mfma (rw). All use this layout.

__device__ __forceinline__ float gelu_fast(float x){
    float x2 = x*x;
    float u  = __builtin_fmaf(0.044715f*x2, x, x);
    float e  = __builtin_amdgcn_exp2f(2.3022077f*u);
    float r  = __builtin_amdgcn_rcpf(e+1.f);
    return x - x*r;
}
__device__ __forceinline__ float wave_sum64(float v){
    #pragma unroll
    for (int o=1;o<64;o<<=1) v += __shfl_xor(v,o,64);
    return v;
}
__device__ __forceinline__ void async_load16(const void* g, void* l){
    __builtin_amdgcn_global_load_lds(
        (const __attribute__((address_space(1))) void*)g,
        (__attribute__((address_space(3))) void*)l, 16, 0, 0);
}
__device__ __forceinline__ unsigned short f2bf(float x){
    unsigned int u = __float_as_uint(x);
    unsigned int r = (u + 0x7fffu + ((u>>16)&1u)) >> 16;
    return (unsigned short)r;
}
__device__ __forceinline__ unsigned long long umax64(unsigned long long a, unsigned long long b){return a>b?a:b;}
__device__ __forceinline__ unsigned long long umin64(unsigned long long a, unsigned long long b){return a<b?a:b;}

// ---------------- emb norm ----------------
__global__ __launch_bounds__(64) void k_embnorm(const float* __restrict__ emb,
                                                float* __restrict__ out){
    int n = blockIdx.x; int l = threadIdx.x;
    float v = emb[(size_t)n*HH+l];
    float ss = wave_sum64(v*v);
    float nrm = fmaxf(sqrtf(ss), 1e-12f);
    out[(size_t)n*HH+l] = v/nrm;
}

// ------- front: h = LN(x@fp_w^T+fp_b)+embn ; ctx -> Q/K packed bf16 -------
__global__ __launch_bounds__(256) void k_front(
    const float* __restrict__ x, const float* __restrict__ fpw, const float* __restrict__ fpb,
    const float* __restrict__ lng, const float* __restrict__ lnb,
    const float* __restrict__ embn,
    const float* __restrict__ qw, const float* __restrict__ qb,
    const float* __restrict__ kw, const float* __restrict__ kb,
    float* __restrict__ h,
    unsigned short* __restrict__ qpack, unsigned short* __restrict__ kpack)
{
    int bn = blockIdx.x; int n = bn % NN;
    int tid=threadIdx.x; int lane=tid&63; int wv=tid>>6;
    __shared__ float xin[SS*FIN];
    __shared__ float wlds[HH*FIN];
    __shared__ float rw[SS];
    __shared__ float rsum;
    __shared__ float red[4][HH];
    __shared__ float ctxs[HH];
    for (int i=tid;i<SS*FIN;i+=256) xin[i]=x[(size_t)bn*SS*FIN+i];
    for (int i=tid;i<HH*FIN;i+=256) wlds[i]=fpw[i];
    if (tid<SS) rw[tid]=expf(-(float)(SS-tid)/14.0f);
    __syncthreads();
    if (tid==0){ float s=0.f; for(int i=0;i<SS;++i) s+=rw[i]; rsum=s; }
    __syncthreads();
    float inv_rs = 1.0f/rsum;
    float gg=lng[lane], bv=lnb[lane], el=embn[(size_t)n*HH+lane], fb0=fpb[lane];
    int paddr = (lane&15)*4 + (lane>>4);
    float cacc=0.f;
    for (int s=wv;s<SS;s+=4){
        float v=fb0;
        #pragma unroll
        for (int c=0;c<FIN;++c) v += xin[s*FIN+c]*wlds[lane*FIN+c];
        float m = wave_sum64(v)*(1.f/HH);
        float d = v-m;
        float va = wave_sum64(d*d)*(1.f/HH);
        float hn = d*rsqrtf(va+1e-5f)*gg + bv + el;
        h[((size_t)bn*SS+s)*HH + paddr]=hn;
        cacc += hn * rw[s]*inv_rs;
    }
    red[wv][lane]=cacc;
    __syncthreads();
    if (wv==0) ctxs[lane]=red[0][lane]+red[1][lane]+red[2][lane]+red[3][lane];
    __syncthreads();
    if (wv==0){
        const float4* qr = reinterpret_cast<const float4*>(qw + (size_t)lane*HH);
        const float4* kr = reinterpret_cast<const float4*>(kw + (size_t)lane*HH);
        float q=qb[lane], k=kb[lane];
        #pragma unroll 4
        for (int t=0;t<16;++t){
            float4 qv=qr[t], kv=kr[t];
            float c0=ctxs[4*t], c1=ctxs[4*t+1], c2=ctxs[4*t+2], c3=ctxs[4*t+3];
            q += qv.x*c0+qv.y*c1+qv.z*c2+qv.w*c3;
            k += kv.x*c0+kv.y*c1+kv.z*c2+kv.w*c3;
        }
        int b = bn/NN, m = bn%NN;
        size_t off = (size_t)b*8*MP*8 + (size_t)(lane>>3)*MP*8 + (size_t)m*8 + (lane&7);
        qpack[off]=f2bf(q); kpack[off]=f2bf(k);
    }
}

// ---------------- QK^T via MFMA -> scores = relu(clip(QK^T/8)) f32 ----------------
__global__ __launch_bounds__(256) void k_qkt(
    const unsigned short* __restrict__ qp, const unsigned short* __restrict__ kp,
    float* __restrict__ scores)
{
    int bm=blockIdx.x, bnn=blockIdx.y, b=blockIdx.z;
    int tid=threadIdx.x, lane=tid&63, wv=tid>>6;
    int g=lane>>4, c15=lane&15;
    int m0=bm*128, n0=bnn*128;
    __shared__ unsigned short As[8192];  // [8][128][8]
    __shared__ unsigned short Bs[8192];
    const char* qbase = (const char*)(qp + (size_t)b*8*MP*8);
    const char* kbase = (const char*)(kp + (size_t)b*8*MP*8);
    #pragma unroll
    for (int i=0;i<4;++i){
        int idx=i*256+tid; int ch=idx>>7, r=idx&127;
        async_load16(qbase + ((size_t)(ch*MP + m0 + r))*16, (char*)As + idx*16);
        async_load16(kbase + ((size_t)(ch*MP + n0 + r))*16, (char*)Bs + idx*16);
    }
    asm volatile("s_waitcnt vmcnt(0)");
    __syncthreads();
    int wr=wv>>1, wc=wv&1;
    f32x4 acc[4][4];
    #pragma unroll
    for (int i=0;i<4;++i)
        #pragma unroll
        for (int j=0;j<4;++j) acc[i][j]=(f32x4){0.f,0.f,0.f,0.f};
    #pragma unroll
    for (int kc=0;kc<2;++kc){
        bf16x8 af[4], bfv[4];
        #pragma unroll
        for (int i=0;i<4;++i)
            af[i]=*(const bf16x8*)((const char*)As + ((4*kc+g)*128 + wr*64+i*16+c15)*16);
        #pragma unroll
        for (int j=0;j<4;++j)
            bfv[j]=*(const bf16x8*)((const char*)Bs + ((4*kc+g)*128 + wc*64+j*16+c15)*16);
        #pragma unroll
        for (int i=0;i<4;++i)
            #pragma unroll
            for (int j=0;j<4;++j)
                acc[i][j]=__builtin_amdgcn_mfma_f32_16x16x32_bf16(af[i],bfv[j],acc[i][j],0,0,0);
    }
    #pragma unroll
    for (int i=0;i<4;++i){
        #pragma unroll
        for (int q=0;q<4;++q){
            int m = m0 + wr*64 + i*16 + g*4 + q;
            float* sr = scores + ((size_t)b*SP + m)*SP + n0 + wc*64 + c15;
            #pragma unroll
            for (int j=0;j<4;++j){
                float v = acc[i][j][q]*0.125f;
                v = fminf(fmaxf(v,0.f),10.f);
                sr[j*16]=v;
            }
        }
    }
}

// ---- top-5 + softmax + blend + L1 normalize -> comb bf16 [b][MP][KP] ----
#define INS(x) do{ unsigned long long t_=(x); \
    unsigned long long n0_=umax64(u0,t_), t1_=umin64(u0,t_); \
    unsigned long long n1_=umax64(u1,t1_), t2_=umin64(u1,t1_); \
    unsigned long long n2_=umax64(u2,t2_), t3_=umin64(u2,t2_); \
    unsigned long long n3_=umax64(u3,t3_), t4_=umin64(u3,t3_); \
    unsigned long long n4_=umax64(u4,t4_); \
    u0=n0_;u1=n1_;u2=n2_;u3=n3_;u4=n4_; }while(0)

#define MERGE(b0,b1,b2,b3,b4) do{ \
    unsigned long long o0_=umax64(u0,(b0)); \
    unsigned long long o1_=umax64(umax64((b1),umin64(u0,(b0))),u1); \
    unsigned long long o2_=umax64(umax64((b2),umin64(u0,(b1))),umax64(umin64(u1,(b0)),u2)); \
    unsigned long long o3_=umax64(umax64((b3),umin64(u0,(b2))),umax64(umin64(u1,(b1)),umax64(umin64(u2,(b0)),u3))); \
    unsigned long long o4_=umax64(umax64((b4),umin64(u0,(b3))),umax64(umax64(umin64(u1,(b2)),umin64(u2,(b1))),umax64(umin64(u3,(b0)),u4))); \
    u0=o0_;u1=o1_;u2=o2_;u3=o3_;u4=o4_; }while(0)

__global__ __launch_bounds__(256) void k_topk(
    const float* __restrict__ scores, const float* __restrict__ adj,
    const float* __restrict__ galpha, __hip_bfloat16* __restrict__ combh)
{
    int m=blockIdx.x, b=blockIdx.y, tid=threadIdx.x, lane=tid&63, wv=tid>>6;
    __shared__ float row[KP];
    __shared__ unsigned long long wtop[4][8];
    __shared__ float redp[4];
    const float* srow = scores + ((size_t)b*SP + m)*SP;
    unsigned long long u0=0,u1=0,u2=0,u3=0,u4=0;
    for (int n=tid;n<NN;n+=256){
        float v=srow[n];
        unsigned long long key=((unsigned long long)__float_as_uint(v)<<32)|(unsigned long long)(0xFFFFFFFFu-(unsigned)n);
        INS(key);
    }
    #pragma unroll
    for (int off=1; off<64; off<<=1){
        unsigned long long b0=__shfl_xor(u0,off,64), b1=__shfl_xor(u1,off,64),
                           b2=__shfl_xor(u2,off,64), b3=__shfl_xor(u3,off,64),
                           b4=__shfl_xor(u4,off,64);
        MERGE(b0,b1,b2,b3,b4);
    }
    if (lane==0){ wtop[wv][0]=u0; wtop[wv][1]=u1; wtop[wv][2]=u2; wtop[wv][3]=u3; wtop[wv][4]=u4; }
    __syncthreads();
    u0=wtop[0][0]; u1=wtop[0][1]; u2=wtop[0][2]; u3=wtop[0][3]; u4=wtop[0][4];
    #pragma unroll
    for (int w2=1;w2<4;++w2)
        MERGE(wtop[w2][0],wtop[w2][1],wtop[w2][2],wtop[w2][3],wtop[w2][4]);

    float s0=__uint_as_float((unsigned)(u0>>32)), s1=__uint_as_float((unsigned)(u1>>32)),
          s2=__uint_as_float((unsigned)(u2>>32)), s3=__uint_as_float((unsigned)(u3>>32)),
          s4=__uint_as_float((unsigned)(u4>>32));
    int i0=(int)(0xFFFFFFFFu-(unsigned)u0), i1=(int)(0xFFFFFFFFu-(unsigned)u1),
        i2=(int)(0xFFFFFFFFu-(unsigned)u2), i3=(int)(0xFFFFFFFFu-(unsigned)u3),
        i4=(int)(0xFFFFFFFFu-(unsigned)u4);
    float e0=1.f, e1=expf(s1-s0), e2=expf(s2-s0), e3=expf(s3-s0), e4=expf(s4-s0);
    float den=e0+e1+e2+e3+e4;
    float alpha=1.f/(1.f+expf(-galpha[0]));
    float oma=(1.f-alpha)/den;
    float p0=oma*e0, p1=oma*e1, p2=oma*e2, p3=oma*e3, p4=oma*e4;

    const float* arow = adj + (size_t)m*NN;
    float part=0.f;
    for (int n=tid;n<NN;n+=256){
        float v=alpha*arow[n];
        v += (n==i0)?p0:0.f;
        v += (n==i1)?p1:0.f;
        v += (n==i2)?p2:0.f;
        v += (n==i3)?p3:0.f;
        v += (n==i4)?p4:0.f;
        row[n]=v;
        part+=fabsf(v);
    }
    part=wave_sum64(part);
    if (lane==0) redp[wv]=part;
    __syncthreads();
    float inv=1.f/fmaxf(redp[0]+redp[1]+redp[2]+redp[3],1e-12f);
    __hip_bfloat16* dst = combh + ((size_t)b*MP+m)*KP;
    for (int n=tid;n<KP;n+=256){
        float v = (n<NN) ? row[n]*inv : 0.f;
        dst[n]=__float2bfloat16(v);
    }
}
#undef INS
#undef MERGE

// ---- prep: build per-mixer-block bf16 weight images ----
__global__ __launch_bounds__(256) void k_prepw(
    const float* __restrict__ wk, const float* __restrict__ mk,
    const float* __restrict__ tw, const float* __restrict__ fw,
    const float* __restrict__ sw, unsigned short* __restrict__ wimg)
{
    int i = blockIdx.x; int tid = threadIdx.x;
    const float* wki = wk + i*7;
    const float* mki = mk + i*28;
    const float* twi = tw + i*SS*SS;
    const float* fwi = fw + i*HH*HH;
    const float* swi = sw + i*HH*HH;
    unsigned short* o = wimg + (size_t)i*WIMG_SZ;
    for (int e=tid; e<4096; e+=256){
        int r = e>>6, k = e&63;
        int swz = ((k*2) ^ ((r&7)<<4)) >> 1;
        float mv = 0.f;
        if (r<SS && k<SS){
            int a = k-r+3;  if (a>=0 && a<7)  mv += wki[a];
            int b2= k-r+13; if (b2>=0 && b2<28) mv += mki[b2];
        }
        o[r*64 + swz] = f2bf(mv);
        float tv = (r<SS && k<SS) ? twi[r*SS+k] : 0.f;
        o[4096 + r*64 + swz] = f2bf(tv);
        int pk = (k>>3)*512 + r*8 + (k&7);
        o[8192  + pk] = f2bf(fwi[r*HH+k]);
        o[12288 + pk] = f2bf(swi[r*HH+k]);
    }
}

// ---- prep: head_w f32 [28][5376] -> bf16 [32][5376] (pad rows zero) ----
__global__ __launch_bounds__(256) void k_prep_head(
    const float* __restrict__ hw, __hip_bfloat16* __restrict__ hw16)
{
    int i = blockIdx.x*256 + threadIdx.x;   // 32*TOT total
    int r = i / TOT, k = i - r*TOT;
    float v = (r<PP) ? hw[(size_t)r*TOT + k] : 0.f;
    hw16[i] = __float2bfloat16(v);
}

// ---- fut: feats16[bn][3584+q] = bf16(x_future @ futw^T + futb) ----
__global__ __launch_bounds__(256) void k_fut(
    const float* __restrict__ xf, const float* __restrict__ fw,
    const float* __restrict__ fbias, __hip_bfloat16* __restrict__ feats)
{
    int bn=blockIdx.x, tid=threadIdx.x;
    __shared__ float fwl[HH*FFUT];
    __shared__ float fbl[HH];
    __shared__ float xfl[PP*FFUT];
    for (int i=tid;i<HH*FFUT;i+=256) fwl[i]=fw[i];
    if (tid<HH) fbl[tid]=fbias[tid];
    for (int i=tid;i<PP*FFUT;i+=256) xfl[i]=xf[(size_t)bn*PP*FFUT+i];
    __syncthreads();
    __hip_bfloat16* dst = feats + (size_t)bn*TOT + DD;
    for (int q=tid;q<FD;q+=256){
        int pp=q>>6, hh2=q&63;
        float v=fbl[hh2];
        #pragma unroll
        for (int c2=0;c2<FFUT;++c2) v += xfl[pp*FFUT+c2]*fwl[hh2*FFUT+c2];
        dst[q]=__float2bfloat16(v);
    }
}

// ---------------- MFMA mixer block (h permuted; xpg direct-write; XCD-chunked grid) ----------------
__global__ __launch_bounds__(256) void k_mixer2(
    float* __restrict__ h, unsigned short* __restrict__ xpg,
    const unsigned short* __restrict__ wimg,
    const float* __restrict__ lncg, const float* __restrict__ lncb,
    const float* __restrict__ lntg, const float* __restrict__ lntb,
    const float* __restrict__ lnfg, const float* __restrict__ lnfb,
    const float* __restrict__ lnsg, const float* __restrict__ lnsb,
    const float* __restrict__ tb, const float* __restrict__ fb)
{
    // XCD-chunked block->node map: the 8 nodes sharing an xpg 16B line run on the
    // same XCD so their 2B stores merge in that XCD's L2. 5748 = 4*719 + 4*718.
    int bid = blockIdx.x;
    int xx = bid & 7, ii = bid >> 3;
    int bn = (xx < 4) ? xx*719 + ii : 2876 + (xx-4)*718 + ii;
    int tid=threadIdx.x, lane=tid&63, w=tid>>6;
    int g=lane>>4, c=lane&15;
    __shared__ unsigned short wbuf[2][4096];
    __shared__ unsigned short xs[4096];
    __shared__ float prm[640];

    const char* wsrc=(const char*)wimg;
#define LOADW(SLOTB, BUFP) do{ \
    async_load16(wsrc+(size_t)(SLOTB)+((size_t)tid)*16,       (char*)(BUFP)+(w*64)*16); \
    async_load16(wsrc+(size_t)(SLOTB)+((size_t)(256+tid))*16, (char*)(BUFP)+((256+w*64))*16); } while(0)

    LOADW(0,    wbuf[0]);
    LOADW(8192, wbuf[1]);
    if (tid<64){
        prm[tid]      =lncg[tid]; prm[64+tid] =lncb[tid];
        prm[128+tid]  =lntg[tid]; prm[192+tid]=lntb[tid];
        prm[256+tid]  =lnfg[tid]; prm[320+tid]=lnfb[tid];
        prm[384+tid]  =lnsg[tid]; prm[448+tid]=lnsb[tid];
        prm[512+tid]  =(tid<SS)?tb[tid]:0.f;
        prm[576+tid]  =fb[tid];
    }
    float xl[4][4];
    float* hb = h + (size_t)bn*DD;
    int srow = 16*w + 4*g;
    #pragma unroll
    for (int q=0;q<4;++q){
        int s=srow+q;
        if (s<SS){
            const float4 v4 = *reinterpret_cast<const float4*>(hb + s*HH + c*4);
            xl[q][0]=v4.x; xl[q][1]=v4.y; xl[q][2]=v4.z; xl[q][3]=v4.w;
        } else {
            xl[q][0]=0.f; xl[q][1]=0.f; xl[q][2]=0.f; xl[q][3]=0.f;
        }
    }
    __syncthreads();

    float xn[4][4];
    f32x4 acc[4];

#define LNSTAGE(GOFF,BOFF) do{ \
    _Pragma("unroll") \
    for (int q=0;q<4;++q){ \
        float sv = xl[q][0]+xl[q][1]+xl[q][2]+xl[q][3]; \
        float s2 = xl[q][0]*xl[q][0]+xl[q][1]*xl[q][1]+xl[q][2]*xl[q][2]+xl[q][3]*xl[q][3]; \
        _Pragma("unroll") \
        for (int m2=1;m2<16;m2<<=1){ sv += __shfl_xor(sv,m2,64); s2 += __shfl_xor(s2,m2,64); } \
        float mn = sv*(1.f/64.f); \
        float var = s2*(1.f/64.f)-mn*mn; \
        float rstd = rsqrtf(var+1e-5f); \
        bool ok = (srow+q)<SS; \
        _Pragma("unroll") \
        for (int tj=0;tj<4;++tj){ \
            float v=(xl[q][tj]-mn)*rstd*prm[(GOFF)+tj*16+c]+prm[(BOFF)+tj*16+c]; \
            xn[q][tj]= ok ? v : 0.f; \
        } \
    } }while(0)

#define WRITE_XNP() do{ \
    _Pragma("unroll") \
    for (int qp=0;qp<2;++qp){ \
        int s0=srow+2*qp; \
        _Pragma("unroll") \
        for (int tj=0;tj<4;++tj){ \
            unsigned int pv=(unsigned int)f2bf(xn[2*qp][tj])|((unsigned int)f2bf(xn[2*qp+1][tj])<<16); \
            *(unsigned int*)((char*)xs + ((s0>>3)*1024 + (tj*16+c)*16 + (s0&7)*2)) = pv; \
        } \
    } }while(0)

#define WRITE_XNR() do{ \
    _Pragma("unroll") \
    for (int q=0;q<4;++q){ int s=srow+q; \
        _Pragma("unroll") \
        for (int tj=0;tj<4;++tj){ \
            *(unsigned short*)((char*)xs + s*128 + (((tj*16+c)*2) ^ ((s&7)<<4))) = f2bf(xn[q][tj]); \
        } \
    } }while(0)

#define MM(APTR,BPTR) do{ \
    _Pragma("unroll") \
    for (int tj=0;tj<4;++tj) acc[tj]=(f32x4){0.f,0.f,0.f,0.f}; \
    _Pragma("unroll") \
    for (int kc=0;kc<2;++kc){ \
        int arow=16*w+c; \
        bf16x8 af=*(const bf16x8*)((const char*)(APTR)+arow*128+((kc*64+g*16)^((arow&7)<<4))); \
        _Pragma("unroll") \
        for (int tj=0;tj<4;++tj){ \
            bf16x8 bf2=*(const bf16x8*)((const char*)(BPTR)+(kc*4+g)*1024+(tj*16+c)*16); \
            acc[tj]=__builtin_amdgcn_mfma_f32_16x16x32_bf16(af,bf2,acc[tj],0,0,0); \
        } \
    } }while(0)

    // ---- conv (banded matmul) ----
    LNSTAGE(0,64); WRITE_XNP();
    __syncthreads();
    MM(&wbuf[0][0], xs);
    #pragma unroll
    for (int q=0;q<4;++q)
        #pragma unroll
        for (int tj=0;tj<4;++tj) xl[q][tj]+=acc[tj][q];
    __syncthreads();
    LOADW(16384, wbuf[0]);
    // ---- temporal ----
    LNSTAGE(128,192); WRITE_XNP();
    __syncthreads();
    MM(&wbuf[1][0], xs);
    #pragma unroll
    for (int q=0;q<4;++q){
        float tbv=prm[512+srow+q];
        #pragma unroll
        for (int tj=0;tj<4;++tj) xl[q][tj]+=gelu_fast(acc[tj][q]+tbv);
    }
    __syncthreads();
    LOADW(24576, wbuf[1]);
    // ---- feature ----
    LNSTAGE(256,320); WRITE_XNR();
    __syncthreads();
    MM(xs, &wbuf[0][0]);
    #pragma unroll
    for (int q=0;q<4;++q)
        #pragma unroll
        for (int tj=0;tj<4;++tj) xl[q][tj]+=gelu_fast(acc[tj][q]+prm[576+tj*16+c]);
    __syncthreads();
    // ---- spatial projection ----
    LNSTAGE(384,448); WRITE_XNR();
    __syncthreads();
    MM(xs, &wbuf[1][0]);
    int b_=bn/NN, n_=bn%NN;
    unsigned short* xpo = xpg + ((size_t)b_*(KP/8) + (size_t)(n_>>3))*(size_t)DD*8 + (n_&7);
    #pragma unroll
    for (int q=0;q<4;++q){
        int s=srow+q;
        if (s<SS){
            float4 hv; hv.x=xl[q][0]; hv.y=xl[q][1]; hv.z=xl[q][2]; hv.w=xl[q][3];
            *reinterpret_cast<float4*>(hb + s*HH + c*4) = hv;
            #pragma unroll
            for (int tj=0;tj<4;++tj){
                int d = s*HH + tj*16 + c;
                xpo[(size_t)d*8] = f2bf(acc[tj][q]);
            }
        }
    }
#undef LNSTAGE
#undef WRITE_XNP
#undef WRITE_XNR
#undef MM
#undef LOADW
}

// ---- spatial bmm via MFMA: h[b] += comb[b] @ xp[b] + sb ----
// 64x128 tile, 4 waves (2x2 of 32x64), 3-buffer depth-2 prefetch, counted vmcnt.
__global__ __launch_bounds__(256,4) void k_bmm_mfma(
    const __hip_bfloat16* __restrict__ combh,
    const __hip_bfloat16* __restrict__ xpg,
    const float* __restrict__ sb,
    float* __restrict__ h,
    __hip_bfloat16* __restrict__ h16,
    int write_h)
{
    __shared__ short As[3][2048];
    __shared__ short Bs[3][4096];

    int bid = blockIdx.x;
    int wg = (bid & 7)*336 + (bid >> 3);
    int bm = wg % 24; int tmp2 = wg / 24; int bd = tmp2 % 28; int b = tmp2 / 28;
    int tid=threadIdx.x, lane=tid&63, w=tid>>6;
    int g=lane>>4, c=lane&15;
    int wr=w>>1, wc=w&1;
    int m0=bm*64, d0=bd*128;

    const char* cb = (const char*)(combh + (size_t)b*MP*KP);
    const char* xb = (const char*)(xpg   + (size_t)b*(KP/8)*(size_t)DD*8);

    int arow_s = tid>>2, aslot = tid&3;
    int ag = aslot ^ ((arow_s>>1)&3);
    const char* srcA = cb + ((size_t)(m0+arow_s)*KP + ag*8)*2;
    int bch = tid>>7, bcol = tid&127;
    const char* srcB0 = xb + ((size_t)bch*DD + d0 + bcol)*16;
    const char* srcB1 = xb + ((size_t)(bch+2)*DD + d0 + bcol)*16;
    const size_t BSTEP = (size_t)4*DD*16;

    f32x4 acc[2][4];
    #pragma unroll
    for (int i=0;i<2;++i)
        #pragma unroll
        for (int j=0;j<4;++j) acc[i][j]=(f32x4){0.f,0.f,0.f,0.f};

    int aoff[2], boff[4];
    #pragma unroll
    for (int i=0;i<2;++i){
        int row = 32*wr + 16*i + c;
        aoff[i] = row*64 + ((g*16) ^ (((row>>1)&3)<<4));
    }
    #pragma unroll
    for (int j=0;j<4;++j) boff[j] = (g*128 + 64*wc + 16*j + c)*16;

#define STAGE(BUF,T) do { \
    async_load16(srcA  + (size_t)(T)*64,    (char*)As[BUF] + w*1024); \
    async_load16(srcB0 + (size_t)(T)*BSTEP, (char*)Bs[BUF] + w*1024); \
    async_load16(srcB1 + (size_t)(T)*BSTEP, (char*)Bs[BUF] + 4096 + w*1024); } while(0)

    STAGE(0,0); STAGE(1,1);
    asm volatile("s_waitcnt vmcnt(3)" ::: "memory");
    __builtin_amdgcn_s_barrier();

    int cur=0;
    for (int t=0;t<NT;++t){
        if (t+2<NT){
            int nb = cur+2; if (nb>=3) nb-=3;
            STAGE(nb, t+2);
        }
        const char* Ab=(const char*)As[cur];
        const char* Bb=(const char*)Bs[cur];
        bf16x8 af[2], bfv[4];
        #pragma unroll
        for (int i=0;i<2;++i) af[i]=*(const bf16x8*)(Ab + aoff[i]);
        #pragma unroll
        for (int j=0;j<4;++j) bfv[j]=*(const bf16x8*)(Bb + boff[j]);
        #pragma unroll
        for (int i=0;i<2;++i)
            #pragma unroll
            for (int j=0;j<4;++j)
                acc[i][j]=__builtin_amdgcn_mfma_f32_16x16x32_bf16(af[i],bfv[j],acc[i][j],0,0,0);
        if (t+2<NT) asm volatile("s_waitcnt vmcnt(3)" ::: "memory");
        else        asm volatile("s_waitcnt vmcnt(0)" ::: "memory");
        __builtin_amdgcn_s_barrier();
        ++cur; if (cur>=3) cur=0;
    }
#undef STAGE

    int row_b = m0 + 32*wr + g*4;
    int s2 = 2*bd + wc;
    float sb0=sb[c], sb1=sb[16+c], sb2=sb[32+c], sb3=sb[48+c];
    #pragma unroll
    for (int i=0;i<2;++i){
        #pragma unroll
        for (int q=0;q<4;++q){
            int m = row_b + 16*i + q;
            if (m < NN){
                float* hp = h + ((size_t)b*NN+m)*DD + s2*HH + c*4;
                float4 hv = *reinterpret_cast<const float4*>(hp);
                float nv0 = hv.x + acc[i][0][q] + sb0;
                float nv1 = hv.y + acc[i][1][q] + sb1;
                float nv2 = hv.z + acc[i][2][q] + sb2;
                float nv3 = hv.w + acc[i][3][q] + sb3;
                if (write_h){
                    float4 ov; ov.x=nv0; ov.y=nv1; ov.z=nv2; ov.w=nv3;
                    *reinterpret_cast<float4*>(hp) = ov;
                }
                if (h16){
                    size_t fr = ((size_t)b*NN+m)*TOT + (size_t)bd*128 + wc*64;
                    h16[fr + c]      = __float2bfloat16(nv0);
                    h16[fr + 16 + c] = __float2bfloat16(nv1);
                    h16[fr + 32 + c] = __float2bfloat16(nv2);
                    h16[fr + 48 + c] = __float2bfloat16(nv3);
                }
            }
        }
    }
}

// ---------------- head GEMM: out = feats16 @ hw16^T + hb ----------------
__global__ __launch_bounds__(256) void k_head_mfma(
    const __hip_bfloat16* __restrict__ feats, const __hip_bfloat16* __restrict__ hw16,
    const float* __restrict__ hb, float* __restrict__ out)
{
    int tid=threadIdx.x, lane=tid&63, w=tid>>6;
    int g=lane>>4, c=lane&15;
    int m0=blockIdx.x*32;
    int rt=w>>1, pt=w&1;
    int arow = m0 + rt*16 + c;
    if (arow > BB*NN-1) arow = BB*NN-1;
    const char* abase = (const char*)feats + (size_t)arow*TOT*2 + g*16;
    const char* bbase = (const char*)hw16 + (size_t)(pt*16+c)*TOT*2 + g*16;
    f32x4 acc=(f32x4){0.f,0.f,0.f,0.f};
    #pragma unroll 4
    for (int kc=0;kc<TOT/32;++kc){
        bf16x8 af =*(const bf16x8*)(abase + (size_t)kc*64);
        bf16x8 bf2=*(const bf16x8*)(bbase + (size_t)kc*64);
        acc=__builtin_amdgcn_mfma_f32_16x16x32_bf16(af,bf2,acc,0,0,0);
    }
    int col = pt*16 + c;
    #pragma unroll
    for (int q=0;q<4;++q){
        int row = m0 + rt*16 + g*4 + q;
        if (row < BB*NN && col < PP)
            out[(size_t)row*PP + col] = acc[q] + hb[col];
    }
}

extern "C" void kernel_launch(void* const* d_in, const int* in_sizes, int n_in,
                              void* d_out, int out_size, void* d_ws, size_t ws_size,
                              hipStream_t stream)
{
    const float* x      = (const float*)d_in[0];
    const float* xfut   = (const float*)d_in[1];
    const float* adj    = (const float*)d_in[2];
    const float* fp_w   = (const float*)d_in[3];
    const float* fp_b   = (const float*)d_in[4];
    const float* inlng  = (const float*)d_in[5];
    const float* inlnb  = (const float*)d_in[6];
    const float* q_w    = (const float*)d_in[7];
    const float* q_b    = (const float*)d_in[8];
    const float* k_w    = (const float*)d_in[9];
    const float* k_b    = (const float*)d_in[10];
    const float* nemb   = (const float*)d_in[11];
    const float* galpha = (const float*)d_in[12];
    const float* wk     = (const float*)d_in[13];
    const float* mk     = (const float*)d_in[14];
    const float* lncg   = (const float*)d_in[15];
    const float* lncb   = (const float*)d_in[16];
    const float* lntg   = (const float*)d_in[17];
    const float* lntb   = (const float*)d_in[18];
    const float* lnfg   = (const float*)d_in[19];
    const float* lnfb   = (const float*)d_in[20];
    const float* lnsg   = (const float*)d_in[21];
    const float* lnsb   = (const float*)d_in[22];
    const float* tw     = (const float*)d_in[23];
    const float* tb     = (const float*)d_in[24];
    const float* fw     = (const float*)d_in[25];
    const float* fb     = (const float*)d_in[26];
    const float* sw     = (const float*)d_in[27];
    const float* sb     = (const float*)d_in[28];
    const float* futw   = (const float*)d_in[29];
    const float* futb   = (const float*)d_in[30];
    const float* hw     = (const float*)d_in[31];
    const float* hb     = (const float*)d_in[32];
    (void)in_sizes; (void)n_in; (void)out_size; (void)ws_size;
    float* out = (float*)d_out;
    float* ws = (float*)d_ws;
    const size_t HSZ = (size_t)BB*NN*SS*HH;

    float* h    = ws;
    float* embn = h + HSZ;
    __hip_bfloat16* combh = (__hip_bfloat16*)(embn + (size_t)NN*HH);
    __hip_bfloat16* xpg   = combh + (size_t)BB*MP*KP;
    float* scores = (float*)xpg;   // aliased: scores dead before xpg is written
    unsigned short* wimg  = (unsigned short*)(xpg + (size_t)BB*(KP/8)*(size_t)DD*8);
    unsigned short* qpack = wimg + (size_t)NBLK*WIMG_SZ;
    unsigned short* kpack = qpack + (size_t)BB*8*MP*8;
    __hip_bfloat16* feats16 = (__hip_bfloat16*)(kpack + (size_t)BB*8*MP*8);
    __hip_bfloat16* hw16    = feats16 + (size_t)BB*NN*TOT;

    k_prepw<<<NBLK,256,0,stream>>>(wk, mk, tw, fw, sw, wimg);
    k_prep_head<<<(32*TOT)/256,256,0,stream>>>(hw, hw16);
    k_fut<<<BB*NN,256,0,stream>>>(xfut, futw, futb, feats16);
    k_embnorm<<<NN,64,0,stream>>>(nemb, embn);
    k_front<<<BB*NN,256,0,stream>>>(x, fp_w, fp_b, inlng, inlnb, embn,
                                    q_w,q_b,k_w,k_b, h, qpack, kpack);
    dim3 gqkt(MP/128, MP/128, BB);
    k_qkt<<<gqkt,256,0,stream>>>(qpack, kpack, scores);
    dim3 gtop(NN,BB);
    k_topk<<<gtop,256,0,stream>>>(scores, adj, galpha, combh);
    // zero the K-pad rows of xpg (kc in [179,184)) — scores alias is dead now
    for (int b2=0;b2<BB;++b2)
        hipMemsetAsync(xpg + ((size_t)b2*(KP/8)+179)*(size_t)DD*8, 0,
                       (size_t)5*DD*8*sizeof(__hip_bfloat16), stream);
    for (int i=0;i<NBLK;++i){
        k_mixer2<<<BB*NN,256,0,stream>>>(h, (unsigned short*)xpg, wimg + (size_t)i*WIMG_SZ,
            lncg+i*HH,lncb+i*HH, lntg+i*HH,lntb+i*HH, lnfg+i*HH,lnfb+i*HH, lnsg+i*HH,lnsb+i*HH,
            tb+i*SS, fb+i*HH);
        k_bmm_mfma<<<2688,256,0,stream>>>(combh, xpg, sb+i*HH, h,
            (i==NBLK-1) ? feats16 : (__hip_bfloat16*)nullptr,
            (i==NBLK-1) ? 0 : 1);
    }
    k_head_mfma<<<(BB*NN+31)/32,256,0,stream>>>(feats16, hw16, hb, out);
}

// Round 13
// 510.557 us; speedup vs baseline: 1.4690x; 1.0968x over previous
//
#include <hip/hip_runtime.h>
#include <hip/hip_bf16.h>
#include <math.h>

#define BB 4
#define NN 1437
#define SS 56
#define PP 28
#define FIN 10
#define FFUT 6
#define HH 64
#define NBLK 2
#define TOPK 5
#define DD (SS*HH)     /* 3584 */
#define FD (PP*HH)     /* 1792 */
#define TOT (DD+FD)    /* 5376 */
#define MP 1536        /* padded M (12*128) */
#define KP 1472        /* padded K (46*32)  */
#define NT (KP/32)     /* 46 K-steps */
#define SP 1536        /* scores stride */
#define WIMG_SZ 16384  /* shorts per mixer-block weight image */

typedef __attribute__((ext_vector_type(8))) __bf16 bf16x8;
typedef __attribute__((ext_vector_type(4))) float  f32x4;

// h lives in a permuted intra-row layout: element (s,f) at s*64 + (f&15)*4 + (f>>4).
// Consumers: k_front (write), k_mixer2 (rw), k_bmm_mfma (rw). All use this layout.
// spat0 (bmm iter0 output) shares this permuted layout, packed bf16, row stride TOT,
// living in feats16's h-region (dead until bmm iter1 overwrites it).

__device__ __forceinline__ float gelu_fast(float x){
    float x2 = x*x;
    float u  = __builtin_fmaf(0.044715f*x2, x, x);
    float e  = __builtin_amdgcn_exp2f(2.3022077f*u);
    float r  = __builtin_amdgcn_rcpf(e+1.f);
    return x - x*r;
}
template<int C>
__device__ __forceinline__ float dppadd(float v){
    int x = __builtin_amdgcn_mov_dpp(__float_as_int(v), C, 0xF, 0xF, true);
    return v + __int_as_float(x);
}
// sum over the 16 lanes of each row (lane&15 varies)
__device__ __forceinline__ float row16_sum(float v){
    v = dppadd<0xB1>(v);    // quad_perm(1,0,3,2)  : xor1
    v = dppadd<0x4E>(v);    // quad_perm(2,3,0,1)  : xor2
    v = dppadd<0x141>(v);   // row_half_mirror     : quad<->quad (xor7 post-collapse)
    v = dppadd<0x140>(v);   // row_mirror          : half<->half
    return v;
}
__device__ __forceinline__ float wave_sum64(float v){
    v = row16_sum(v);
    v += __shfl_xor(v,16,64);
    v += __shfl_xor(v,32,64);
    return v;
}
__device__ __forceinline__ void async_load16(const void* g, void* l){
    __builtin_amdgcn_global_load_lds(
        (const __attribute__((address_space(1))) void*)g,
        (__attribute__((address_space(3))) void*)l, 16, 0, 0);
}
__device__ __forceinline__ unsigned short f2bf(float x){
    unsigned int u = __float_as_uint(x);
    unsigned int r = (u + 0x7fffu + ((u>>16)&1u)) >> 16;
    return (unsigned short)r;
}
__device__ __forceinline__ float bf2f(unsigned short u){
    return __uint_as_float(((unsigned int)u)<<16);
}
__device__ __forceinline__ unsigned long long umax64(unsigned long long a, unsigned long long b){return a>b?a:b;}
__device__ __forceinline__ unsigned long long umin64(unsigned long long a, unsigned long long b){return a<b?a:b;}

// ------- front: h = LN(x@fp_w^T+fp_b)+norm(emb) ; ctx -> Q/K packed bf16 -------
__global__ __launch_bounds__(256) void k_front(
    const float* __restrict__ x, const float* __restrict__ fpw, const float* __restrict__ fpb,
    const float* __restrict__ lng, const float* __restrict__ lnb,
    const float* __restrict__ nemb,
    const float* __restrict__ qw, const float* __restrict__ qb,
    const float* __restrict__ kw, const float* __restrict__ kb,
    float* __restrict__ h,
    unsigned short* __restrict__ qpack, unsigned short* __restrict__ kpack)
{
    int bn = blockIdx.x; int n = bn % NN;
    int tid=threadIdx.x; int lane=tid&63; int wv=tid>>6;
    __shared__ float xin[SS*FIN];
    __shared__ float wlds[HH*FIN];
    __shared__ float rw[SS];
    __shared__ float rsum;
    __shared__ float red[4][HH];
    __shared__ float ctxs[HH];
    for (int i=tid;i<SS*FIN;i+=256) xin[i]=x[(size_t)bn*SS*FIN+i];
    for (int i=tid;i<HH*FIN;i+=256) wlds[i]=fpw[i];
    if (tid<SS) rw[tid]=expf(-(float)(SS-tid)/14.0f);
    __syncthreads();
    if (tid==0){ float s=0.f; for(int i=0;i<SS;++i) s+=rw[i]; rsum=s; }
    __syncthreads();
    float inv_rs = 1.0f/rsum;
    float ev = nemb[(size_t)n*HH+lane];
    float ss = wave_sum64(ev*ev);
    float el = ev / fmaxf(sqrtf(ss), 1e-12f);
    float gg=lng[lane], bv=lnb[lane], fb0=fpb[lane];
    int paddr = (lane&15)*4 + (lane>>4);
    float cacc=0.f;
    for (int s=wv;s<SS;s+=4){
        float v=fb0;
        #pragma unroll
        for (int c=0;c<FIN;++c) v += xin[s*FIN+c]*wlds[lane*FIN+c];
        float m = wave_sum64(v)*(1.f/HH);
        float d = v-m;
        float va = wave_sum64(d*d)*(1.f/HH);
        float hn = d*rsqrtf(va+1e-5f)*gg + bv + el;
        h[((size_t)bn*SS+s)*HH + paddr]=hn;
        cacc += hn * rw[s]*inv_rs;
    }
    red[wv][lane]=cacc;
    __syncthreads();
    if (wv==0) ctxs[lane]=red[0][lane]+red[1][lane]+red[2][lane]+red[3][lane];
    __syncthreads();
    if (wv==0){
        const float4* qr = reinterpret_cast<const float4*>(qw + (size_t)lane*HH);
        const float4* kr = reinterpret_cast<const float4*>(kw + (size_t)lane*HH);
        float q=qb[lane], k=kb[lane];
        #pragma unroll 4
        for (int t=0;t<16;++t){
            float4 qv=qr[t], kv=kr[t];
            float c0=ctxs[4*t], c1=ctxs[4*t+1], c2=ctxs[4*t+2], c3=ctxs[4*t+3];
            q += qv.x*c0+qv.y*c1+qv.z*c2+qv.w*c3;
            k += kv.x*c0+kv.y*c1+kv.z*c2+kv.w*c3;
        }
        int b = bn/NN, m = bn%NN;
        size_t off = (size_t)b*8*MP*8 + (size_t)(lane>>3)*MP*8 + (size_t)m*8 + (lane&7);
        qpack[off]=f2bf(q); kpack[off]=f2bf(k);
    }
}

// ---------------- QK^T via MFMA -> scores = relu(clip(QK^T/8)) f32 ----------------
__global__ __launch_bounds__(256) void k_qkt(
    const unsigned short* __restrict__ qp, const unsigned short* __restrict__ kp,
    float* __restrict__ scores)
{
    int bm=blockIdx.x, bnn=blockIdx.y, b=blockIdx.z;
    int tid=threadIdx.x, lane=tid&63, wv=tid>>6;
    int g=lane>>4, c15=lane&15;
    int m0=bm*128, n0=bnn*128;
    __shared__ unsigned short As[8192];  // [8][128][8]
    __shared__ unsigned short Bs[8192];
    const char* qbase = (const char*)(qp + (size_t)b*8*MP*8);
    const char* kbase = (const char*)(kp + (size_t)b*8*MP*8);
    #pragma unroll
    for (int i=0;i<4;++i){
        int idx=i*256+tid; int ch=idx>>7, r=idx&127;
        async_load16(qbase + ((size_t)(ch*MP + m0 + r))*16, (char*)As + idx*16);
        async_load16(kbase + ((size_t)(ch*MP + n0 + r))*16, (char*)Bs + idx*16);
    }
    asm volatile("s_waitcnt vmcnt(0)");
    __syncthreads();
    int wr=wv>>1, wc=wv&1;
    f32x4 acc[4][4];
    #pragma unroll
    for (int i=0;i<4;++i)
        #pragma unroll
        for (int j=0;j<4;++j) acc[i][j]=(f32x4){0.f,0.f,0.f,0.f};
    #pragma unroll
    for (int kc=0;kc<2;++kc){
        bf16x8 af[4], bfv[4];
        #pragma unroll
        for (int i=0;i<4;++i)
            af[i]=*(const bf16x8*)((const char*)As + ((4*kc+g)*128 + wr*64+i*16+c15)*16);
        #pragma unroll
        for (int j=0;j<4;++j)
            bfv[j]=*(const bf16x8*)((const char*)Bs + ((4*kc+g)*128 + wc*64+j*16+c15)*16);
        #pragma unroll
        for (int i=0;i<4;++i)
            #pragma unroll
            for (int j=0;j<4;++j)
                acc[i][j]=__builtin_amdgcn_mfma_f32_16x16x32_bf16(af[i],bfv[j],acc[i][j],0,0,0);
    }
    #pragma unroll
    for (int i=0;i<4;++i){
        #pragma unroll
        for (int q=0;q<4;++q){
            int m = m0 + wr*64 + i*16 + g*4 + q;
            float* sr = scores + ((size_t)b*SP + m)*SP + n0 + wc*64 + c15;
            #pragma unroll
            for (int j=0;j<4;++j){
                float v = acc[i][j][q]*0.125f;
                v = fminf(fmaxf(v,0.f),10.f);
                sr[j*16]=v;
            }
        }
    }
}

// ---- top-5 + softmax + blend + L1 normalize -> comb bf16 [b][MP][KP] ----
#define INS(x) do{ unsigned long long t_=(x); \
    unsigned long long n0_=umax64(u0,t_), t1_=umin64(u0,t_); \
    unsigned long long n1_=umax64(u1,t1_), t2_=umin64(u1,t1_); \
    unsigned long long n2_=umax64(u2,t2_), t3_=umin64(u2,t2_); \
    unsigned long long n3_=umax64(u3,t3_), t4_=umin64(u3,t3_); \
    unsigned long long n4_=umax64(u4,t4_); \
    u0=n0_;u1=n1_;u2=n2_;u3=n3_;u4=n4_; }while(0)

#define MERGE(b0,b1,b2,b3,b4) do{ \
    unsigned long long o0_=umax64(u0,(b0)); \
    unsigned long long o1_=umax64(umax64((b1),umin64(u0,(b0))),u1); \
    unsigned long long o2_=umax64(umax64((b2),umin64(u0,(b1))),umax64(umin64(u1,(b0)),u2)); \
    unsigned long long o3_=umax64(umax64((b3),umin64(u0,(b2))),umax64(umin64(u1,(b1)),umax64(umin64(u2,(b0)),u3))); \
    unsigned long long o4_=umax64(umax64((b4),umin64(u0,(b3))),umax64(umax64(umin64(u1,(b2)),umin64(u2,(b1))),umax64(umin64(u3,(b0)),u4))); \
    u0=o0_;u1=o1_;u2=o2_;u3=o3_;u4=o4_; }while(0)

__global__ __launch_bounds__(256) void k_topk(
    const float* __restrict__ scores, const float* __restrict__ adj,
    const float* __restrict__ galpha, __hip_bfloat16* __restrict__ combh)
{
    int m=blockIdx.x, b=blockIdx.y, tid=threadIdx.x, lane=tid&63, wv=tid>>6;
    __shared__ float row[KP];
    __shared__ unsigned long long wtop[4][8];
    __shared__ float redp[4];
    const float* srow = scores + ((size_t)b*SP + m)*SP;
    unsigned long long u0=0,u1=0,u2=0,u3=0,u4=0;
    for (int n=tid;n<NN;n+=256){
        float v=srow[n];
        unsigned long long key=((unsigned long long)__float_as_uint(v)<<32)|(unsigned long long)(0xFFFFFFFFu-(unsigned)n);
        INS(key);
    }
    #pragma unroll
    for (int off=1; off<64; off<<=1){
        unsigned long long b0=__shfl_xor(u0,off,64), b1=__shfl_xor(u1,off,64),
                           b2=__shfl_xor(u2,off,64), b3=__shfl_xor(u3,off,64),
                           b4=__shfl_xor(u4,off,64);
        MERGE(b0,b1,b2,b3,b4);
    }
    if (lane==0){ wtop[wv][0]=u0; wtop[wv][1]=u1; wtop[wv][2]=u2; wtop[wv][3]=u3; wtop[wv][4]=u4; }
    __syncthreads();
    u0=wtop[0][0]; u1=wtop[0][1]; u2=wtop[0][2]; u3=wtop[0][3]; u4=wtop[0][4];
    #pragma unroll
    for (int w2=1;w2<4;++w2)
        MERGE(wtop[w2][0],wtop[w2][1],wtop[w2][2],wtop[w2][3],wtop[w2][4]);

    float s0=__uint_as_float((unsigned)(u0>>32)), s1=__uint_as_float((unsigned)(u1>>32)),
          s2=__uint_as_float((unsigned)(u2>>32)), s3=__uint_as_float((unsigned)(u3>>32)),
          s4=__uint_as_float((unsigned)(u4>>32));
    int i0=(int)(0xFFFFFFFFu-(unsigned)u0), i1=(int)(0xFFFFFFFFu-(unsigned)u1),
        i2=(int)(0xFFFFFFFFu-(unsigned)u2), i3=(int)(0xFFFFFFFFu-(unsigned)u3),
        i4=(int)(0xFFFFFFFFu-(unsigned)u4);
    float e0=1.f, e1=expf(s1-s0), e2=expf(s2-s0), e3=expf(s3-s0), e4=expf(s4-s0);
    float den=e0+e1+e2+e3+e4;
    float alpha=1.f/(1.f+expf(-galpha[0]));
    float oma=(1.f-alpha)/den;
    float p0=oma*e0, p1=oma*e1, p2=oma*e2, p3=oma*e3, p4=oma*e4;

    const float* arow = adj + (size_t)m*NN;
    float part=0.f;
    for (int n=tid;n<NN;n+=256){
        float v=alpha*arow[n];
        v += (n==i0)?p0:0.f;
        v += (n==i1)?p1:0.f;
        v += (n==i2)?p2:0.f;
        v += (n==i3)?p3:0.f;
        v += (n==i4)?p4:0.f;
        row[n]=v;
        part+=fabsf(v);
    }
    part=wave_sum64(part);
    if (lane==0) redp[wv]=part;
    __syncthreads();
    float inv=1.f/fmaxf(redp[0]+redp[1]+redp[2]+redp[3],1e-12f);
    __hip_bfloat16* dst = combh + ((size_t)b*MP+m)*KP;
    for (int n=tid;n<KP;n+=256){
        float v = (n<NN) ? row[n]*inv : 0.f;
        dst[n]=__float2bfloat16(v);
    }
}
#undef INS
#undef MERGE

// ---- prep: build per-mixer-block bf16 weight images ----
__global__ __launch_bounds__(256) void k_prepw(
    const float* __restrict__ wk, const float* __restrict__ mk,
    const float* __restrict__ tw, const float* __restrict__ fw,
    const float* __restrict__ sw, unsigned short* __restrict__ wimg)
{
    int i = blockIdx.x; int tid = threadIdx.x;
    const float* wki = wk + i*7;
    const float* mki = mk + i*28;
    const float* twi = tw + i*SS*SS;
    const float* fwi = fw + i*HH*HH;
    const float* swi = sw + i*HH*HH;
    unsigned short* o = wimg + (size_t)i*WIMG_SZ;
    for (int e=tid; e<4096; e+=256){
        int r = e>>6, k = e&63;
        int swz = ((k*2) ^ ((r&7)<<4)) >> 1;
        float mv = 0.f;
        if (r<SS && k<SS){
            int a = k-r+3;  if (a>=0 && a<7)  mv += wki[a];
            int b2= k-r+13; if (b2>=0 && b2<28) mv += mki[b2];
        }
        o[r*64 + swz] = f2bf(mv);
        float tv = (r<SS && k<SS) ? twi[r*SS+k] : 0.f;
        o[4096 + r*64 + swz] = f2bf(tv);
        int pk = (k>>3)*512 + r*8 + (k&7);
        o[8192  + pk] = f2bf(fwi[r*HH+k]);
        o[12288 + pk] = f2bf(swi[r*HH+k]);
    }
}

// ---- prep: head_w f32 [28][5376] -> bf16 [32][5376] (pad rows zero) ----
__global__ __launch_bounds__(256) void k_prep_head(
    const float* __restrict__ hw, __hip_bfloat16* __restrict__ hw16)
{
    int i = blockIdx.x*256 + threadIdx.x;   // 32*TOT total
    int r = i / TOT, k = i - r*TOT;
    float v = (r<PP) ? hw[(size_t)r*TOT + k] : 0.f;
    hw16[i] = __float2bfloat16(v);
}

// ---- fut: feats16[bn][3584+q] = bf16(x_future @ futw^T + futb) ----
__global__ __launch_bounds__(256) void k_fut(
    const float* __restrict__ xf, const float* __restrict__ fw,
    const float* __restrict__ fbias, __hip_bfloat16* __restrict__ feats)
{
    int bn=blockIdx.x, tid=threadIdx.x;
    __shared__ float fwl[HH*FFUT];
    __shared__ float fbl[HH];
    __shared__ float xfl[PP*FFUT];
    for (int i=tid;i<HH*FFUT;i+=256) fwl[i]=fw[i];
    if (tid<HH) fbl[tid]=fbias[tid];
    for (int i=tid;i<PP*FFUT;i+=256) xfl[i]=xf[(size_t)bn*PP*FFUT+i];
    __syncthreads();
    __hip_bfloat16* dst = feats + (size_t)bn*TOT + DD;
    for (int q=tid;q<FD;q+=256){
        int pp=q>>6, hh2=q&63;
        float v=fbl[hh2];
        #pragma unroll
        for (int c2=0;c2<FFUT;++c2) v += xfl[pp*FFUT+c2]*fwl[hh2*FFUT+c2];
        dst[q]=__float2bfloat16(v);
    }
}

// ---------------- MFMA mixer block (h permuted; xpg direct-write; XCD-chunked grid) ----------------
__global__ __launch_bounds__(256) void k_mixer2(
    float* __restrict__ h, unsigned short* __restrict__ xpg,
    const unsigned short* __restrict__ spat_in,   // nullable: bf16 permuted, row stride TOT
    const unsigned short* __restrict__ wimg,
    const float* __restrict__ lncg, const float* __restrict__ lncb,
    const float* __restrict__ lntg, const float* __restrict__ lntb,
    const float* __restrict__ lnfg, const float* __restrict__ lnfb,
    const float* __restrict__ lnsg, const float* __restrict__ lnsb,
    const float* __restrict__ tb, const float* __restrict__ fb)
{
    int bid = blockIdx.x;
    int xx = bid & 7, ii = bid >> 3;
    int bn = (xx < 4) ? xx*719 + ii : 2876 + (xx-4)*718 + ii;
    int tid=threadIdx.x, lane=tid&63, w=tid>>6;
    int g=lane>>4, c=lane&15;
    __shared__ unsigned short wbuf[2][4096];
    __shared__ unsigned short xs[4096];
    __shared__ float prm[640];

    const char* wsrc=(const char*)wimg;
#define LOADW(SLOTB, BUFP) do{ \
    async_load16(wsrc+(size_t)(SLOTB)+((size_t)tid)*16,       (char*)(BUFP)+(w*64)*16); \
    async_load16(wsrc+(size_t)(SLOTB)+((size_t)(256+tid))*16, (char*)(BUFP)+((256+w*64))*16); } while(0)

    LOADW(0,    wbuf[0]);
    LOADW(8192, wbuf[1]);
    if (tid<64){
        prm[tid]      =lncg[tid]; prm[64+tid] =lncb[tid];
        prm[128+tid]  =lntg[tid]; prm[192+tid]=lntb[tid];
        prm[256+tid]  =lnfg[tid]; prm[320+tid]=lnfb[tid];
        prm[384+tid]  =lnsg[tid]; prm[448+tid]=lnsb[tid];
        prm[512+tid]  =(tid<SS)?tb[tid]:0.f;
        prm[576+tid]  =fb[tid];
    }
    float xl[4][4];
    float* hb = h + (size_t)bn*DD;
    int srow = 16*w + 4*g;
    #pragma unroll
    for (int q=0;q<4;++q){
        int s=srow+q;
        if (s<SS){
            const float4 v4 = *reinterpret_cast<const float4*>(hb + s*HH + c*4);
            float a0=v4.x, a1=v4.y, a2=v4.z, a3=v4.w;
            if (spat_in){
                ushort4 sv = *reinterpret_cast<const ushort4*>(spat_in + (size_t)bn*TOT + s*HH + c*4);
                a0 += bf2f(sv.x); a1 += bf2f(sv.y); a2 += bf2f(sv.z); a3 += bf2f(sv.w);
            }
            xl[q][0]=a0; xl[q][1]=a1; xl[q][2]=a2; xl[q][3]=a3;
        } else {
            xl[q][0]=0.f; xl[q][1]=0.f; xl[q][2]=0.f; xl[q][3]=0.f;
        }
    }
    __syncthreads();

    float xn[4][4];
    f32x4 acc[4];

#define LNSTAGE(GOFF,BOFF) do{ \
    _Pragma("unroll") \
    for (int q=0;q<4;++q){ \
        float sv = xl[q][0]+xl[q][1]+xl[q][2]+xl[q][3]; \
        float s2 = xl[q][0]*xl[q][0]+xl[q][1]*xl[q][1]+xl[q][2]*xl[q][2]+xl[q][3]*xl[q][3]; \
        sv = row16_sum(sv); \
        s2 = row16_sum(s2); \
        float mn = sv*(1.f/64.f); \
        float var = s2*(1.f/64.f)-mn*mn; \
        float rstd = rsqrtf(var+1e-5f); \
        bool ok = (srow+q)<SS; \
        _Pragma("unroll") \
        for (int tj=0;tj<4;++tj){ \
            float v=(xl[q][tj]-mn)*rstd*prm[(GOFF)+tj*16+c]+prm[(BOFF)+tj*16+c]; \
            xn[q][tj]= ok ? v : 0.f; \
        } \
    } }while(0)

#define WRITE_XNP() do{ \
    _Pragma("unroll") \
    for (int qp=0;qp<2;++qp){ \
        int s0=srow+2*qp; \
        _Pragma("unroll") \
        for (int tj=0;tj<4;++tj){ \
            unsigned int pv=(unsigned int)f2bf(xn[2*qp][tj])|((unsigned int)f2bf(xn[2*qp+1][tj])<<16); \
            *(unsigned int*)((char*)xs + ((s0>>3)*1024 + (tj*16+c)*16 + (s0&7)*2)) = pv; \
        } \
    } }while(0)

#define WRITE_XNR() do{ \
    _Pragma("unroll") \
    for (int q=0;q<4;++q){ int s=srow+q; \
        _Pragma("unroll") \
        for (int tj=0;tj<4;++tj){ \
            *(unsigned short*)((char*)xs + s*128 + (((tj*16+c)*2) ^ ((s&7)<<4))) = f2bf(xn[q][tj]); \
        } \
    } }while(0)

#define MM(APTR,BPTR) do{ \
    _Pragma("unroll") \
    for (int tj=0;tj<4;++tj) acc[tj]=(f32x4){0.f,0.f,0.f,0.f}; \
    _Pragma("unroll") \
    for (int kc=0;kc<2;++kc){ \
        int arow=16*w+c; \
        bf16x8 af=*(const bf16x8*)((const char*)(APTR)+arow*128+((kc*64+g*16)^((arow&7)<<4))); \
        _Pragma("unroll") \
        for (int tj=0;tj<4;++tj){ \
            bf16x8 bf2=*(const bf16x8*)((const char*)(BPTR)+(kc*4+g)*1024+(tj*16+c)*16); \
            acc[tj]=__builtin_amdgcn_mfma_f32_16x16x32_bf16(af,bf2,acc[tj],0,0,0); \
        } \
    } }while(0)

    // ---- conv (banded matmul) ----
    LNSTAGE(0,64); WRITE_XNP();
    __syncthreads();
    MM(&wbuf[0][0], xs);
    #pragma unroll
    for (int q=0;q<4;++q)
        #pragma unroll
        for (int tj=0;tj<4;++tj) xl[q][tj]+=acc[tj][q];
    __syncthreads();
    LOADW(16384, wbuf[0]);
    // ---- temporal ----
    LNSTAGE(128,192); WRITE_XNP();
    __syncthreads();
    MM(&wbuf[1][0], xs);
    #pragma unroll
    for (int q=0;q<4;++q){
        float tbv=prm[512+srow+q];
        #pragma unroll
        for (int tj=0;tj<4;++tj) xl[q][tj]+=gelu_fast(acc[tj][q]+tbv);
    }
    __syncthreads();
    LOADW(24576, wbuf[1]);
    // ---- feature ----
    LNSTAGE(256,320); WRITE_XNR();
    __syncthreads();
    MM(xs, &wbuf[0][0]);
    #pragma unroll
    for (int q=0;q<4;++q)
        #pragma unroll
        for (int tj=0;tj<4;++tj) xl[q][tj]+=gelu_fast(acc[tj][q]+prm[576+tj*16+c]);
    __syncthreads();
    // ---- spatial projection ----
    LNSTAGE(384,448); WRITE_XNR();
    __syncthreads();
    MM(xs, &wbuf[1][0]);
    int b_=bn/NN, n_=bn%NN;
    unsigned short* xpo = xpg + ((size_t)b_*(KP/8) + (size_t)(n_>>3))*(size_t)DD*8 + (n_&7);
    #pragma unroll
    for (int q=0;q<4;++q){
        int s=srow+q;
        if (s<SS){
            float4 hv; hv.x=xl[q][0]; hv.y=xl[q][1]; hv.z=xl[q][2]; hv.w=xl[q][3];
            *reinterpret_cast<float4*>(hb + s*HH + c*4) = hv;
            #pragma unroll
            for (int tj=0;tj<4;++tj){
                int d = s*HH + tj*16 + c;
                xpo[(size_t)d*8] = f2bf(acc[tj][q]);
            }
        }
    }
#undef LNSTAGE
#undef WRITE_XNP
#undef WRITE_XNR
#undef MM
#undef LOADW
}

// ---- spatial bmm via MFMA ----
// iter0 (spat_out != null): spat = comb@xp + sb -> bf16 permuted (row stride TOT)
// iter1 (feats_out != null): feats16 = h + comb@xp + sb (standard layout)
__global__ __launch_bounds__(256,4) void k_bmm_mfma(
    const __hip_bfloat16* __restrict__ combh,
    const __hip_bfloat16* __restrict__ xpg,
    const float* __restrict__ sb,
    const float* __restrict__ h,
    unsigned short* __restrict__ spat_out,
    __hip_bfloat16* __restrict__ feats_out)
{
    __shared__ short As[3][2048];
    __shared__ short Bs[3][4096];

    int bid = blockIdx.x;
    int wg = (bid & 7)*336 + (bid >> 3);
    int bm = wg % 24; int tmp2 = wg / 24; int bd = tmp2 % 28; int b = tmp2 / 28;
    int tid=threadIdx.x, lane=tid&63, w=tid>>6;
    int g=lane>>4, c=lane&15;
    int wr=w>>1, wc=w&1;
    int m0=bm*64, d0=bd*128;

    const char* cb = (const char*)(combh + (size_t)b*MP*KP);
    const char* xb = (const char*)(xpg   + (size_t)b*(KP/8)*(size_t)DD*8);

    int arow_s = tid>>2, aslot = tid&3;
    int ag = aslot ^ ((arow_s>>1)&3);
    const char* srcA = cb + ((size_t)(m0+arow_s)*KP + ag*8)*2;
    int bch = tid>>7, bcol = tid&127;
    const char* srcB0 = xb + ((size_t)bch*DD + d0 + bcol)*16;
    const char* srcB1 = xb + ((size_t)(bch+2)*DD + d0 + bcol)*16;
    const size_t BSTEP = (size_t)4*DD*16;

    f32x4 acc[2][4];
    #pragma unroll
    for (int i=0;i<2;++i)
        #pragma unroll
        for (int j=0;j<4;++j) acc[i][j]=(f32x4){0.f,0.f,0.f,0.f};

    int aoff[2], boff[4];
    #pragma unroll
    for (int i=0;i<2;++i){
        int row = 32*wr + 16*i + c;
        aoff[i] = row*64 + ((g*16) ^ (((row>>1)&3)<<4));
    }
    #pragma unroll
    for (int j=0;j<4;++j) boff[j] = (g*128 + 64*wc + 16*j + c)*16;

#define STAGE(BUF,T) do { \
    async_load16(srcA  + (size_t)(T)*64,    (char*)As[BUF] + w*1024); \
    async_load16(srcB0 + (size_t)(T)*BSTEP, (char*)Bs[BUF] + w*1024); \
    async_load16(srcB1 + (size_t)(T)*BSTEP, (char*)Bs[BUF] + 4096 + w*1024); } while(0)

    STAGE(0,0); STAGE(1,1);
    asm volatile("s_waitcnt vmcnt(3)" ::: "memory");
    __builtin_amdgcn_s_barrier();

    int cur=0;
    for (int t=0;t<NT;++t){
        if (t+2<NT){
            int nb = cur+2; if (nb>=3) nb-=3;
            STAGE(nb, t+2);
        }
        const char* Ab=(const char*)As[cur];
        const char* Bb=(const char*)Bs[cur];
        bf16x8 af[2], bfv[4];
        #pragma unroll
        for (int i=0;i<2;++i) af[i]=*(const bf16x8*)(Ab + aoff[i]);
        #pragma unroll
        for (int j=0;j<4;++j) bfv[j]=*(const bf16x8*)(Bb + boff[j]);
        #pragma unroll
        for (int i=0;i<2;++i)
            #pragma unroll
            for (int j=0;j<4;++j)
                acc[i][j]=__builtin_amdgcn_mfma_f32_16x16x32_bf16(af[i],bfv[j],acc[i][j],0,0,0);
        if (t+2<NT) asm volatile("s_waitcnt vmcnt(3)" ::: "memory");
        else        asm volatile("s_waitcnt vmcnt(0)" ::: "memory");
        __builtin_amdgcn_s_barrier();
        ++cur; if (cur>=3) cur=0;
    }
#undef STAGE

    int row_b = m0 + 32*wr + g*4;
    int s2 = 2*bd + wc;
    float sb0=sb[c], sb1=sb[16+c], sb2=sb[32+c], sb3=sb[48+c];
    #pragma unroll
    for (int i=0;i<2;++i){
        #pragma unroll
        for (int q=0;q<4;++q){
            int m = row_b + 16*i + q;
            if (m < NN){
                if (spat_out){
                    ushort4 pv;
                    pv.x = f2bf(acc[i][0][q] + sb0);
                    pv.y = f2bf(acc[i][1][q] + sb1);
                    pv.z = f2bf(acc[i][2][q] + sb2);
                    pv.w = f2bf(acc[i][3][q] + sb3);
                    *reinterpret_cast<ushort4*>(spat_out + ((size_t)b*NN+m)*TOT + s2*HH + c*4) = pv;
                } else {
                    const float* hp = h + ((size_t)b*NN+m)*DD + s2*HH + c*4;
                    float4 hv = *reinterpret_cast<const float4*>(hp);
                    float nv0 = hv.x + acc[i][0][q] + sb0;
                    float nv1 = hv.y + acc[i][1][q] + sb1;
                    float nv2 = hv.z + acc[i][2][q] + sb2;
                    float nv3 = hv.w + acc[i][3][q] + sb3;
                    size_t fr = ((size_t)b*NN+m)*TOT + (size_t)bd*128 + wc*64;
                    feats_out[fr + c]      = __float2bfloat16(nv0);
                    feats_out[fr + 16 + c] = __float2bfloat16(nv1);
                    feats_out[fr + 32 + c] = __float2bfloat16(nv2);
                    feats_out[fr + 48 + c] = __float2bfloat16(nv3);
                }
            }
        }
    }
}

// ---------------- head GEMM: out = feats16 @ hw16^T + hb ----------------
__global__ __launch_bounds__(256) void k_head_mfma(
    const __hip_bfloat16* __restrict__ feats, const __hip_bfloat16* __restrict__ hw16,
    const float* __restrict__ hb, float* __restrict__ out)
{
    int tid=threadIdx.x, lane=tid&63, w=tid>>6;
    int g=lane>>4, c=lane&15;
    int m0=blockIdx.x*32;
    int rt=w>>1, pt=w&1;
    int arow = m0 + rt*16 + c;
    if (arow > BB*NN-1) arow = BB*NN-1;
    const char* abase = (const char*)feats + (size_t)arow*TOT*2 + g*16;
    const char* bbase = (const char*)hw16 + (size_t)(pt*16+c)*TOT*2 + g*16;
    f32x4 acc=(f32x4){0.f,0.f,0.f,0.f};
    #pragma unroll 4
    for (int kc=0;kc<TOT/32;++kc){
        bf16x8 af =*(const bf16x8*)(abase + (size_t)kc*64);
        bf16x8 bf2=*(const bf16x8*)(bbase + (size_t)kc*64);
        acc=__builtin_amdgcn_mfma_f32_16x16x32_bf16(af,bf2,acc,0,0,0);
    }
    int col = pt*16 + c;
    #pragma unroll
    for (int q=0;q<4;++q){
        int row = m0 + rt*16 + g*4 + q;
        if (row < BB*NN && col < PP)
            out[(size_t)row*PP + col] = acc[q] + hb[col];
    }
}

extern "C" void kernel_launch(void* const* d_in, const int* in_sizes, int n_in,
                              void* d_out, int out_size, void* d_ws, size_t ws_size,
                              hipStream_t stream)
{
    const float* x      = (const float*)d_in[0];
    const float* xfut   = (const float*)d_in[1];
    const float* adj    = (const float*)d_in[2];
    const float* fp_w   = (const float*)d_in[3];
    const float* fp_b   = (const float*)d_in[4];
    const float* inlng  = (const float*)d_in[5];
    const float* inlnb  = (const float*)d_in[6];
    const float* q_w    = (const float*)d_in[7];
    const float* q_b    = (const float*)d_in[8];
    const float* k_w    = (const float*)d_in[9];
    const float* k_b    = (const float*)d_in[10];
    const float* nemb   = (const float*)d_in[11];
    const float* galpha = (const float*)d_in[12];
    const float* wk     = (const float*)d_in[13];
    const float* mk     = (const float*)d_in[14];
    const float* lncg   = (const float*)d_in[15];
    const float* lncb   = (const float*)d_in[16];
    const float* lntg   = (const float*)d_in[17];
    const float* lntb   = (const float*)d_in[18];
    const float* lnfg   = (const float*)d_in[19];
    const float* lnfb   = (const float*)d_in[20];
    const float* lnsg   = (const float*)d_in[21];
    const float* lnsb   = (const float*)d_in[22];
    const float* tw     = (const float*)d_in[23];
    const float* tb     = (const float*)d_in[24];
    const float* fw     = (const float*)d_in[25];
    const float* fb     = (const float*)d_in[26];
    const float* sw     = (const float*)d_in[27];
    const float* sb     = (const float*)d_in[28];
    const float* futw   = (const float*)d_in[29];
    const float* futb   = (const float*)d_in[30];
    const float* hw     = (const float*)d_in[31];
    const float* hb     = (const float*)d_in[32];
    (void)in_sizes; (void)n_in; (void)out_size; (void)ws_size;
    float* out = (float*)d_out;
    float* ws = (float*)d_ws;
    const size_t HSZ = (size_t)BB*NN*SS*HH;

    float* h    = ws;
    __hip_bfloat16* combh = (__hip_bfloat16*)(h + HSZ);
    __hip_bfloat16* xpg   = combh + (size_t)BB*MP*KP;
    float* scores = (float*)xpg;   // aliased: scores dead before xpg is written
    unsigned short* wimg  = (unsigned short*)(xpg + (size_t)BB*(KP/8)*(size_t)DD*8);
    unsigned short* qpack = wimg + (size_t)NBLK*WIMG_SZ;
    unsigned short* kpack = qpack + (size_t)BB*8*MP*8;
    __hip_bfloat16* feats16 = (__hip_bfloat16*)(kpack + (size_t)BB*8*MP*8);
    __hip_bfloat16* hw16    = feats16 + (size_t)BB*NN*TOT;

    k_prepw<<<NBLK,256,0,stream>>>(wk, mk, tw, fw, sw, wimg);
    k_prep_head<<<(32*TOT)/256,256,0,stream>>>(hw, hw16);
    k_fut<<<BB*NN,256,0,stream>>>(xfut, futw, futb, feats16);
    k_front<<<BB*NN,256,0,stream>>>(x, fp_w, fp_b, inlng, inlnb, nemb,
                                    q_w,q_b,k_w,k_b, h, qpack, kpack);
    dim3 gqkt(MP/128, MP/128, BB);
    k_qkt<<<gqkt,256,0,stream>>>(qpack, kpack, scores);
    dim3 gtop(NN,BB);
    k_topk<<<gtop,256,0,stream>>>(scores, adj, galpha, combh);
    // zero the K-pad rows of xpg (kc in [179,184)) — scores alias is dead now
    for (int b2=0;b2<BB;++b2)
        hipMemsetAsync(xpg + ((size_t)b2*(KP/8)+179)*(size_t)DD*8, 0,
                       (size_t)5*DD*8*sizeof(__hip_bfloat16), stream);
    // iter 0: mixer (no spat), bmm -> spat buffer (feats16 h-region, permuted bf16)
    k_mixer2<<<BB*NN,256,0,stream>>>(h, (unsigned short*)xpg, (const unsigned short*)nullptr,
        wimg, lncg,lncb, lntg,lntb, lnfg,lnfb, lnsg,lnsb, tb, fb);
    k_bmm_mfma<<<2688,256,0,stream>>>(combh, xpg, sb, h,
        (unsigned short*)feats16, (__hip_bfloat16*)nullptr);
    // iter 1: mixer adds spat at load, bmm -> feats16 (h + spat1)
    k_mixer2<<<BB*NN,256,0,stream>>>(h, (unsigned short*)xpg, (const unsigned short*)feats16,
        wimg + WIMG_SZ, lncg+HH,lncb+HH, lntg+HH,lntb+HH, lnfg+HH,lnfb+HH, lnsg+HH,lnsb+HH,
        tb+SS, fb+HH);
    k_bmm_mfma<<<2688,256,0,stream>>>(combh, xpg, sb+HH, h,
        (unsigned short*)nullptr, feats16);
    k_head_mfma<<<(BB*NN+31)/32,256,0,stream>>>(feats16, hw16, hb, out);
}